// Round 1
// baseline (5903.481 us; speedup 1.0000x reference)
//
#include <hip/hip_runtime.h>
#include <math.h>

#define NHEADS 6
#define DMODEL 384
#define TMAXT  577
#define NMAXT  576
#define BATCH  8
#define LAYERS 12

// ---------------- workspace layout (float indices) ----------------
#define XSZ      (8ull*577*384)            // 1,772,544
#define X0_OFF   0ull
#define X1_OFF   (X0_OFF + XSZ)
#define XN_OFF   (X1_OFF + XSZ)
#define QKV_OFF  (XN_OFF + XSZ)
#define QKV_SZ   (8ull*577*1152)           // 5,317,632
#define AO_OFF   (QKV_OFF + QKV_SZ)        // attn out, aliased into hbuf
#define HB_OFF   QKV_OFF                   // mlp hidden = qkv region + ao region (1152+384=1536)
#define RAWH_OFF (AO_OFF + XSZ)            // 8*6*576
#define RAWH_SZ  (8ull*6*576)
#define ENT_OFF  (RAWH_OFF + RAWH_SZ)      // 48 (pad 64)
#define PM_OFF   (ENT_OFF + 64)            // 8 (pad 64)
#define XF_OFF   (PM_OFF + 64)             // 8*384
#define KEEP_OFF (XF_OFF + 8*384)          // 577 ints (pad 640)
#define T_OFF    (KEEP_OFF + 640)
#define TN_OFF   (T_OFF + 16)

// ---------------- prologue: cls row + pos, init T ----------------
__global__ __launch_bounds__(128) void prologue_kernel(const float* __restrict__ cls_tok,
                                                       const float* __restrict__ pos,
                                                       float* __restrict__ x0,
                                                       int* __restrict__ dT)
{
    int b = blockIdx.x;
    for (int d = threadIdx.x; d < 384; d += 128)
        x0[(size_t)b*577*384 + d] = cls_tok[d] + pos[d];
    if (b == 0 && threadIdx.x == 0) *dT = 577;
}

// ---------------- patch embed GEMM: tok = patches @ patch_w + b + pos ----------------
__global__ __launch_bounds__(256) void patch_kernel(const float* __restrict__ x,
                                                    const float* __restrict__ pw,
                                                    const float* __restrict__ pb,
                                                    const float* __restrict__ pos,
                                                    float* __restrict__ x0)
{
    const int K = 768, Nc = 384;
    int row0 = blockIdx.y * 64, col0 = blockIdx.x * 64;
    __shared__ float As[16][68];
    __shared__ float Bs[16][68];
    int t = threadIdx.x;
    int tx = t & 15, ty = t >> 4;
    int am = t >> 2, ak = (t & 3) * 4;
    int bk = t >> 4, bn = (t & 15) * 4;
    float acc[4][4];
#pragma unroll
    for (int i = 0; i < 4; i++)
#pragma unroll
        for (int j = 0; j < 4; j++) acc[i][j] = 0.f;

    int arow = row0 + am;                    // < 4608 always (72*64)
    int b  = arow / 576, tt = arow % 576;
    int g1 = tt / 24,    g2 = tt % 24;
    const float* xr = x + ((size_t)(b*3)*384 + g1*16)*384 + g2*16;
    const float* Wp = pw + (size_t)bk*Nc + col0 + bn;

    for (int k0 = 0; k0 < K; k0 += 16) {
        int k = k0 + ak;
        int c = k >> 8, rr = k & 255, p1 = rr >> 4, p2 = rr & 15;
        float4 av = *(const float4*)(xr + ((size_t)c*384 + p1)*384 + p2);
        float4 wv = *(const float4*)(Wp + (size_t)k0*Nc);
        __syncthreads();
        As[ak+0][am] = av.x; As[ak+1][am] = av.y; As[ak+2][am] = av.z; As[ak+3][am] = av.w;
        *(float4*)&Bs[bk][bn] = wv;
        __syncthreads();
#pragma unroll
        for (int kk = 0; kk < 16; kk++) {
            float4 a4 = *(const float4*)&As[kk][ty*4];
            float4 b4 = *(const float4*)&Bs[kk][tx*4];
            acc[0][0] += a4.x*b4.x; acc[0][1] += a4.x*b4.y; acc[0][2] += a4.x*b4.z; acc[0][3] += a4.x*b4.w;
            acc[1][0] += a4.y*b4.x; acc[1][1] += a4.y*b4.y; acc[1][2] += a4.y*b4.z; acc[1][3] += a4.y*b4.w;
            acc[2][0] += a4.z*b4.x; acc[2][1] += a4.z*b4.y; acc[2][2] += a4.z*b4.z; acc[2][3] += a4.z*b4.w;
            acc[3][0] += a4.w*b4.x; acc[3][1] += a4.w*b4.y; acc[3][2] += a4.w*b4.z; acc[3][3] += a4.w*b4.w;
        }
    }
#pragma unroll
    for (int i = 0; i < 4; i++) {
        int r = row0 + ty*4 + i;
        int bb = r / 576, ttt = r % 576;
#pragma unroll
        for (int j = 0; j < 4; j++) {
            int c = col0 + tx*4 + j;
            float v = acc[i][j] + pb[c] + pos[(size_t)(1 + ttt)*384 + c];
            x0[(size_t)(bb*577 + 1 + ttt)*384 + c] = v;
        }
    }
}

// ---------------- LayerNorm (one wave per row) ----------------
__global__ __launch_bounds__(256) void ln_kernel(const float* __restrict__ xin,
                                                 const float* __restrict__ sc,
                                                 const float* __restrict__ bi,
                                                 float* __restrict__ xout,
                                                 const int* __restrict__ dT)
{
    int T = *dT;
    int M = 8 * T;
    int r = blockIdx.x * 4 + (threadIdx.x >> 6);
    if (r >= M) return;
    int lane = threadIdx.x & 63;
    const float* xr = xin + (size_t)r * 384;
    float v[6];
#pragma unroll
    for (int i = 0; i < 6; i++) v[i] = xr[lane + 64*i];
    float s = v[0]+v[1]+v[2]+v[3]+v[4]+v[5];
#pragma unroll
    for (int off = 32; off; off >>= 1) s += __shfl_xor(s, off, 64);
    float mean = s * (1.0f/384.0f);
    float q = 0.f;
#pragma unroll
    for (int i = 0; i < 6; i++) { float d = v[i]-mean; q += d*d; }
#pragma unroll
    for (int off = 32; off; off >>= 1) q += __shfl_xor(q, off, 64);
    float var = q * (1.0f/384.0f);
    float rstd = 1.0f / sqrtf(var + 1e-5f);
    float* yr = xout + (size_t)r * 384;
#pragma unroll
    for (int i = 0; i < 6; i++) {
        int d = lane + 64*i;
        yr[d] = (v[i]-mean) * rstd * sc[d] + bi[d];
    }
}

// ---------------- generic fp32 GEMM, 64x64x16 tile ----------------
template<bool GELU, bool RES>
__global__ __launch_bounds__(256) void gemm_kernel(const float* __restrict__ A,
                                                   const float* __restrict__ W,
                                                   const float* __restrict__ bias,
                                                   const float* __restrict__ resid,
                                                   float* __restrict__ C,
                                                   int K, int N,
                                                   const int* __restrict__ dT)
{
    int T = *dT;
    int M = 8 * T;
    int row0 = blockIdx.y * 64;
    if (row0 >= M) return;
    int col0 = blockIdx.x * 64;
    __shared__ float As[16][68];
    __shared__ float Bs[16][68];
    int t = threadIdx.x;
    int tx = t & 15, ty = t >> 4;
    int am = t >> 2, ak = (t & 3) * 4;
    int bk = t >> 4, bn = (t & 15) * 4;
    float acc[4][4];
#pragma unroll
    for (int i = 0; i < 4; i++)
#pragma unroll
        for (int j = 0; j < 4; j++) acc[i][j] = 0.f;

    bool aval = (row0 + am) < M;
    const float* Ap = A + (size_t)(row0 + am)*K + ak;
    const float* Wp = W + (size_t)bk*N + col0 + bn;

    for (int k0 = 0; k0 < K; k0 += 16) {
        float4 av = make_float4(0.f,0.f,0.f,0.f);
        if (aval) av = *(const float4*)(Ap + k0);
        float4 wv = *(const float4*)(Wp + (size_t)k0*N);
        __syncthreads();
        As[ak+0][am] = av.x; As[ak+1][am] = av.y; As[ak+2][am] = av.z; As[ak+3][am] = av.w;
        *(float4*)&Bs[bk][bn] = wv;
        __syncthreads();
#pragma unroll
        for (int kk = 0; kk < 16; kk++) {
            float4 a4 = *(const float4*)&As[kk][ty*4];
            float4 b4 = *(const float4*)&Bs[kk][tx*4];
            acc[0][0] += a4.x*b4.x; acc[0][1] += a4.x*b4.y; acc[0][2] += a4.x*b4.z; acc[0][3] += a4.x*b4.w;
            acc[1][0] += a4.y*b4.x; acc[1][1] += a4.y*b4.y; acc[1][2] += a4.y*b4.z; acc[1][3] += a4.y*b4.w;
            acc[2][0] += a4.z*b4.x; acc[2][1] += a4.z*b4.y; acc[2][2] += a4.z*b4.z; acc[2][3] += a4.z*b4.w;
            acc[3][0] += a4.w*b4.x; acc[3][1] += a4.w*b4.y; acc[3][2] += a4.w*b4.z; acc[3][3] += a4.w*b4.w;
        }
    }
#pragma unroll
    for (int i = 0; i < 4; i++) {
        int r = row0 + ty*4 + i;
        if (r >= M) continue;
#pragma unroll
        for (int j = 0; j < 4; j++) {
            int c = col0 + tx*4 + j;
            float v = acc[i][j] + bias[c];
            if (GELU) v = 0.5f * v * (1.0f + erff(v * 0.70710678118654752440f));
            if (RES)  v += resid[(size_t)r*N + c];
            C[(size_t)r*N + c] = v;
        }
    }
}

// ---------------- flash attention, fp32, 64-query tile ----------------
__global__ __launch_bounds__(256) void attn_kernel(const float* __restrict__ qkv,
                                                   float* __restrict__ out,
                                                   const int* __restrict__ dT)
{
    int T = *dT;
    int q0 = blockIdx.x * 64;
    if (q0 >= T) return;
    int bh = blockIdx.y;
    int b = bh / NHEADS, h = bh % NHEADS;

    __shared__ float Qs[64][68];
    __shared__ float KPs[64][68];   // K tile, then reused for P
    __shared__ float Vs[64][68];
    __shared__ float m_s[64], l_s[64], al_s[64];

    int t = threadIdx.x;
    int tx = t & 15, ty = t >> 4;
    int lr = t >> 4, d4 = (t & 15) * 4;

    // load Q tile
#pragma unroll
    for (int rep = 0; rep < 4; rep++) {
        int row = rep*16 + lr;
        int gq = q0 + row;
        float4 v = make_float4(0.f,0.f,0.f,0.f);
        if (gq < T) v = *(const float4*)(qkv + (size_t)(b*T + gq)*1152 + h*64 + d4);
        *(float4*)&Qs[row][d4] = v;
    }
    if (t < 64) { m_s[t] = -INFINITY; l_s[t] = 0.f; al_s[t] = 0.f; }

    float acc[4][4];
#pragma unroll
    for (int i = 0; i < 4; i++)
#pragma unroll
        for (int j = 0; j < 4; j++) acc[i][j] = 0.f;

    int ntiles = (T + 63) >> 6;
    for (int kt = 0; kt < ntiles; kt++) {
        int kbase = kt * 64;
        float4 kreg[4], vreg[4];
#pragma unroll
        for (int rep = 0; rep < 4; rep++) {
            int gk = kbase + rep*16 + lr;
            float4 a = make_float4(0.f,0.f,0.f,0.f), c = a;
            if (gk < T) {
                const float* base = qkv + (size_t)(b*T + gk)*1152 + h*64 + d4;
                a = *(const float4*)(base + 384);
                c = *(const float4*)(base + 768);
            }
            kreg[rep] = a; vreg[rep] = c;
        }
        __syncthreads();             // previous tile fully consumed
#pragma unroll
        for (int rep = 0; rep < 4; rep++) {
            int row = rep*16 + lr;
            *(float4*)&KPs[row][d4] = kreg[rep];
            *(float4*)&Vs[row][d4]  = vreg[rep];
        }
        __syncthreads();

        // S = Q K^T
        float s[4][4];
#pragma unroll
        for (int i = 0; i < 4; i++)
#pragma unroll
            for (int j = 0; j < 4; j++) s[i][j] = 0.f;
#pragma unroll
        for (int dd = 0; dd < 64; dd += 4) {
            float4 qa[4], kb[4];
#pragma unroll
            for (int i = 0; i < 4; i++) qa[i] = *(const float4*)&Qs[ty*4+i][dd];
#pragma unroll
            for (int j = 0; j < 4; j++) kb[j] = *(const float4*)&KPs[tx*4+j][dd];
#pragma unroll
            for (int i = 0; i < 4; i++)
#pragma unroll
                for (int j = 0; j < 4; j++)
                    s[i][j] += qa[i].x*kb[j].x + qa[i].y*kb[j].y + qa[i].z*kb[j].z + qa[i].w*kb[j].w;
        }
        __syncthreads();             // done reading K
#pragma unroll
        for (int i = 0; i < 4; i++)
#pragma unroll
            for (int j = 0; j < 4; j++) {
                int gk = kbase + tx*4 + j;
                KPs[ty*4+i][tx*4+j] = (gk < T) ? s[i][j]*0.125f : -INFINITY;
            }
        __syncthreads();

        // online softmax, 4 threads per row
        {
            int rr = t >> 2, sub = t & 3;
            float mx = -INFINITY;
#pragma unroll
            for (int kk = 0; kk < 16; kk++) mx = fmaxf(mx, KPs[rr][sub*16 + kk]);
            mx = fmaxf(mx, __shfl_xor(mx, 1, 64));
            mx = fmaxf(mx, __shfl_xor(mx, 2, 64));
            float mold = m_s[rr];
            float newm = fmaxf(mold, mx);
            float ps = 0.f;
#pragma unroll
            for (int kk = 0; kk < 16; kk++) {
                float p = expf(KPs[rr][sub*16 + kk] - newm);
                KPs[rr][sub*16 + kk] = p;
                ps += p;
            }
            ps += __shfl_xor(ps, 1, 64);
            ps += __shfl_xor(ps, 2, 64);
            if (sub == 0) {
                float alpha = expf(mold - newm);
                l_s[rr] = l_s[rr]*alpha + ps;
                m_s[rr] = newm;
                al_s[rr] = alpha;
            }
        }
        __syncthreads();

        // O = alpha*O + P V
#pragma unroll
        for (int i = 0; i < 4; i++) {
            float alpha = al_s[ty*4 + i];
#pragma unroll
            for (int j = 0; j < 4; j++) acc[i][j] *= alpha;
        }
        for (int kk = 0; kk < 64; kk++) {
            float4 v4 = *(const float4*)&Vs[kk][tx*4];
#pragma unroll
            for (int i = 0; i < 4; i++) {
                float p = KPs[ty*4 + i][kk];
                acc[i][0] += p*v4.x; acc[i][1] += p*v4.y; acc[i][2] += p*v4.z; acc[i][3] += p*v4.w;
            }
        }
    }
#pragma unroll
    for (int i = 0; i < 4; i++) {
        int gq = q0 + ty*4 + i;
        if (gq < T) {
            float inv = 1.0f / l_s[ty*4 + i];
            float* op = out + (size_t)(b*T + gq)*384 + h*64 + tx*4;
            op[0] = acc[i][0]*inv; op[1] = acc[i][1]*inv; op[2] = acc[i][2]*inv; op[3] = acc[i][3]*inv;
        }
    }
}

// ---------------- cls-row stats: entropy + raw importance per head ----------------
__global__ __launch_bounds__(256) void cls_stats_kernel(const float* __restrict__ qkv,
                                                        float* __restrict__ raw_h,
                                                        float* __restrict__ ent,
                                                        const int* __restrict__ dT)
{
    int T = *dT;
    int bh = blockIdx.x;
    int b = bh / NHEADS, h = bh % NHEADS;
    __shared__ float q0s[64];
    __shared__ float logit[TMAXT];
    __shared__ float red[8];
    int t = threadIdx.x;
    if (t < 64) q0s[t] = qkv[(size_t)(b*T)*1152 + h*64 + t];
    __syncthreads();
    float lmax = -INFINITY;
    for (int j = t; j < T; j += 256) {
        const float* kp = qkv + (size_t)(b*T + j)*1152 + 384 + h*64;
        float dot = 0.f;
#pragma unroll
        for (int d = 0; d < 64; d += 4) {
            float4 kk = *(const float4*)(kp + d);
            dot += q0s[d]*kk.x + q0s[d+1]*kk.y + q0s[d+2]*kk.z + q0s[d+3]*kk.w;
        }
        float lg = dot * 0.125f;
        logit[j] = lg;
        lmax = fmaxf(lmax, lg);
    }
#pragma unroll
    for (int off = 32; off; off >>= 1) lmax = fmaxf(lmax, __shfl_xor(lmax, off, 64));
    if ((t & 63) == 0) red[t >> 6] = lmax;
    __syncthreads();
    float gmax = fmaxf(fmaxf(red[0], red[1]), fmaxf(red[2], red[3]));
    __syncthreads();
    float psum = 0.f;
    for (int j = t; j < T; j += 256) psum += expf(logit[j] - gmax);
#pragma unroll
    for (int off = 32; off; off >>= 1) psum += __shfl_xor(psum, off, 64);
    if ((t & 63) == 0) red[4 + (t >> 6)] = psum;
    __syncthreads();
    float inv = 1.0f / (red[4] + red[5] + red[6] + red[7]);
    float entp = 0.f;
    for (int j = t; j < T; j += 256) {
        float p = expf(logit[j] - gmax) * inv;
        entp += -p * logf(p + 1e-6f);
        if (j >= 1) {
            const float* vp = qkv + (size_t)(b*T + j)*1152 + 768 + h*64;
            float vn = 0.f;
#pragma unroll
            for (int d = 0; d < 64; d += 4) {
                float4 vx = *(const float4*)(vp + d);
                vn += vx.x*vx.x + vx.y*vx.y + vx.z*vx.z + vx.w*vx.w;
            }
            raw_h[(size_t)bh*576 + (j - 1)] = p * sqrtf(vn);
        }
    }
#pragma unroll
    for (int off = 32; off; off >>= 1) entp += __shfl_xor(entp, off, 64);
    __syncthreads();
    if ((t & 63) == 0) red[t >> 6] = entp;
    __syncthreads();
    if (t == 0) ent[bh] = red[0] + red[1] + red[2] + red[3];
}

// ---------------- prune decision (single block) ----------------
__global__ __launch_bounds__(256) void decide_kernel(const float* __restrict__ raw_h,
                                                     const float* __restrict__ ent,
                                                     float* __restrict__ prev_mass,
                                                     int* __restrict__ keep,
                                                     const int* __restrict__ dT,
                                                     int* __restrict__ dTnext,
                                                     int layer)
{
    int t = threadIdx.x;
    int T = *dT, N = T - 1;
    __shared__ float massS[8];
    __shared__ float scores[NMAXT];
    __shared__ int   keptFlag[NMAXT];
    __shared__ int   nnS;
    if (N <= 16) {
        for (int i = t; i < T; i += 256) keep[i] = i;
        if (t == 0) *dTnext = T;
        return;
    }
    // mass[b]: 8 groups of 32 lanes
    {
        int b = t >> 5, lane = t & 31;
        float s = 0.f;
        for (int h = 0; h < 6; h++)
            for (int j = lane; j < N; j += 32)
                s += raw_h[(size_t)(b*6 + h)*576 + j];
#pragma unroll
        for (int off = 16; off; off >>= 1) s += __shfl_xor(s, off, 64);
        if (lane == 0) massS[b] = s;
    }
    __syncthreads();
    // scores[j] = mean_b raw[b,j]/(mass_b+eps)
    for (int j = t; j < N; j += 256) {
        float s = 0.f;
        for (int b = 0; b < 8; b++) {
            float rb = 0.f;
            for (int h = 0; h < 6; h++) rb += raw_h[(size_t)(b*6 + h)*576 + j];
            s += rb / (massS[b] + 1e-6f);
        }
        scores[j] = s * 0.125f;
    }
    __syncthreads();
    if (t == 0) {
        float es = 0.f;
        for (int i = 0; i < 48; i++) es += ent[i];
        float rho_mean = es / 48.0f / logf((float)T);
        int Nn;
        if (layer == 0) {
            Nn = N;
        } else {
            float dm = 0.f;
            for (int b = 0; b < 8; b++)
                dm += fabsf(massS[b] - prev_mass[b]) / (prev_mass[b] + 1e-6f);
            dm *= 0.125f;
            float kr = 1.0f - 0.1f * (rho_mean + dm);
            kr = fminf(fmaxf(kr, 0.0f), 1.0f);
            Nn = (int)((double)N * (double)kr);   // Python int() truncation
            if (Nn < 16) Nn = 16;
        }
        nnS = Nn;
        *dTnext = Nn + 1;
    }
    __syncthreads();
    if (t < 8) prev_mass[t] = massS[t];          // after delta was read
    int Nn = nnS;
    if (Nn < N) {
        for (int j = t; j < N; j += 256) {
            float sj = scores[j];
            int cnt = 0;
            for (int j2 = 0; j2 < N; j2++) {
                float s2 = scores[j2];
                cnt += (s2 > sj) || (s2 == sj && j2 < j);
            }
            keptFlag[j] = (cnt < Nn) ? 1 : 0;
        }
        __syncthreads();
        if (t == 0) {
            keep[0] = 0;
            int pos = 1;
            for (int j = 0; j < N; j++)
                if (keptFlag[j]) keep[pos++] = j + 1;
        }
    } else {
        for (int i = t; i < T; i += 256) keep[i] = i;
    }
}

// ---------------- gather pruned tokens (ping-pong) ----------------
__global__ __launch_bounds__(128) void gather_kernel(const float* __restrict__ src,
                                                     float* __restrict__ dst,
                                                     const int* __restrict__ keep,
                                                     const int* __restrict__ dT,
                                                     const int* __restrict__ dTnext)
{
    int Tn = *dTnext;
    int ti = blockIdx.x;
    if (ti >= Tn) return;
    int To = *dT;
    int b = blockIdx.y;
    const float* s = src + (size_t)(b*To + keep[ti]) * 384;
    float* d = dst + (size_t)(b*Tn + ti) * 384;
    int t = threadIdx.x;
    if (t < 96) ((float4*)d)[t] = ((const float4*)s)[t];
}

__global__ void bump_kernel(int* dT, const int* dTnext) { *dT = *dTnext; }

// ---------------- final LN on cls rows ----------------
__global__ __launch_bounds__(64) void lnf_kernel(const float* __restrict__ xin,
                                                 const float* __restrict__ sc,
                                                 const float* __restrict__ bi,
                                                 float* __restrict__ xf,
                                                 const int* __restrict__ dT)
{
    int T = *dT;
    int b = blockIdx.x;
    int lane = threadIdx.x;
    const float* xr = xin + (size_t)(b*T) * 384;
    float v[6];
#pragma unroll
    for (int i = 0; i < 6; i++) v[i] = xr[lane + 64*i];
    float s = v[0]+v[1]+v[2]+v[3]+v[4]+v[5];
#pragma unroll
    for (int off = 32; off; off >>= 1) s += __shfl_xor(s, off, 64);
    float mean = s * (1.0f/384.0f);
    float q = 0.f;
#pragma unroll
    for (int i = 0; i < 6; i++) { float d = v[i]-mean; q += d*d; }
#pragma unroll
    for (int off = 32; off; off >>= 1) q += __shfl_xor(q, off, 64);
    float rstd = 1.0f / sqrtf(q * (1.0f/384.0f) + 1e-5f);
#pragma unroll
    for (int i = 0; i < 6; i++) {
        int d = lane + 64*i;
        xf[(size_t)b*384 + d] = (v[i]-mean) * rstd * sc[d] + bi[d];
    }
}

// ---------------- head ----------------
__global__ __launch_bounds__(256) void head_kernel(const float* __restrict__ xf,
                                                   const float* __restrict__ hw,
                                                   const float* __restrict__ hb,
                                                   float* __restrict__ out)
{
    int idx = blockIdx.x * 256 + threadIdx.x;
    if (idx >= 8000) return;
    int b = idx / 1000, n = idx - b*1000;
    const float* xr = xf + (size_t)b*384;
    float s = hb[n];
#pragma unroll 4
    for (int k = 0; k < 384; k++) s += xr[k] * hw[(size_t)k*1000 + n];
    out[idx] = s;
}

// ---------------- launch ----------------
extern "C" void kernel_launch(void* const* d_in, const int* in_sizes, int n_in,
                              void* d_out, int out_size, void* d_ws, size_t ws_size,
                              hipStream_t stream)
{
    (void)in_sizes; (void)n_in; (void)out_size; (void)ws_size;
    const float* x       = (const float*)d_in[0];
    const float* patch_w = (const float*)d_in[1];
    const float* patch_b = (const float*)d_in[2];
    const float* cls_tok = (const float*)d_in[3];
    const float* pos     = (const float*)d_in[4];
    const float* ln1_s   = (const float*)d_in[5];
    const float* ln1_b   = (const float*)d_in[6];
    const float* qkv_w   = (const float*)d_in[7];
    const float* qkv_b   = (const float*)d_in[8];
    const float* proj_w  = (const float*)d_in[9];
    const float* proj_b  = (const float*)d_in[10];
    const float* ln2_s   = (const float*)d_in[11];
    const float* ln2_b   = (const float*)d_in[12];
    const float* fc1_w   = (const float*)d_in[13];
    const float* fc1_b   = (const float*)d_in[14];
    const float* fc2_w   = (const float*)d_in[15];
    const float* fc2_b   = (const float*)d_in[16];
    const float* norm_s  = (const float*)d_in[17];
    const float* norm_b  = (const float*)d_in[18];
    const float* head_w  = (const float*)d_in[19];
    const float* head_b  = (const float*)d_in[20];
    float* out = (float*)d_out;
    float* ws  = (float*)d_ws;

    float* x0   = ws + X0_OFF;
    float* x1   = ws + X1_OFF;
    float* xn   = ws + XN_OFF;
    float* qkvb = ws + QKV_OFF;
    float* ao   = ws + AO_OFF;
    float* hb   = ws + HB_OFF;
    float* rawh = ws + RAWH_OFF;
    float* entb = ws + ENT_OFF;
    float* pm   = ws + PM_OFF;
    float* xf   = ws + XF_OFF;
    int*   keep = (int*)(ws + KEEP_OFF);
    int*   dT   = (int*)(ws + T_OFF);
    int*   dTn  = (int*)(ws + TN_OFF);

    prologue_kernel<<<8, 128, 0, stream>>>(cls_tok, pos, x0, dT);
    patch_kernel<<<dim3(6, 72), 256, 0, stream>>>(x, patch_w, patch_b, pos, x0);

    float* bufs[2] = { x0, x1 };
    for (int l = 0; l < LAYERS; l++) {
        float* src = bufs[l & 1];
        float* dst = bufs[(l + 1) & 1];
        ln_kernel<<<1154, 256, 0, stream>>>(src, ln1_s + l*384, ln1_b + l*384, xn, dT);
        gemm_kernel<false, false><<<dim3(18, 73), 256, 0, stream>>>(
            xn, qkv_w + (size_t)l*384*1152, qkv_b + l*1152, nullptr, qkvb, 384, 1152, dT);
        attn_kernel<<<dim3(10, 48), 256, 0, stream>>>(qkvb, ao, dT);
        cls_stats_kernel<<<48, 256, 0, stream>>>(qkvb, rawh, entb, dT);
        gemm_kernel<false, true><<<dim3(6, 73), 256, 0, stream>>>(
            ao, proj_w + (size_t)l*384*384, proj_b + l*384, src, src, 384, 384, dT);
        ln_kernel<<<1154, 256, 0, stream>>>(src, ln2_s + l*384, ln2_b + l*384, xn, dT);
        gemm_kernel<true, false><<<dim3(24, 73), 256, 0, stream>>>(
            xn, fc1_w + (size_t)l*384*1536, fc1_b + l*1536, nullptr, hb, 384, 1536, dT);
        gemm_kernel<false, true><<<dim3(6, 73), 256, 0, stream>>>(
            hb, fc2_w + (size_t)l*1536*384, fc2_b + l*384, src, src, 1536, 384, dT);
        decide_kernel<<<1, 256, 0, stream>>>(rawh, entb, pm, keep, dT, dTn, l);
        gather_kernel<<<dim3(577, 8), 128, 0, stream>>>(src, dst, keep, dT, dTn);
        bump_kernel<<<1, 1, 0, stream>>>(dT, dTn);
    }
    lnf_kernel<<<8, 64, 0, stream>>>(bufs[0], norm_s, norm_b, xf, dT);
    head_kernel<<<32, 256, 0, stream>>>(xf, head_w, head_b, out);
}

// Round 2
// 4817.948 us; speedup vs baseline: 1.2253x; 1.2253x over previous
//
#include <hip/hip_runtime.h>
#include <math.h>

#define NHEADS 6
#define DMODEL 384
#define TMAXT  577
#define NMAXT  576
#define BATCH  8
#define LAYERS 12

// ---------------- workspace layout (float indices) ----------------
#define XSZ      (8ull*577*384)            // 1,772,544
#define X0_OFF   0ull
#define X1_OFF   (X0_OFF + XSZ)
#define XN_OFF   (X1_OFF + XSZ)
#define QKV_OFF  (XN_OFF + XSZ)
#define QKV_SZ   (8ull*577*1152)           // 5,317,632
#define AO_OFF   (QKV_OFF + QKV_SZ)        // attn out, aliased into hbuf
#define HB_OFF   QKV_OFF                   // mlp hidden = qkv region + ao region (1152+384=1536)
#define RAWH_OFF (AO_OFF + XSZ)            // 8*6*576
#define RAWH_SZ  (8ull*6*576)
#define ENT_OFF  (RAWH_OFF + RAWH_SZ)      // 48 (pad 64)
#define PM_OFF   (ENT_OFF + 64)            // 8 (pad 64)
#define XF_OFF   (PM_OFF + 64)             // 8*384
#define KEEP_OFF (XF_OFF + 8*384)          // 577 ints (pad 640)
#define T_OFF    (KEEP_OFF + 640)
#define TN_OFF   (T_OFF + 16)

// ---------------- prologue: cls row + pos, init T ----------------
__global__ __launch_bounds__(128) void prologue_kernel(const float* __restrict__ cls_tok,
                                                       const float* __restrict__ pos,
                                                       float* __restrict__ x0,
                                                       int* __restrict__ dT)
{
    int b = blockIdx.x;
    for (int d = threadIdx.x; d < 384; d += 128)
        x0[(size_t)b*577*384 + d] = cls_tok[d] + pos[d];
    if (b == 0 && threadIdx.x == 0) *dT = 577;
}

// ---------------- patch embed GEMM: tok = patches @ patch_w + b + pos ----------------
__global__ __launch_bounds__(256) void patch_kernel(const float* __restrict__ x,
                                                    const float* __restrict__ pw,
                                                    const float* __restrict__ pb,
                                                    const float* __restrict__ pos,
                                                    float* __restrict__ x0)
{
    const int K = 768, Nc = 384;
    int row0 = blockIdx.y * 64, col0 = blockIdx.x * 64;
    __shared__ float As[16][68];
    __shared__ float Bs[16][68];
    int t = threadIdx.x;
    int tx = t & 15, ty = t >> 4;
    int am = t >> 2, ak = (t & 3) * 4;
    int bk = t >> 4, bn = (t & 15) * 4;
    float acc[4][4];
#pragma unroll
    for (int i = 0; i < 4; i++)
#pragma unroll
        for (int j = 0; j < 4; j++) acc[i][j] = 0.f;

    int arow = row0 + am;                    // < 4608 always (72*64)
    int b  = arow / 576, tt = arow % 576;
    int g1 = tt / 24,    g2 = tt % 24;
    const float* xr = x + ((size_t)(b*3)*384 + g1*16)*384 + g2*16;
    const float* Wp = pw + (size_t)bk*Nc + col0 + bn;

    for (int k0 = 0; k0 < K; k0 += 16) {
        int k = k0 + ak;
        int c = k >> 8, rr = k & 255, p1 = rr >> 4, p2 = rr & 15;
        float4 av = *(const float4*)(xr + ((size_t)c*384 + p1)*384 + p2);
        float4 wv = *(const float4*)(Wp + (size_t)k0*Nc);
        __syncthreads();
        As[ak+0][am] = av.x; As[ak+1][am] = av.y; As[ak+2][am] = av.z; As[ak+3][am] = av.w;
        *(float4*)&Bs[bk][bn] = wv;
        __syncthreads();
#pragma unroll
        for (int kk = 0; kk < 16; kk++) {
            float4 a4 = *(const float4*)&As[kk][ty*4];
            float4 b4 = *(const float4*)&Bs[kk][tx*4];
            acc[0][0] += a4.x*b4.x; acc[0][1] += a4.x*b4.y; acc[0][2] += a4.x*b4.z; acc[0][3] += a4.x*b4.w;
            acc[1][0] += a4.y*b4.x; acc[1][1] += a4.y*b4.y; acc[1][2] += a4.y*b4.z; acc[1][3] += a4.y*b4.w;
            acc[2][0] += a4.z*b4.x; acc[2][1] += a4.z*b4.y; acc[2][2] += a4.z*b4.z; acc[2][3] += a4.z*b4.w;
            acc[3][0] += a4.w*b4.x; acc[3][1] += a4.w*b4.y; acc[3][2] += a4.w*b4.z; acc[3][3] += a4.w*b4.w;
        }
    }
#pragma unroll
    for (int i = 0; i < 4; i++) {
        int r = row0 + ty*4 + i;
        int bb = r / 576, ttt = r % 576;
#pragma unroll
        for (int j = 0; j < 4; j++) {
            int c = col0 + tx*4 + j;
            float v = acc[i][j] + pb[c] + pos[(size_t)(1 + ttt)*384 + c];
            x0[(size_t)(bb*577 + 1 + ttt)*384 + c] = v;
        }
    }
}

// ---------------- LayerNorm (one wave per row) ----------------
__global__ __launch_bounds__(256) void ln_kernel(const float* __restrict__ xin,
                                                 const float* __restrict__ sc,
                                                 const float* __restrict__ bi,
                                                 float* __restrict__ xout,
                                                 const int* __restrict__ dT)
{
    int T = *dT;
    int M = 8 * T;
    int r = blockIdx.x * 4 + (threadIdx.x >> 6);
    if (r >= M) return;
    int lane = threadIdx.x & 63;
    const float* xr = xin + (size_t)r * 384;
    float v[6];
#pragma unroll
    for (int i = 0; i < 6; i++) v[i] = xr[lane + 64*i];
    float s = v[0]+v[1]+v[2]+v[3]+v[4]+v[5];
#pragma unroll
    for (int off = 32; off; off >>= 1) s += __shfl_xor(s, off, 64);
    float mean = s * (1.0f/384.0f);
    float q = 0.f;
#pragma unroll
    for (int i = 0; i < 6; i++) { float d = v[i]-mean; q += d*d; }
#pragma unroll
    for (int off = 32; off; off >>= 1) q += __shfl_xor(q, off, 64);
    float var = q * (1.0f/384.0f);
    float rstd = 1.0f / sqrtf(var + 1e-5f);
    float* yr = xout + (size_t)r * 384;
#pragma unroll
    for (int i = 0; i < 6; i++) {
        int d = lane + 64*i;
        yr[d] = (v[i]-mean) * rstd * sc[d] + bi[d];
    }
}

// ---------------- generic fp32 GEMM, 64x64x16 tile ----------------
template<bool GELU, bool RES>
__global__ __launch_bounds__(256) void gemm_kernel(const float* __restrict__ A,
                                                   const float* __restrict__ W,
                                                   const float* __restrict__ bias,
                                                   const float* __restrict__ resid,
                                                   float* __restrict__ C,
                                                   int K, int N,
                                                   const int* __restrict__ dT)
{
    int T = *dT;
    int M = 8 * T;
    int row0 = blockIdx.y * 64;
    if (row0 >= M) return;
    int col0 = blockIdx.x * 64;
    __shared__ float As[16][68];
    __shared__ float Bs[16][68];
    int t = threadIdx.x;
    int tx = t & 15, ty = t >> 4;
    int am = t >> 2, ak = (t & 3) * 4;
    int bk = t >> 4, bn = (t & 15) * 4;
    float acc[4][4];
#pragma unroll
    for (int i = 0; i < 4; i++)
#pragma unroll
        for (int j = 0; j < 4; j++) acc[i][j] = 0.f;

    bool aval = (row0 + am) < M;
    const float* Ap = A + (size_t)(row0 + am)*K + ak;
    const float* Wp = W + (size_t)bk*N + col0 + bn;

    for (int k0 = 0; k0 < K; k0 += 16) {
        float4 av = make_float4(0.f,0.f,0.f,0.f);
        if (aval) av = *(const float4*)(Ap + k0);
        float4 wv = *(const float4*)(Wp + (size_t)k0*N);
        __syncthreads();
        As[ak+0][am] = av.x; As[ak+1][am] = av.y; As[ak+2][am] = av.z; As[ak+3][am] = av.w;
        *(float4*)&Bs[bk][bn] = wv;
        __syncthreads();
#pragma unroll
        for (int kk = 0; kk < 16; kk++) {
            float4 a4 = *(const float4*)&As[kk][ty*4];
            float4 b4 = *(const float4*)&Bs[kk][tx*4];
            acc[0][0] += a4.x*b4.x; acc[0][1] += a4.x*b4.y; acc[0][2] += a4.x*b4.z; acc[0][3] += a4.x*b4.w;
            acc[1][0] += a4.y*b4.x; acc[1][1] += a4.y*b4.y; acc[1][2] += a4.y*b4.z; acc[1][3] += a4.y*b4.w;
            acc[2][0] += a4.z*b4.x; acc[2][1] += a4.z*b4.y; acc[2][2] += a4.z*b4.z; acc[2][3] += a4.z*b4.w;
            acc[3][0] += a4.w*b4.x; acc[3][1] += a4.w*b4.y; acc[3][2] += a4.w*b4.z; acc[3][3] += a4.w*b4.w;
        }
    }
#pragma unroll
    for (int i = 0; i < 4; i++) {
        int r = row0 + ty*4 + i;
        if (r >= M) continue;
#pragma unroll
        for (int j = 0; j < 4; j++) {
            int c = col0 + tx*4 + j;
            float v = acc[i][j] + bias[c];
            if (GELU) v = 0.5f * v * (1.0f + erff(v * 0.70710678118654752440f));
            if (RES)  v += resid[(size_t)r*N + c];
            C[(size_t)r*N + c] = v;
        }
    }
}

// ---------------- flash attention, fp32, 64-query tile (register-lean v2) ----------------
// v1 pathology: 256 VGPRs + ~280 MB/dispatch scratch spills (auto-unrolled 64-iter
// PV loop hoisted ~64 LDS loads). v2: direct global->LDS staging (no reg prefetch),
// capped unrolls, native __expf, __launch_bounds__(256,3) -> <=168 VGPR, 3 blk/CU.
__global__ __launch_bounds__(256, 3) void attn_kernel(const float* __restrict__ qkv,
                                                      float* __restrict__ out,
                                                      const int* __restrict__ dT)
{
    int T = *dT;
    int q0 = blockIdx.x * 64;
    if (q0 >= T) return;
    int bh = blockIdx.y;
    int b = bh / NHEADS, h = bh % NHEADS;

    __shared__ float Qs[64][68];
    __shared__ float KPs[64][68];   // K tile, then reused for P
    __shared__ float Vs[64][68];
    __shared__ float m_s[64], l_s[64], al_s[64];

    int t = threadIdx.x;
    int tx = t & 15, ty = t >> 4;
    int lr = t >> 4, d4 = (t & 15) * 4;

    // load Q tile
#pragma unroll
    for (int rep = 0; rep < 4; rep++) {
        int row = rep*16 + lr;
        int gq = q0 + row;
        float4 v = make_float4(0.f,0.f,0.f,0.f);
        if (gq < T) v = *(const float4*)(qkv + (size_t)(b*T + gq)*1152 + h*64 + d4);
        *(float4*)&Qs[row][d4] = v;
    }
    if (t < 64) { m_s[t] = -INFINITY; l_s[t] = 0.f; }

    float acc[4][4];
#pragma unroll
    for (int i = 0; i < 4; i++)
#pragma unroll
        for (int j = 0; j < 4; j++) acc[i][j] = 0.f;

    int ntiles = (T + 63) >> 6;
    for (int kt = 0; kt < ntiles; kt++) {
        int kbase = kt * 64;
        __syncthreads();             // prev tile's P/V fully consumed (covers Q/m/l init on kt=0)
#pragma unroll
        for (int rep = 0; rep < 4; rep++) {
            int row = rep*16 + lr;
            int gk = kbase + row;
            float4 a = make_float4(0.f,0.f,0.f,0.f), c = a;
            if (gk < T) {
                const float* base = qkv + (size_t)(b*T + gk)*1152 + h*64 + d4;
                a = *(const float4*)(base + 384);
                c = *(const float4*)(base + 768);
            }
            *(float4*)&KPs[row][d4] = a;
            *(float4*)&Vs[row][d4]  = c;
        }
        __syncthreads();

        // S = Q K^T  (capped unroll: 8 ds_read_b128 + 64 FMA per chunk)
        float s[4][4];
#pragma unroll
        for (int i = 0; i < 4; i++)
#pragma unroll
            for (int j = 0; j < 4; j++) s[i][j] = 0.f;
#pragma unroll 2
        for (int dd = 0; dd < 64; dd += 4) {
            float4 qa[4], kb[4];
#pragma unroll
            for (int i = 0; i < 4; i++) qa[i] = *(const float4*)&Qs[ty*4+i][dd];
#pragma unroll
            for (int j = 0; j < 4; j++) kb[j] = *(const float4*)&KPs[tx*4+j][dd];
#pragma unroll
            for (int i = 0; i < 4; i++)
#pragma unroll
                for (int j = 0; j < 4; j++)
                    s[i][j] += qa[i].x*kb[j].x + qa[i].y*kb[j].y + qa[i].z*kb[j].z + qa[i].w*kb[j].w;
        }
        __syncthreads();             // done reading K
#pragma unroll
        for (int i = 0; i < 4; i++)
#pragma unroll
            for (int j = 0; j < 4; j++) {
                int gk = kbase + tx*4 + j;
                KPs[ty*4+i][tx*4+j] = (gk < T) ? s[i][j]*0.125f : -INFINITY;
            }
        __syncthreads();

        // online softmax, 4 threads per row (native exp: rel err ~1e-6)
        {
            int rr = t >> 2, sub = t & 3;
            float mx = -INFINITY;
#pragma unroll
            for (int kk = 0; kk < 16; kk++) mx = fmaxf(mx, KPs[rr][sub*16 + kk]);
            mx = fmaxf(mx, __shfl_xor(mx, 1, 64));
            mx = fmaxf(mx, __shfl_xor(mx, 2, 64));
            float mold = m_s[rr];
            float newm = fmaxf(mold, mx);
            float ps = 0.f;
#pragma unroll
            for (int kk = 0; kk < 16; kk++) {
                float p = __expf(KPs[rr][sub*16 + kk] - newm);
                KPs[rr][sub*16 + kk] = p;
                ps += p;
            }
            ps += __shfl_xor(ps, 1, 64);
            ps += __shfl_xor(ps, 2, 64);
            if (sub == 0) {
                float alpha = __expf(mold - newm);
                l_s[rr] = l_s[rr]*alpha + ps;
                m_s[rr] = newm;
                al_s[rr] = alpha;
            }
        }
        __syncthreads();

        // O = alpha*O + P V  (chunked like the S loop: 8 ds_read_b128 + 64 FMA)
#pragma unroll
        for (int i = 0; i < 4; i++) {
            float alpha = al_s[ty*4 + i];
#pragma unroll
            for (int j = 0; j < 4; j++) acc[i][j] *= alpha;
        }
#pragma unroll 2
        for (int kk = 0; kk < 64; kk += 4) {
            float4 pv[4], vb[4];
#pragma unroll
            for (int i = 0; i < 4; i++) pv[i] = *(const float4*)&KPs[ty*4+i][kk];
#pragma unroll
            for (int m = 0; m < 4; m++) vb[m] = *(const float4*)&Vs[kk+m][tx*4];
#pragma unroll
            for (int i = 0; i < 4; i++) {
                acc[i][0] += pv[i].x*vb[0].x + pv[i].y*vb[1].x + pv[i].z*vb[2].x + pv[i].w*vb[3].x;
                acc[i][1] += pv[i].x*vb[0].y + pv[i].y*vb[1].y + pv[i].z*vb[2].y + pv[i].w*vb[3].y;
                acc[i][2] += pv[i].x*vb[0].z + pv[i].y*vb[1].z + pv[i].z*vb[2].z + pv[i].w*vb[3].z;
                acc[i][3] += pv[i].x*vb[0].w + pv[i].y*vb[1].w + pv[i].z*vb[2].w + pv[i].w*vb[3].w;
            }
        }
    }
#pragma unroll
    for (int i = 0; i < 4; i++) {
        int gq = q0 + ty*4 + i;
        if (gq < T) {
            float inv = 1.0f / l_s[ty*4 + i];
            float* op = out + (size_t)(b*T + gq)*384 + h*64 + tx*4;
            op[0] = acc[i][0]*inv; op[1] = acc[i][1]*inv; op[2] = acc[i][2]*inv; op[3] = acc[i][3]*inv;
        }
    }
}

// ---------------- cls-row stats: entropy + raw importance per head ----------------
__global__ __launch_bounds__(256) void cls_stats_kernel(const float* __restrict__ qkv,
                                                        float* __restrict__ raw_h,
                                                        float* __restrict__ ent,
                                                        const int* __restrict__ dT)
{
    int T = *dT;
    int bh = blockIdx.x;
    int b = bh / NHEADS, h = bh % NHEADS;
    __shared__ float q0s[64];
    __shared__ float logit[TMAXT];
    __shared__ float red[8];
    int t = threadIdx.x;
    if (t < 64) q0s[t] = qkv[(size_t)(b*T)*1152 + h*64 + t];
    __syncthreads();
    float lmax = -INFINITY;
    for (int j = t; j < T; j += 256) {
        const float* kp = qkv + (size_t)(b*T + j)*1152 + 384 + h*64;
        float dot = 0.f;
#pragma unroll
        for (int d = 0; d < 64; d += 4) {
            float4 kk = *(const float4*)(kp + d);
            dot += q0s[d]*kk.x + q0s[d+1]*kk.y + q0s[d+2]*kk.z + q0s[d+3]*kk.w;
        }
        float lg = dot * 0.125f;
        logit[j] = lg;
        lmax = fmaxf(lmax, lg);
    }
#pragma unroll
    for (int off = 32; off; off >>= 1) lmax = fmaxf(lmax, __shfl_xor(lmax, off, 64));
    if ((t & 63) == 0) red[t >> 6] = lmax;
    __syncthreads();
    float gmax = fmaxf(fmaxf(red[0], red[1]), fmaxf(red[2], red[3]));
    __syncthreads();
    float psum = 0.f;
    for (int j = t; j < T; j += 256) psum += expf(logit[j] - gmax);
#pragma unroll
    for (int off = 32; off; off >>= 1) psum += __shfl_xor(psum, off, 64);
    if ((t & 63) == 0) red[4 + (t >> 6)] = psum;
    __syncthreads();
    float inv = 1.0f / (red[4] + red[5] + red[6] + red[7]);
    float entp = 0.f;
    for (int j = t; j < T; j += 256) {
        float p = expf(logit[j] - gmax) * inv;
        entp += -p * logf(p + 1e-6f);
        if (j >= 1) {
            const float* vp = qkv + (size_t)(b*T + j)*1152 + 768 + h*64;
            float vn = 0.f;
#pragma unroll
            for (int d = 0; d < 64; d += 4) {
                float4 vx = *(const float4*)(vp + d);
                vn += vx.x*vx.x + vx.y*vx.y + vx.z*vx.z + vx.w*vx.w;
            }
            raw_h[(size_t)bh*576 + (j - 1)] = p * sqrtf(vn);
        }
    }
#pragma unroll
    for (int off = 32; off; off >>= 1) entp += __shfl_xor(entp, off, 64);
    __syncthreads();
    if ((t & 63) == 0) red[t >> 6] = entp;
    __syncthreads();
    if (t == 0) ent[bh] = red[0] + red[1] + red[2] + red[3];
}

// ---------------- prune decision (single block) ----------------
__global__ __launch_bounds__(256) void decide_kernel(const float* __restrict__ raw_h,
                                                     const float* __restrict__ ent,
                                                     float* __restrict__ prev_mass,
                                                     int* __restrict__ keep,
                                                     const int* __restrict__ dT,
                                                     int* __restrict__ dTnext,
                                                     int layer)
{
    int t = threadIdx.x;
    int T = *dT, N = T - 1;
    __shared__ float massS[8];
    __shared__ float scores[NMAXT];
    __shared__ int   keptFlag[NMAXT];
    __shared__ int   nnS;
    if (N <= 16) {
        for (int i = t; i < T; i += 256) keep[i] = i;
        if (t == 0) *dTnext = T;
        return;
    }
    // mass[b]: 8 groups of 32 lanes
    {
        int b = t >> 5, lane = t & 31;
        float s = 0.f;
        for (int h = 0; h < 6; h++)
            for (int j = lane; j < N; j += 32)
                s += raw_h[(size_t)(b*6 + h)*576 + j];
#pragma unroll
        for (int off = 16; off; off >>= 1) s += __shfl_xor(s, off, 64);
        if (lane == 0) massS[b] = s;
    }
    __syncthreads();
    // scores[j] = mean_b raw[b,j]/(mass_b+eps)
    for (int j = t; j < N; j += 256) {
        float s = 0.f;
        for (int b = 0; b < 8; b++) {
            float rb = 0.f;
            for (int h = 0; h < 6; h++) rb += raw_h[(size_t)(b*6 + h)*576 + j];
            s += rb / (massS[b] + 1e-6f);
        }
        scores[j] = s * 0.125f;
    }
    __syncthreads();
    if (t == 0) {
        float es = 0.f;
        for (int i = 0; i < 48; i++) es += ent[i];
        float rho_mean = es / 48.0f / logf((float)T);
        int Nn;
        if (layer == 0) {
            Nn = N;
        } else {
            float dm = 0.f;
            for (int b = 0; b < 8; b++)
                dm += fabsf(massS[b] - prev_mass[b]) / (prev_mass[b] + 1e-6f);
            dm *= 0.125f;
            float kr = 1.0f - 0.1f * (rho_mean + dm);
            kr = fminf(fmaxf(kr, 0.0f), 1.0f);
            Nn = (int)((double)N * (double)kr);   // Python int() truncation
            if (Nn < 16) Nn = 16;
        }
        nnS = Nn;
        *dTnext = Nn + 1;
    }
    __syncthreads();
    if (t < 8) prev_mass[t] = massS[t];          // after delta was read
    int Nn = nnS;
    if (Nn < N) {
        for (int j = t; j < N; j += 256) {
            float sj = scores[j];
            int cnt = 0;
            for (int j2 = 0; j2 < N; j2++) {
                float s2 = scores[j2];
                cnt += (s2 > sj) || (s2 == sj && j2 < j);
            }
            keptFlag[j] = (cnt < Nn) ? 1 : 0;
        }
        __syncthreads();
        if (t == 0) {
            keep[0] = 0;
            int pos = 1;
            for (int j = 0; j < N; j++)
                if (keptFlag[j]) keep[pos++] = j + 1;
        }
    } else {
        for (int i = t; i < T; i += 256) keep[i] = i;
    }
}

// ---------------- gather pruned tokens (ping-pong) ----------------
__global__ __launch_bounds__(128) void gather_kernel(const float* __restrict__ src,
                                                     float* __restrict__ dst,
                                                     const int* __restrict__ keep,
                                                     const int* __restrict__ dT,
                                                     const int* __restrict__ dTnext)
{
    int Tn = *dTnext;
    int ti = blockIdx.x;
    if (ti >= Tn) return;
    int To = *dT;
    int b = blockIdx.y;
    const float* s = src + (size_t)(b*To + keep[ti]) * 384;
    float* d = dst + (size_t)(b*Tn + ti) * 384;
    int t = threadIdx.x;
    if (t < 96) ((float4*)d)[t] = ((const float4*)s)[t];
}

__global__ void bump_kernel(int* dT, const int* dTnext) { *dT = *dTnext; }

// ---------------- final LN on cls rows ----------------
__global__ __launch_bounds__(64) void lnf_kernel(const float* __restrict__ xin,
                                                 const float* __restrict__ sc,
                                                 const float* __restrict__ bi,
                                                 float* __restrict__ xf,
                                                 const int* __restrict__ dT)
{
    int T = *dT;
    int b = blockIdx.x;
    int lane = threadIdx.x;
    const float* xr = xin + (size_t)(b*T) * 384;
    float v[6];
#pragma unroll
    for (int i = 0; i < 6; i++) v[i] = xr[lane + 64*i];
    float s = v[0]+v[1]+v[2]+v[3]+v[4]+v[5];
#pragma unroll
    for (int off = 32; off; off >>= 1) s += __shfl_xor(s, off, 64);
    float mean = s * (1.0f/384.0f);
    float q = 0.f;
#pragma unroll
    for (int i = 0; i < 6; i++) { float d = v[i]-mean; q += d*d; }
#pragma unroll
    for (int off = 32; off; off >>= 1) q += __shfl_xor(q, off, 64);
    float rstd = 1.0f / sqrtf(q * (1.0f/384.0f) + 1e-5f);
#pragma unroll
    for (int i = 0; i < 6; i++) {
        int d = lane + 64*i;
        xf[(size_t)b*384 + d] = (v[i]-mean) * rstd * sc[d] + bi[d];
    }
}

// ---------------- head ----------------
__global__ __launch_bounds__(256) void head_kernel(const float* __restrict__ xf,
                                                   const float* __restrict__ hw,
                                                   const float* __restrict__ hb,
                                                   float* __restrict__ out)
{
    int idx = blockIdx.x * 256 + threadIdx.x;
    if (idx >= 8000) return;
    int b = idx / 1000, n = idx - b*1000;
    const float* xr = xf + (size_t)b*384;
    float s = hb[n];
#pragma unroll 4
    for (int k = 0; k < 384; k++) s += xr[k] * hw[(size_t)k*1000 + n];
    out[idx] = s;
}

// ---------------- launch ----------------
extern "C" void kernel_launch(void* const* d_in, const int* in_sizes, int n_in,
                              void* d_out, int out_size, void* d_ws, size_t ws_size,
                              hipStream_t stream)
{
    (void)in_sizes; (void)n_in; (void)out_size; (void)ws_size;
    const float* x       = (const float*)d_in[0];
    const float* patch_w = (const float*)d_in[1];
    const float* patch_b = (const float*)d_in[2];
    const float* cls_tok = (const float*)d_in[3];
    const float* pos     = (const float*)d_in[4];
    const float* ln1_s   = (const float*)d_in[5];
    const float* ln1_b   = (const float*)d_in[6];
    const float* qkv_w   = (const float*)d_in[7];
    const float* qkv_b   = (const float*)d_in[8];
    const float* proj_w  = (const float*)d_in[9];
    const float* proj_b  = (const float*)d_in[10];
    const float* ln2_s   = (const float*)d_in[11];
    const float* ln2_b   = (const float*)d_in[12];
    const float* fc1_w   = (const float*)d_in[13];
    const float* fc1_b   = (const float*)d_in[14];
    const float* fc2_w   = (const float*)d_in[15];
    const float* fc2_b   = (const float*)d_in[16];
    const float* norm_s  = (const float*)d_in[17];
    const float* norm_b  = (const float*)d_in[18];
    const float* head_w  = (const float*)d_in[19];
    const float* head_b  = (const float*)d_in[20];
    float* out = (float*)d_out;
    float* ws  = (float*)d_ws;

    float* x0   = ws + X0_OFF;
    float* x1   = ws + X1_OFF;
    float* xn   = ws + XN_OFF;
    float* qkvb = ws + QKV_OFF;
    float* ao   = ws + AO_OFF;
    float* hb   = ws + HB_OFF;
    float* rawh = ws + RAWH_OFF;
    float* entb = ws + ENT_OFF;
    float* pm   = ws + PM_OFF;
    float* xf   = ws + XF_OFF;
    int*   keep = (int*)(ws + KEEP_OFF);
    int*   dT   = (int*)(ws + T_OFF);
    int*   dTn  = (int*)(ws + TN_OFF);

    prologue_kernel<<<8, 128, 0, stream>>>(cls_tok, pos, x0, dT);
    patch_kernel<<<dim3(6, 72), 256, 0, stream>>>(x, patch_w, patch_b, pos, x0);

    float* bufs[2] = { x0, x1 };
    for (int l = 0; l < LAYERS; l++) {
        float* src = bufs[l & 1];
        float* dst = bufs[(l + 1) & 1];
        ln_kernel<<<1154, 256, 0, stream>>>(src, ln1_s + l*384, ln1_b + l*384, xn, dT);
        gemm_kernel<false, false><<<dim3(18, 73), 256, 0, stream>>>(
            xn, qkv_w + (size_t)l*384*1152, qkv_b + l*1152, nullptr, qkvb, 384, 1152, dT);
        attn_kernel<<<dim3(10, 48), 256, 0, stream>>>(qkvb, ao, dT);
        cls_stats_kernel<<<48, 256, 0, stream>>>(qkvb, rawh, entb, dT);
        gemm_kernel<false, true><<<dim3(6, 73), 256, 0, stream>>>(
            ao, proj_w + (size_t)l*384*384, proj_b + l*384, src, src, 384, 384, dT);
        ln_kernel<<<1154, 256, 0, stream>>>(src, ln2_s + l*384, ln2_b + l*384, xn, dT);
        gemm_kernel<true, false><<<dim3(24, 73), 256, 0, stream>>>(
            xn, fc1_w + (size_t)l*384*1536, fc1_b + l*1536, nullptr, hb, 384, 1536, dT);
        gemm_kernel<false, true><<<dim3(6, 73), 256, 0, stream>>>(
            hb, fc2_w + (size_t)l*1536*384, fc2_b + l*384, src, src, 1536, 384, dT);
        decide_kernel<<<1, 256, 0, stream>>>(rawh, entb, pm, keep, dT, dTn, l);
        gather_kernel<<<dim3(577, 8), 128, 0, stream>>>(src, dst, keep, dT, dTn);
        bump_kernel<<<1, 1, 0, stream>>>(dT, dTn);
    }
    lnf_kernel<<<8, 64, 0, stream>>>(bufs[0], norm_s, norm_b, xf, dT);
    head_kernel<<<32, 256, 0, stream>>>(xf, head_w, head_b, out);
}

// Round 3
// 3472.132 us; speedup vs baseline: 1.7002x; 1.3876x over previous
//
#include <hip/hip_runtime.h>
#include <math.h>

#define NHEADS 6
#define DMODEL 384
#define TMAXT  577
#define NMAXT  576
#define BATCH  8
#define LAYERS 12

typedef __attribute__((ext_vector_type(8))) short bf16x8v;
typedef __attribute__((ext_vector_type(4))) float f32x4v;

// ---------------- workspace layout (float indices) ----------------
#define XSZ      (8ull*577*384)            // 1,772,544
#define X0_OFF   0ull
#define X1_OFF   (X0_OFF + XSZ)
#define XN_OFF   (X1_OFF + XSZ)            // xn split planes: 2 x XSZ ushort = XSZ floats
#define QKV_OFF  (XN_OFF + XSZ)
#define QKV_SZ   (8ull*577*1152)           // 5,317,632 floats
#define AO_OFF   (QKV_OFF + QKV_SZ)        // ao split planes: 2 x XSZ ushort = XSZ floats
#define HBELEM   (8ull*577*1536)           // 7,090,176 elements (= QKV_SZ + XSZ floats as 2 ushort planes)
#define RAWH_OFF (AO_OFF + XSZ)            // 8*6*576
#define RAWH_SZ  (8ull*6*576)
#define ENT_OFF  (RAWH_OFF + RAWH_SZ)      // 48 (pad 64)
#define PM_OFF   (ENT_OFF + 64)            // 8 (pad 64)
#define XF_OFF   (PM_OFF + 64)             // 8*384
#define KEEP_OFF (XF_OFF + 8*384)          // 577 ints (pad 640)
#define T_OFF    (KEEP_OFF + 640)
#define TN_OFF   (T_OFF + 16)
#define WSPL_OFF (TN_OFF + 16)             // weight splits: 3,538,944 ushort = 1,769,472 floats

// weight split sub-offsets (ushort units inside WSPL)
#define W_QKV   0ull
#define W_PROJ  884736ull
#define W_FC1   1179648ull
#define W_FC2   2359296ull

// ---------------- bf16 split helpers ----------------
__device__ inline unsigned short rne_bf16(float f) {
    unsigned int u = __float_as_uint(f);
    u += 0x7FFFu + ((u >> 16) & 1u);
    return (unsigned short)(u >> 16);
}
__device__ inline float bf16_to_f(unsigned short h) {
    return __uint_as_float(((unsigned int)h) << 16);
}
__device__ inline void split_bf16(float x, unsigned short& h, unsigned short& l) {
    h = rne_bf16(x);
    l = rne_bf16(x - bf16_to_f(h));
}

// ---------------- prologue: cls row + pos, init T ----------------
__global__ __launch_bounds__(128) void prologue_kernel(const float* __restrict__ cls_tok,
                                                       const float* __restrict__ pos,
                                                       float* __restrict__ x0,
                                                       int* __restrict__ dT)
{
    int b = blockIdx.x;
    for (int d = threadIdx.x; d < 384; d += 128)
        x0[(size_t)b*577*384 + d] = cls_tok[d] + pos[d];
    if (b == 0 && threadIdx.x == 0) *dT = 577;
}

// ---------------- patch embed GEMM (fp32 vector, unchanged) ----------------
__global__ __launch_bounds__(256) void patch_kernel(const float* __restrict__ x,
                                                    const float* __restrict__ pw,
                                                    const float* __restrict__ pb,
                                                    const float* __restrict__ pos,
                                                    float* __restrict__ x0)
{
    const int K = 768, Nc = 384;
    int row0 = blockIdx.y * 64, col0 = blockIdx.x * 64;
    __shared__ float As[16][68];
    __shared__ float Bs[16][68];
    int t = threadIdx.x;
    int tx = t & 15, ty = t >> 4;
    int am = t >> 2, ak = (t & 3) * 4;
    int bk = t >> 4, bn = (t & 15) * 4;
    float acc[4][4];
#pragma unroll
    for (int i = 0; i < 4; i++)
#pragma unroll
        for (int j = 0; j < 4; j++) acc[i][j] = 0.f;

    int arow = row0 + am;
    int b  = arow / 576, tt = arow % 576;
    int g1 = tt / 24,    g2 = tt % 24;
    const float* xr = x + ((size_t)(b*3)*384 + g1*16)*384 + g2*16;
    const float* Wp = pw + (size_t)bk*Nc + col0 + bn;

    for (int k0 = 0; k0 < K; k0 += 16) {
        int k = k0 + ak;
        int c = k >> 8, rr = k & 255, p1 = rr >> 4, p2 = rr & 15;
        float4 av = *(const float4*)(xr + ((size_t)c*384 + p1)*384 + p2);
        float4 wv = *(const float4*)(Wp + (size_t)k0*Nc);
        __syncthreads();
        As[ak+0][am] = av.x; As[ak+1][am] = av.y; As[ak+2][am] = av.z; As[ak+3][am] = av.w;
        *(float4*)&Bs[bk][bn] = wv;
        __syncthreads();
#pragma unroll
        for (int kk = 0; kk < 16; kk++) {
            float4 a4 = *(const float4*)&As[kk][ty*4];
            float4 b4 = *(const float4*)&Bs[kk][tx*4];
            acc[0][0] += a4.x*b4.x; acc[0][1] += a4.x*b4.y; acc[0][2] += a4.x*b4.z; acc[0][3] += a4.x*b4.w;
            acc[1][0] += a4.y*b4.x; acc[1][1] += a4.y*b4.y; acc[1][2] += a4.y*b4.z; acc[1][3] += a4.y*b4.w;
            acc[2][0] += a4.z*b4.x; acc[2][1] += a4.z*b4.y; acc[2][2] += a4.z*b4.z; acc[2][3] += a4.z*b4.w;
            acc[3][0] += a4.w*b4.x; acc[3][1] += a4.w*b4.y; acc[3][2] += a4.w*b4.z; acc[3][3] += a4.w*b4.w;
        }
    }
#pragma unroll
    for (int i = 0; i < 4; i++) {
        int r = row0 + ty*4 + i;
        int bb = r / 576, ttt = r % 576;
#pragma unroll
        for (int j = 0; j < 4; j++) {
            int c = col0 + tx*4 + j;
            float v = acc[i][j] + pb[c] + pos[(size_t)(1 + ttt)*384 + c];
            x0[(size_t)(bb*577 + 1 + ttt)*384 + c] = v;
        }
    }
}

// ---------------- weight split+transpose: W[K][N] fp32 -> Wt_hi/lo [N][K] bf16 ----------------
__global__ __launch_bounds__(256) void wsplit_kernel(const float* __restrict__ qkvw,
                                                     const float* __restrict__ projw,
                                                     const float* __restrict__ fc1w,
                                                     const float* __restrict__ fc2w,
                                                     unsigned short* __restrict__ wspl)
{
    int mat = blockIdx.y;
    const float* W; int K, N; size_t off;
    if (mat == 0)      { W = qkvw; K = 384;  N = 1152; off = W_QKV; }
    else if (mat == 1) { W = projw; K = 384; N = 384;  off = W_PROJ; }
    else if (mat == 2) { W = fc1w; K = 384;  N = 1536; off = W_FC1; }
    else               { W = fc2w; K = 1536; N = 384;  off = W_FC2; }
    int ktiles = K >> 5, ntiles = N >> 5;
    int tid = blockIdx.x;
    if (tid >= ktiles * ntiles) return;
    int tk = tid % ktiles, tn = tid / ktiles;
    int k0 = tk << 5, n0 = tn << 5;
    __shared__ unsigned short Th[32][34];
    __shared__ unsigned short Tl[32][34];
    int t = threadIdx.x;
    {
        int row = t >> 3, c4 = (t & 7) << 2;
        float4 wv = *(const float4*)(W + (size_t)(k0 + row) * N + n0 + c4);
        unsigned short h, l;
        split_bf16(wv.x, h, l); Th[c4+0][row] = h; Tl[c4+0][row] = l;
        split_bf16(wv.y, h, l); Th[c4+1][row] = h; Tl[c4+1][row] = l;
        split_bf16(wv.z, h, l); Th[c4+2][row] = h; Tl[c4+2][row] = l;
        split_bf16(wv.w, h, l); Th[c4+3][row] = h; Tl[c4+3][row] = l;
    }
    __syncthreads();
    {
        int n = t >> 3, k4 = (t & 7) << 2;
        unsigned short* dh = wspl + off + (size_t)(n0 + n) * K + k0 + k4;
        unsigned short* dl = dh + (size_t)K * N;
        ushort4 oh = make_ushort4(Th[n][k4], Th[n][k4+1], Th[n][k4+2], Th[n][k4+3]);
        ushort4 ol = make_ushort4(Tl[n][k4], Tl[n][k4+1], Tl[n][k4+2], Tl[n][k4+3]);
        *(ushort4*)dh = oh;
        *(ushort4*)dl = ol;
    }
}

// ---------------- LayerNorm -> split bf16 planes ----------------
__global__ __launch_bounds__(256) void ln_kernel(const float* __restrict__ xin,
                                                 const float* __restrict__ sc,
                                                 const float* __restrict__ bi,
                                                 unsigned short* __restrict__ yhi,
                                                 unsigned short* __restrict__ ylo,
                                                 const int* __restrict__ dT)
{
    int T = *dT;
    int M = 8 * T;
    int r = blockIdx.x * 4 + (threadIdx.x >> 6);
    if (r >= M) return;
    int lane = threadIdx.x & 63;
    const float* xr = xin + (size_t)r * 384;
    float v[6];
#pragma unroll
    for (int i = 0; i < 6; i++) v[i] = xr[lane + 64*i];
    float s = v[0]+v[1]+v[2]+v[3]+v[4]+v[5];
#pragma unroll
    for (int off = 32; off; off >>= 1) s += __shfl_xor(s, off, 64);
    float mean = s * (1.0f/384.0f);
    float q = 0.f;
#pragma unroll
    for (int i = 0; i < 6; i++) { float d = v[i]-mean; q += d*d; }
#pragma unroll
    for (int off = 32; off; off >>= 1) q += __shfl_xor(q, off, 64);
    float rstd = 1.0f / sqrtf(q * (1.0f/384.0f) + 1e-5f);
#pragma unroll
    for (int i = 0; i < 6; i++) {
        int d = lane + 64*i;
        float y = (v[i]-mean) * rstd * sc[d] + bi[d];
        unsigned short h, l;
        split_bf16(y, h, l);
        yhi[(size_t)r*384 + d] = h;
        ylo[(size_t)r*384 + d] = l;
    }
}

// ---------------- bf16x3 MFMA GEMM: C = A*W + bias (+gelu / +resid) ----------------
// A: split planes [M][K]; Wt: transposed split [N][K], lo plane at +K*N.
// EPI 0: fp32 out; EPI 1: gelu -> split-bf16 out; EPI 2: +resid -> fp32 out.
template<int EPI>
__global__ __launch_bounds__(256, 3) void gemm3_kernel(const unsigned short* __restrict__ Ahi,
                                                       const unsigned short* __restrict__ Alo,
                                                       const unsigned short* __restrict__ Wt,
                                                       const float* __restrict__ bias,
                                                       const float* __restrict__ resid,
                                                       float* __restrict__ Cf,
                                                       unsigned short* __restrict__ Chi,
                                                       unsigned short* __restrict__ Clo,
                                                       int K, int N,
                                                       const int* __restrict__ dT)
{
    int T = *dT; int M = 8 * T;
    int m0 = blockIdx.y * 64;
    if (m0 >= M) return;
    int n0 = blockIdx.x * 128;

    __shared__ unsigned short As[2][64][40];    // [plane][m][k] pad->2-way max
    __shared__ unsigned short Bs[2][128][40];   // [plane][n][k]

    int t = threadIdx.x;
    int lane = t & 63, w = t >> 6;
    int wr = w >> 1, wc = w & 1;
    int quad = lane >> 4, l16 = lane & 15;

    f32x4v acc[2][4];
#pragma unroll
    for (int i = 0; i < 2; i++)
#pragma unroll
        for (int j = 0; j < 4; j++) acc[i][j] = (f32x4v){0.f, 0.f, 0.f, 0.f};

    int arow = t >> 2, ak = (t & 3) * 8;
    int ag = m0 + arow; if (ag > M - 1) ag = M - 1;
    const unsigned short* Ah = Ahi + (size_t)ag * K + ak;
    const unsigned short* Al = Alo + (size_t)ag * K + ak;

    int bn = t >> 1, bk = (t & 1) * 16;
    const unsigned short* Bh = Wt + (size_t)(n0 + bn) * K + bk;
    const unsigned short* Bl = Bh + (size_t)K * N;

    for (int k0 = 0; k0 < K; k0 += 32) {
        uint4 vah  = *(const uint4*)(Ah + k0);
        uint4 val  = *(const uint4*)(Al + k0);
        uint4 vbh0 = *(const uint4*)(Bh + k0);
        uint4 vbh1 = *(const uint4*)(Bh + k0 + 8);
        uint4 vbl0 = *(const uint4*)(Bl + k0);
        uint4 vbl1 = *(const uint4*)(Bl + k0 + 8);
        __syncthreads();
        *(uint4*)&As[0][arow][ak] = vah;
        *(uint4*)&As[1][arow][ak] = val;
        *(uint4*)&Bs[0][bn][bk]     = vbh0;
        *(uint4*)&Bs[0][bn][bk + 8] = vbh1;
        *(uint4*)&Bs[1][bn][bk]     = vbl0;
        *(uint4*)&Bs[1][bn][bk + 8] = vbl1;
        __syncthreads();

        bf16x8v afh[2], afl[2], bfh[4], bfl[4];
#pragma unroll
        for (int rb = 0; rb < 2; rb++) {
            int r = wr * 32 + rb * 16 + l16;
            afh[rb] = *(const bf16x8v*)&As[0][r][quad * 8];
            afl[rb] = *(const bf16x8v*)&As[1][r][quad * 8];
        }
#pragma unroll
        for (int cb = 0; cb < 4; cb++) {
            int c = wc * 64 + cb * 16 + l16;
            bfh[cb] = *(const bf16x8v*)&Bs[0][c][quad * 8];
            bfl[cb] = *(const bf16x8v*)&Bs[1][c][quad * 8];
        }
#pragma unroll
        for (int rb = 0; rb < 2; rb++)
#pragma unroll
            for (int cb = 0; cb < 4; cb++) {
                acc[rb][cb] = __builtin_amdgcn_mfma_f32_16x16x32_bf16(afl[rb], bfh[cb], acc[rb][cb], 0, 0, 0);
                acc[rb][cb] = __builtin_amdgcn_mfma_f32_16x16x32_bf16(afh[rb], bfl[cb], acc[rb][cb], 0, 0, 0);
                acc[rb][cb] = __builtin_amdgcn_mfma_f32_16x16x32_bf16(afh[rb], bfh[cb], acc[rb][cb], 0, 0, 0);
            }
    }

#pragma unroll
    for (int rb = 0; rb < 2; rb++) {
#pragma unroll
        for (int reg = 0; reg < 4; reg++) {
            int r = m0 + wr * 32 + rb * 16 + quad * 4 + reg;
            if (r >= M) continue;
#pragma unroll
            for (int cb = 0; cb < 4; cb++) {
                int c = n0 + wc * 64 + cb * 16 + l16;
                float v = acc[rb][cb][reg] + bias[c];
                if (EPI == 1) {
                    v = 0.5f * v * (1.0f + erff(v * 0.70710678118654752440f));
                    unsigned short h, l;
                    split_bf16(v, h, l);
                    Chi[(size_t)r * N + c] = h;
                    Clo[(size_t)r * N + c] = l;
                } else {
                    if (EPI == 2) v += resid[(size_t)r * N + c];
                    Cf[(size_t)r * N + c] = v;
                }
            }
        }
    }
}

// ---------------- flash attention, fp32 (register-lean), split-bf16 output ----------------
__global__ __launch_bounds__(256, 3) void attn_kernel(const float* __restrict__ qkv,
                                                      unsigned short* __restrict__ out_hi,
                                                      unsigned short* __restrict__ out_lo,
                                                      const int* __restrict__ dT)
{
    int T = *dT;
    int q0 = blockIdx.x * 64;
    if (q0 >= T) return;
    int bh = blockIdx.y;
    int b = bh / NHEADS, h = bh % NHEADS;

    __shared__ float Qs[64][68];
    __shared__ float KPs[64][68];
    __shared__ float Vs[64][68];
    __shared__ float m_s[64], l_s[64], al_s[64];

    int t = threadIdx.x;
    int tx = t & 15, ty = t >> 4;
    int lr = t >> 4, d4 = (t & 15) * 4;

#pragma unroll
    for (int rep = 0; rep < 4; rep++) {
        int row = rep*16 + lr;
        int gq = q0 + row;
        float4 v = make_float4(0.f,0.f,0.f,0.f);
        if (gq < T) v = *(const float4*)(qkv + (size_t)(b*T + gq)*1152 + h*64 + d4);
        *(float4*)&Qs[row][d4] = v;
    }
    if (t < 64) { m_s[t] = -INFINITY; l_s[t] = 0.f; }

    float acc[4][4];
#pragma unroll
    for (int i = 0; i < 4; i++)
#pragma unroll
        for (int j = 0; j < 4; j++) acc[i][j] = 0.f;

    int ntiles = (T + 63) >> 6;
    for (int kt = 0; kt < ntiles; kt++) {
        int kbase = kt * 64;
        __syncthreads();
#pragma unroll
        for (int rep = 0; rep < 4; rep++) {
            int row = rep*16 + lr;
            int gk = kbase + row;
            float4 a = make_float4(0.f,0.f,0.f,0.f), c = a;
            if (gk < T) {
                const float* base = qkv + (size_t)(b*T + gk)*1152 + h*64 + d4;
                a = *(const float4*)(base + 384);
                c = *(const float4*)(base + 768);
            }
            *(float4*)&KPs[row][d4] = a;
            *(float4*)&Vs[row][d4]  = c;
        }
        __syncthreads();

        float s[4][4];
#pragma unroll
        for (int i = 0; i < 4; i++)
#pragma unroll
            for (int j = 0; j < 4; j++) s[i][j] = 0.f;
#pragma unroll 2
        for (int dd = 0; dd < 64; dd += 4) {
            float4 qa[4], kb[4];
#pragma unroll
            for (int i = 0; i < 4; i++) qa[i] = *(const float4*)&Qs[ty*4+i][dd];
#pragma unroll
            for (int j = 0; j < 4; j++) kb[j] = *(const float4*)&KPs[tx*4+j][dd];
#pragma unroll
            for (int i = 0; i < 4; i++)
#pragma unroll
                for (int j = 0; j < 4; j++)
                    s[i][j] += qa[i].x*kb[j].x + qa[i].y*kb[j].y + qa[i].z*kb[j].z + qa[i].w*kb[j].w;
        }
        __syncthreads();
#pragma unroll
        for (int i = 0; i < 4; i++)
#pragma unroll
            for (int j = 0; j < 4; j++) {
                int gk = kbase + tx*4 + j;
                KPs[ty*4+i][tx*4+j] = (gk < T) ? s[i][j]*0.125f : -INFINITY;
            }
        __syncthreads();

        {
            int rr = t >> 2, sub = t & 3;
            float mx = -INFINITY;
#pragma unroll
            for (int kk = 0; kk < 16; kk++) mx = fmaxf(mx, KPs[rr][sub*16 + kk]);
            mx = fmaxf(mx, __shfl_xor(mx, 1, 64));
            mx = fmaxf(mx, __shfl_xor(mx, 2, 64));
            float mold = m_s[rr];
            float newm = fmaxf(mold, mx);
            float ps = 0.f;
#pragma unroll
            for (int kk = 0; kk < 16; kk++) {
                float p = __expf(KPs[rr][sub*16 + kk] - newm);
                KPs[rr][sub*16 + kk] = p;
                ps += p;
            }
            ps += __shfl_xor(ps, 1, 64);
            ps += __shfl_xor(ps, 2, 64);
            if (sub == 0) {
                float alpha = __expf(mold - newm);
                l_s[rr] = l_s[rr]*alpha + ps;
                m_s[rr] = newm;
                al_s[rr] = alpha;
            }
        }
        __syncthreads();

#pragma unroll
        for (int i = 0; i < 4; i++) {
            float alpha = al_s[ty*4 + i];
#pragma unroll
            for (int j = 0; j < 4; j++) acc[i][j] *= alpha;
        }
#pragma unroll 2
        for (int kk = 0; kk < 64; kk += 4) {
            float4 pv[4], vb[4];
#pragma unroll
            for (int i = 0; i < 4; i++) pv[i] = *(const float4*)&KPs[ty*4+i][kk];
#pragma unroll
            for (int m = 0; m < 4; m++) vb[m] = *(const float4*)&Vs[kk+m][tx*4];
#pragma unroll
            for (int i = 0; i < 4; i++) {
                acc[i][0] += pv[i].x*vb[0].x + pv[i].y*vb[1].x + pv[i].z*vb[2].x + pv[i].w*vb[3].x;
                acc[i][1] += pv[i].x*vb[0].y + pv[i].y*vb[1].y + pv[i].z*vb[2].y + pv[i].w*vb[3].y;
                acc[i][2] += pv[i].x*vb[0].z + pv[i].y*vb[1].z + pv[i].z*vb[2].z + pv[i].w*vb[3].z;
                acc[i][3] += pv[i].x*vb[0].w + pv[i].y*vb[1].w + pv[i].z*vb[2].w + pv[i].w*vb[3].w;
            }
        }
    }
#pragma unroll
    for (int i = 0; i < 4; i++) {
        int gq = q0 + ty*4 + i;
        if (gq < T) {
            float inv = 1.0f / l_s[ty*4 + i];
            size_t o = (size_t)(b*T + gq)*384 + h*64 + tx*4;
            ushort4 vh, vl;
            unsigned short hh, ll;
            split_bf16(acc[i][0]*inv, hh, ll); vh.x = hh; vl.x = ll;
            split_bf16(acc[i][1]*inv, hh, ll); vh.y = hh; vl.y = ll;
            split_bf16(acc[i][2]*inv, hh, ll); vh.z = hh; vl.z = ll;
            split_bf16(acc[i][3]*inv, hh, ll); vh.w = hh; vl.w = ll;
            *(ushort4*)(out_hi + o) = vh;
            *(ushort4*)(out_lo + o) = vl;
        }
    }
}

// ---------------- cls-row stats: entropy + raw importance per head ----------------
__global__ __launch_bounds__(256) void cls_stats_kernel(const float* __restrict__ qkv,
                                                        float* __restrict__ raw_h,
                                                        float* __restrict__ ent,
                                                        const int* __restrict__ dT)
{
    int T = *dT;
    int bh = blockIdx.x;
    int b = bh / NHEADS, h = bh % NHEADS;
    __shared__ float q0s[64];
    __shared__ float logit[TMAXT];
    __shared__ float red[8];
    int t = threadIdx.x;
    if (t < 64) q0s[t] = qkv[(size_t)(b*T)*1152 + h*64 + t];
    __syncthreads();
    float lmax = -INFINITY;
    for (int j = t; j < T; j += 256) {
        const float* kp = qkv + (size_t)(b*T + j)*1152 + 384 + h*64;
        float dot = 0.f;
#pragma unroll
        for (int d = 0; d < 64; d += 4) {
            float4 kk = *(const float4*)(kp + d);
            dot += q0s[d]*kk.x + q0s[d+1]*kk.y + q0s[d+2]*kk.z + q0s[d+3]*kk.w;
        }
        float lg = dot * 0.125f;
        logit[j] = lg;
        lmax = fmaxf(lmax, lg);
    }
#pragma unroll
    for (int off = 32; off; off >>= 1) lmax = fmaxf(lmax, __shfl_xor(lmax, off, 64));
    if ((t & 63) == 0) red[t >> 6] = lmax;
    __syncthreads();
    float gmax = fmaxf(fmaxf(red[0], red[1]), fmaxf(red[2], red[3]));
    __syncthreads();
    float psum = 0.f;
    for (int j = t; j < T; j += 256) psum += expf(logit[j] - gmax);
#pragma unroll
    for (int off = 32; off; off >>= 1) psum += __shfl_xor(psum, off, 64);
    if ((t & 63) == 0) red[4 + (t >> 6)] = psum;
    __syncthreads();
    float inv = 1.0f / (red[4] + red[5] + red[6] + red[7]);
    float entp = 0.f;
    for (int j = t; j < T; j += 256) {
        float p = expf(logit[j] - gmax) * inv;
        entp += -p * logf(p + 1e-6f);
        if (j >= 1) {
            const float* vp = qkv + (size_t)(b*T + j)*1152 + 768 + h*64;
            float vn = 0.f;
#pragma unroll
            for (int d = 0; d < 64; d += 4) {
                float4 vx = *(const float4*)(vp + d);
                vn += vx.x*vx.x + vx.y*vx.y + vx.z*vx.z + vx.w*vx.w;
            }
            raw_h[(size_t)bh*576 + (j - 1)] = p * sqrtf(vn);
        }
    }
#pragma unroll
    for (int off = 32; off; off >>= 1) entp += __shfl_xor(entp, off, 64);
    __syncthreads();
    if ((t & 63) == 0) red[t >> 6] = entp;
    __syncthreads();
    if (t == 0) ent[bh] = red[0] + red[1] + red[2] + red[3];
}

// ---------------- prune decision (single block) ----------------
__global__ __launch_bounds__(256) void decide_kernel(const float* __restrict__ raw_h,
                                                     const float* __restrict__ ent,
                                                     float* __restrict__ prev_mass,
                                                     int* __restrict__ keep,
                                                     const int* __restrict__ dT,
                                                     int* __restrict__ dTnext,
                                                     int layer)
{
    int t = threadIdx.x;
    int T = *dT, N = T - 1;
    __shared__ float massS[8];
    __shared__ float scores[NMAXT];
    __shared__ int   keptFlag[NMAXT];
    __shared__ int   nnS;
    if (N <= 16) {
        for (int i = t; i < T; i += 256) keep[i] = i;
        if (t == 0) *dTnext = T;
        return;
    }
    {
        int b = t >> 5, lane = t & 31;
        float s = 0.f;
        for (int h = 0; h < 6; h++)
            for (int j = lane; j < N; j += 32)
                s += raw_h[(size_t)(b*6 + h)*576 + j];
#pragma unroll
        for (int off = 16; off; off >>= 1) s += __shfl_xor(s, off, 64);
        if (lane == 0) massS[b] = s;
    }
    __syncthreads();
    for (int j = t; j < N; j += 256) {
        float s = 0.f;
        for (int b = 0; b < 8; b++) {
            float rb = 0.f;
            for (int h = 0; h < 6; h++) rb += raw_h[(size_t)(b*6 + h)*576 + j];
            s += rb / (massS[b] + 1e-6f);
        }
        scores[j] = s * 0.125f;
    }
    __syncthreads();
    if (t == 0) {
        float es = 0.f;
        for (int i = 0; i < 48; i++) es += ent[i];
        float rho_mean = es / 48.0f / logf((float)T);
        int Nn;
        if (layer == 0) {
            Nn = N;
        } else {
            float dm = 0.f;
            for (int b = 0; b < 8; b++)
                dm += fabsf(massS[b] - prev_mass[b]) / (prev_mass[b] + 1e-6f);
            dm *= 0.125f;
            float kr = 1.0f - 0.1f * (rho_mean + dm);
            kr = fminf(fmaxf(kr, 0.0f), 1.0f);
            Nn = (int)((double)N * (double)kr);
            if (Nn < 16) Nn = 16;
        }
        nnS = Nn;
        *dTnext = Nn + 1;
    }
    __syncthreads();
    if (t < 8) prev_mass[t] = massS[t];
    int Nn = nnS;
    if (Nn < N) {
        for (int j = t; j < N; j += 256) {
            float sj = scores[j];
            int cnt = 0;
            for (int j2 = 0; j2 < N; j2++) {
                float s2 = scores[j2];
                cnt += (s2 > sj) || (s2 == sj && j2 < j);
            }
            keptFlag[j] = (cnt < Nn) ? 1 : 0;
        }
        __syncthreads();
        if (t == 0) {
            keep[0] = 0;
            int pos = 1;
            for (int j = 0; j < N; j++)
                if (keptFlag[j]) keep[pos++] = j + 1;
        }
    } else {
        for (int i = t; i < T; i += 256) keep[i] = i;
    }
}

// ---------------- gather pruned tokens (ping-pong) ----------------
__global__ __launch_bounds__(128) void gather_kernel(const float* __restrict__ src,
                                                     float* __restrict__ dst,
                                                     const int* __restrict__ keep,
                                                     const int* __restrict__ dT,
                                                     const int* __restrict__ dTnext)
{
    int Tn = *dTnext;
    int ti = blockIdx.x;
    if (ti >= Tn) return;
    int To = *dT;
    int b = blockIdx.y;
    const float* s = src + (size_t)(b*To + keep[ti]) * 384;
    float* d = dst + (size_t)(b*Tn + ti) * 384;
    int t = threadIdx.x;
    if (t < 96) ((float4*)d)[t] = ((const float4*)s)[t];
}

__global__ void bump_kernel(int* dT, const int* dTnext) { *dT = *dTnext; }

// ---------------- final LN on cls rows (fp32) ----------------
__global__ __launch_bounds__(64) void lnf_kernel(const float* __restrict__ xin,
                                                 const float* __restrict__ sc,
                                                 const float* __restrict__ bi,
                                                 float* __restrict__ xf,
                                                 const int* __restrict__ dT)
{
    int T = *dT;
    int b = blockIdx.x;
    int lane = threadIdx.x;
    const float* xr = xin + (size_t)(b*T) * 384;
    float v[6];
#pragma unroll
    for (int i = 0; i < 6; i++) v[i] = xr[lane + 64*i];
    float s = v[0]+v[1]+v[2]+v[3]+v[4]+v[5];
#pragma unroll
    for (int off = 32; off; off >>= 1) s += __shfl_xor(s, off, 64);
    float mean = s * (1.0f/384.0f);
    float q = 0.f;
#pragma unroll
    for (int i = 0; i < 6; i++) { float d = v[i]-mean; q += d*d; }
#pragma unroll
    for (int off = 32; off; off >>= 1) q += __shfl_xor(q, off, 64);
    float rstd = 1.0f / sqrtf(q * (1.0f/384.0f) + 1e-5f);
#pragma unroll
    for (int i = 0; i < 6; i++) {
        int d = lane + 64*i;
        xf[(size_t)b*384 + d] = (v[i]-mean) * rstd * sc[d] + bi[d];
    }
}

// ---------------- head ----------------
__global__ __launch_bounds__(256) void head_kernel(const float* __restrict__ xf,
                                                   const float* __restrict__ hw,
                                                   const float* __restrict__ hb,
                                                   float* __restrict__ out)
{
    int idx = blockIdx.x * 256 + threadIdx.x;
    if (idx >= 8000) return;
    int b = idx / 1000, n = idx - b*1000;
    const float* xr = xf + (size_t)b*384;
    float s = hb[n];
#pragma unroll 4
    for (int k = 0; k < 384; k++) s += xr[k] * hw[(size_t)k*1000 + n];
    out[idx] = s;
}

// ---------------- launch ----------------
extern "C" void kernel_launch(void* const* d_in, const int* in_sizes, int n_in,
                              void* d_out, int out_size, void* d_ws, size_t ws_size,
                              hipStream_t stream)
{
    (void)in_sizes; (void)n_in; (void)out_size; (void)ws_size;
    const float* x       = (const float*)d_in[0];
    const float* patch_w = (const float*)d_in[1];
    const float* patch_b = (const float*)d_in[2];
    const float* cls_tok = (const float*)d_in[3];
    const float* pos     = (const float*)d_in[4];
    const float* ln1_s   = (const float*)d_in[5];
    const float* ln1_b   = (const float*)d_in[6];
    const float* qkv_w   = (const float*)d_in[7];
    const float* qkv_b   = (const float*)d_in[8];
    const float* proj_w  = (const float*)d_in[9];
    const float* proj_b  = (const float*)d_in[10];
    const float* ln2_s   = (const float*)d_in[11];
    const float* ln2_b   = (const float*)d_in[12];
    const float* fc1_w   = (const float*)d_in[13];
    const float* fc1_b   = (const float*)d_in[14];
    const float* fc2_w   = (const float*)d_in[15];
    const float* fc2_b   = (const float*)d_in[16];
    const float* norm_s  = (const float*)d_in[17];
    const float* norm_b  = (const float*)d_in[18];
    const float* head_w  = (const float*)d_in[19];
    const float* head_b  = (const float*)d_in[20];
    float* out = (float*)d_out;
    float* ws  = (float*)d_ws;

    float* x0   = ws + X0_OFF;
    float* x1   = ws + X1_OFF;
    float* qkvb = ws + QKV_OFF;
    float* rawh = ws + RAWH_OFF;
    float* entb = ws + ENT_OFF;
    float* pm   = ws + PM_OFF;
    float* xf   = ws + XF_OFF;
    int*   keep = (int*)(ws + KEEP_OFF);
    int*   dT   = (int*)(ws + T_OFF);
    int*   dTn  = (int*)(ws + TN_OFF);

    unsigned short* xn_hi = (unsigned short*)(ws + XN_OFF);
    unsigned short* xn_lo = xn_hi + XSZ;
    unsigned short* ao_hi = (unsigned short*)(ws + AO_OFF);
    unsigned short* ao_lo = ao_hi + XSZ;
    unsigned short* hb_hi = (unsigned short*)(ws + QKV_OFF);   // aliases qkvb (dead by fc1)
    unsigned short* hb_lo = hb_hi + HBELEM;
    unsigned short* wspl  = (unsigned short*)(ws + WSPL_OFF);

    prologue_kernel<<<8, 128, 0, stream>>>(cls_tok, pos, x0, dT);
    patch_kernel<<<dim3(6, 72), 256, 0, stream>>>(x, patch_w, patch_b, pos, x0);

    float* bufs[2] = { x0, x1 };
    for (int l = 0; l < LAYERS; l++) {
        float* src = bufs[l & 1];
        float* dst = bufs[(l + 1) & 1];
        wsplit_kernel<<<dim3(576, 4), 256, 0, stream>>>(
            qkv_w + (size_t)l*384*1152, proj_w + (size_t)l*384*384,
            fc1_w + (size_t)l*384*1536, fc2_w + (size_t)l*1536*384, wspl);
        ln_kernel<<<1154, 256, 0, stream>>>(src, ln1_s + l*384, ln1_b + l*384, xn_hi, xn_lo, dT);
        gemm3_kernel<0><<<dim3(9, 73), 256, 0, stream>>>(
            xn_hi, xn_lo, wspl + W_QKV, qkv_b + l*1152, nullptr, qkvb, nullptr, nullptr, 384, 1152, dT);
        attn_kernel<<<dim3(10, 48), 256, 0, stream>>>(qkvb, ao_hi, ao_lo, dT);
        cls_stats_kernel<<<48, 256, 0, stream>>>(qkvb, rawh, entb, dT);
        gemm3_kernel<2><<<dim3(3, 73), 256, 0, stream>>>(
            ao_hi, ao_lo, wspl + W_PROJ, proj_b + l*384, src, src, nullptr, nullptr, 384, 384, dT);
        ln_kernel<<<1154, 256, 0, stream>>>(src, ln2_s + l*384, ln2_b + l*384, xn_hi, xn_lo, dT);
        gemm3_kernel<1><<<dim3(12, 73), 256, 0, stream>>>(
            xn_hi, xn_lo, wspl + W_FC1, fc1_b + l*1536, nullptr, nullptr, hb_hi, hb_lo, 384, 1536, dT);
        gemm3_kernel<2><<<dim3(3, 73), 256, 0, stream>>>(
            hb_hi, hb_lo, wspl + W_FC2, fc2_b + l*384, src, src, nullptr, nullptr, 1536, 384, dT);
        decide_kernel<<<1, 256, 0, stream>>>(rawh, entb, pm, keep, dT, dTn, l);
        gather_kernel<<<dim3(577, 8), 128, 0, stream>>>(src, dst, keep, dT, dTn);
        bump_kernel<<<1, 1, 0, stream>>>(dT, dTn);
    }
    lnf_kernel<<<8, 64, 0, stream>>>(bufs[0], norm_s, norm_b, xf, dT);
    head_kernel<<<32, 256, 0, stream>>>(xf, head_w, head_b, out);
}

// Round 4
// 3056.527 us; speedup vs baseline: 1.9314x; 1.1360x over previous
//
#include <hip/hip_runtime.h>
#include <math.h>

#define NHEADS 6
#define DMODEL 384
#define TMAXT  577
#define NMAXT  576
#define BATCH  8
#define LAYERS 12

typedef __attribute__((ext_vector_type(8))) short bf16x8v;
typedef __attribute__((ext_vector_type(4))) float f32x4v;

// ---------------- workspace layout (float indices) ----------------
#define XSZ      (8ull*577*384)            // 1,772,544
#define X0_OFF   0ull
#define X1_OFF   (X0_OFF + XSZ)
#define XN_OFF   (X1_OFF + XSZ)            // xn split planes: 2 x XSZ ushort = XSZ floats
#define QKV_OFF  (XN_OFF + XSZ)
#define QKV_SZ   (8ull*577*1152)           // 5,317,632 floats
#define AO_OFF   (QKV_OFF + QKV_SZ)        // ao split planes: 2 x XSZ ushort = XSZ floats
#define HBELEM   (8ull*577*1536)           // 7,090,176 elements
#define RAWH_OFF (AO_OFF + XSZ)            // 8*6*576
#define RAWH_SZ  (8ull*6*576)
#define ENT_OFF  (RAWH_OFF + RAWH_SZ)      // 48 (pad 64)
#define PM_OFF   (ENT_OFF + 64)            // 8 (pad 64)
#define XF_OFF   (PM_OFF + 64)             // 8*384
#define KEEP_OFF (XF_OFF + 8*384)          // 577 ints (pad 640)
#define T_OFF    (KEEP_OFF + 640)
#define TN_OFF   (T_OFF + 16)
#define WSPL_OFF (TN_OFF + 16)             // weight splits: 3,538,944 ushort

// weight split sub-offsets (ushort units inside WSPL)
#define W_QKV   0ull
#define W_PROJ  884736ull
#define W_FC1   1179648ull
#define W_FC2   2359296ull

// ---------------- bf16 split helpers ----------------
__device__ inline unsigned short rne_bf16(float f) {
    unsigned int u = __float_as_uint(f);
    u += 0x7FFFu + ((u >> 16) & 1u);
    return (unsigned short)(u >> 16);
}
__device__ inline float bf16_to_f(unsigned short h) {
    return __uint_as_float(((unsigned int)h) << 16);
}
__device__ inline void split_bf16(float x, unsigned short& h, unsigned short& l) {
    h = rne_bf16(x);
    l = rne_bf16(x - bf16_to_f(h));
}

// ---------------- prologue: cls row + pos, init T ----------------
__global__ __launch_bounds__(128) void prologue_kernel(const float* __restrict__ cls_tok,
                                                       const float* __restrict__ pos,
                                                       float* __restrict__ x0,
                                                       int* __restrict__ dT)
{
    int b = blockIdx.x;
    for (int d = threadIdx.x; d < 384; d += 128)
        x0[(size_t)b*577*384 + d] = cls_tok[d] + pos[d];
    if (b == 0 && threadIdx.x == 0) *dT = 577;
}

// ---------------- patch embed GEMM (fp32 vector) ----------------
__global__ __launch_bounds__(256) void patch_kernel(const float* __restrict__ x,
                                                    const float* __restrict__ pw,
                                                    const float* __restrict__ pb,
                                                    const float* __restrict__ pos,
                                                    float* __restrict__ x0)
{
    const int K = 768, Nc = 384;
    int row0 = blockIdx.y * 64, col0 = blockIdx.x * 64;
    __shared__ float As[16][68];
    __shared__ float Bs[16][68];
    int t = threadIdx.x;
    int tx = t & 15, ty = t >> 4;
    int am = t >> 2, ak = (t & 3) * 4;
    int bk = t >> 4, bn = (t & 15) * 4;
    float acc[4][4];
#pragma unroll
    for (int i = 0; i < 4; i++)
#pragma unroll
        for (int j = 0; j < 4; j++) acc[i][j] = 0.f;

    int arow = row0 + am;
    int b  = arow / 576, tt = arow % 576;
    int g1 = tt / 24,    g2 = tt % 24;
    const float* xr = x + ((size_t)(b*3)*384 + g1*16)*384 + g2*16;
    const float* Wp = pw + (size_t)bk*Nc + col0 + bn;

    for (int k0 = 0; k0 < K; k0 += 16) {
        int k = k0 + ak;
        int c = k >> 8, rr = k & 255, p1 = rr >> 4, p2 = rr & 15;
        float4 av = *(const float4*)(xr + ((size_t)c*384 + p1)*384 + p2);
        float4 wv = *(const float4*)(Wp + (size_t)k0*Nc);
        __syncthreads();
        As[ak+0][am] = av.x; As[ak+1][am] = av.y; As[ak+2][am] = av.z; As[ak+3][am] = av.w;
        *(float4*)&Bs[bk][bn] = wv;
        __syncthreads();
#pragma unroll
        for (int kk = 0; kk < 16; kk++) {
            float4 a4 = *(const float4*)&As[kk][ty*4];
            float4 b4 = *(const float4*)&Bs[kk][tx*4];
            acc[0][0] += a4.x*b4.x; acc[0][1] += a4.x*b4.y; acc[0][2] += a4.x*b4.z; acc[0][3] += a4.x*b4.w;
            acc[1][0] += a4.y*b4.x; acc[1][1] += a4.y*b4.y; acc[1][2] += a4.y*b4.z; acc[1][3] += a4.y*b4.w;
            acc[2][0] += a4.z*b4.x; acc[2][1] += a4.z*b4.y; acc[2][2] += a4.z*b4.z; acc[2][3] += a4.z*b4.w;
            acc[3][0] += a4.w*b4.x; acc[3][1] += a4.w*b4.y; acc[3][2] += a4.w*b4.z; acc[3][3] += a4.w*b4.w;
        }
    }
#pragma unroll
    for (int i = 0; i < 4; i++) {
        int r = row0 + ty*4 + i;
        int bb = r / 576, ttt = r % 576;
#pragma unroll
        for (int j = 0; j < 4; j++) {
            int c = col0 + tx*4 + j;
            float v = acc[i][j] + pb[c] + pos[(size_t)(1 + ttt)*384 + c];
            x0[(size_t)(bb*577 + 1 + ttt)*384 + c] = v;
        }
    }
}

// ---------------- weight split+transpose: W[K][N] fp32 -> Wt_hi/lo [N][K] bf16 ----------------
__global__ __launch_bounds__(256) void wsplit_kernel(const float* __restrict__ qkvw,
                                                     const float* __restrict__ projw,
                                                     const float* __restrict__ fc1w,
                                                     const float* __restrict__ fc2w,
                                                     unsigned short* __restrict__ wspl)
{
    int mat = blockIdx.y;
    const float* W; int K, N; size_t off;
    if (mat == 0)      { W = qkvw; K = 384;  N = 1152; off = W_QKV; }
    else if (mat == 1) { W = projw; K = 384; N = 384;  off = W_PROJ; }
    else if (mat == 2) { W = fc1w; K = 384;  N = 1536; off = W_FC1; }
    else               { W = fc2w; K = 1536; N = 384;  off = W_FC2; }
    int ktiles = K >> 5, ntiles = N >> 5;
    int tid = blockIdx.x;
    if (tid >= ktiles * ntiles) return;
    int tk = tid % ktiles, tn = tid / ktiles;
    int k0 = tk << 5, n0 = tn << 5;
    __shared__ unsigned short Th[32][34];
    __shared__ unsigned short Tl[32][34];
    int t = threadIdx.x;
    {
        int row = t >> 3, c4 = (t & 7) << 2;
        float4 wv = *(const float4*)(W + (size_t)(k0 + row) * N + n0 + c4);
        unsigned short h, l;
        split_bf16(wv.x, h, l); Th[c4+0][row] = h; Tl[c4+0][row] = l;
        split_bf16(wv.y, h, l); Th[c4+1][row] = h; Tl[c4+1][row] = l;
        split_bf16(wv.z, h, l); Th[c4+2][row] = h; Tl[c4+2][row] = l;
        split_bf16(wv.w, h, l); Th[c4+3][row] = h; Tl[c4+3][row] = l;
    }
    __syncthreads();
    {
        int n = t >> 3, k4 = (t & 7) << 2;
        unsigned short* dh = wspl + off + (size_t)(n0 + n) * K + k0 + k4;
        unsigned short* dl = dh + (size_t)K * N;
        ushort4 oh = make_ushort4(Th[n][k4], Th[n][k4+1], Th[n][k4+2], Th[n][k4+3]);
        ushort4 ol = make_ushort4(Tl[n][k4], Tl[n][k4+1], Tl[n][k4+2], Tl[n][k4+3]);
        *(ushort4*)dh = oh;
        *(ushort4*)dl = ol;
    }
}

// ---------------- LayerNorm -> split bf16 planes ----------------
__global__ __launch_bounds__(256) void ln_kernel(const float* __restrict__ xin,
                                                 const float* __restrict__ sc,
                                                 const float* __restrict__ bi,
                                                 unsigned short* __restrict__ yhi,
                                                 unsigned short* __restrict__ ylo,
                                                 const int* __restrict__ dT)
{
    int T = *dT;
    int M = 8 * T;
    int r = blockIdx.x * 4 + (threadIdx.x >> 6);
    if (r >= M) return;
    int lane = threadIdx.x & 63;
    const float* xr = xin + (size_t)r * 384;
    float v[6];
#pragma unroll
    for (int i = 0; i < 6; i++) v[i] = xr[lane + 64*i];
    float s = v[0]+v[1]+v[2]+v[3]+v[4]+v[5];
#pragma unroll
    for (int off = 32; off; off >>= 1) s += __shfl_xor(s, off, 64);
    float mean = s * (1.0f/384.0f);
    float q = 0.f;
#pragma unroll
    for (int i = 0; i < 6; i++) { float d = v[i]-mean; q += d*d; }
#pragma unroll
    for (int off = 32; off; off >>= 1) q += __shfl_xor(q, off, 64);
    float rstd = 1.0f / sqrtf(q * (1.0f/384.0f) + 1e-5f);
#pragma unroll
    for (int i = 0; i < 6; i++) {
        int d = lane + 64*i;
        float y = (v[i]-mean) * rstd * sc[d] + bi[d];
        unsigned short h, l;
        split_bf16(y, h, l);
        yhi[(size_t)r*384 + d] = h;
        ylo[(size_t)r*384 + d] = l;
    }
}

// ---------------- bf16x3 MFMA GEMM: C = A*W + bias (+gelu / +resid) ----------------
template<int EPI>
__global__ __launch_bounds__(256, 3) void gemm3_kernel(const unsigned short* __restrict__ Ahi,
                                                       const unsigned short* __restrict__ Alo,
                                                       const unsigned short* __restrict__ Wt,
                                                       const float* __restrict__ bias,
                                                       const float* __restrict__ resid,
                                                       float* __restrict__ Cf,
                                                       unsigned short* __restrict__ Chi,
                                                       unsigned short* __restrict__ Clo,
                                                       int K, int N,
                                                       const int* __restrict__ dT)
{
    int T = *dT; int M = 8 * T;
    int m0 = blockIdx.y * 64;
    if (m0 >= M) return;
    int n0 = blockIdx.x * 128;

    __shared__ unsigned short As[2][64][40];
    __shared__ unsigned short Bs[2][128][40];

    int t = threadIdx.x;
    int lane = t & 63, w = t >> 6;
    int wr = w >> 1, wc = w & 1;
    int quad = lane >> 4, l16 = lane & 15;

    f32x4v acc[2][4];
#pragma unroll
    for (int i = 0; i < 2; i++)
#pragma unroll
        for (int j = 0; j < 4; j++) acc[i][j] = (f32x4v){0.f, 0.f, 0.f, 0.f};

    int arow = t >> 2, ak = (t & 3) * 8;
    int ag = m0 + arow; if (ag > M - 1) ag = M - 1;
    const unsigned short* Ah = Ahi + (size_t)ag * K + ak;
    const unsigned short* Al = Alo + (size_t)ag * K + ak;

    int bn = t >> 1, bk = (t & 1) * 16;
    const unsigned short* Bh = Wt + (size_t)(n0 + bn) * K + bk;
    const unsigned short* Bl = Bh + (size_t)K * N;

    for (int k0 = 0; k0 < K; k0 += 32) {
        uint4 vah  = *(const uint4*)(Ah + k0);
        uint4 val  = *(const uint4*)(Al + k0);
        uint4 vbh0 = *(const uint4*)(Bh + k0);
        uint4 vbh1 = *(const uint4*)(Bh + k0 + 8);
        uint4 vbl0 = *(const uint4*)(Bl + k0);
        uint4 vbl1 = *(const uint4*)(Bl + k0 + 8);
        __syncthreads();
        *(uint4*)&As[0][arow][ak] = vah;
        *(uint4*)&As[1][arow][ak] = val;
        *(uint4*)&Bs[0][bn][bk]     = vbh0;
        *(uint4*)&Bs[0][bn][bk + 8] = vbh1;
        *(uint4*)&Bs[1][bn][bk]     = vbl0;
        *(uint4*)&Bs[1][bn][bk + 8] = vbl1;
        __syncthreads();

        bf16x8v afh[2], afl[2], bfh[4], bfl[4];
#pragma unroll
        for (int rb = 0; rb < 2; rb++) {
            int r = wr * 32 + rb * 16 + l16;
            afh[rb] = *(const bf16x8v*)&As[0][r][quad * 8];
            afl[rb] = *(const bf16x8v*)&As[1][r][quad * 8];
        }
#pragma unroll
        for (int cb = 0; cb < 4; cb++) {
            int c = wc * 64 + cb * 16 + l16;
            bfh[cb] = *(const bf16x8v*)&Bs[0][c][quad * 8];
            bfl[cb] = *(const bf16x8v*)&Bs[1][c][quad * 8];
        }
#pragma unroll
        for (int rb = 0; rb < 2; rb++)
#pragma unroll
            for (int cb = 0; cb < 4; cb++) {
                acc[rb][cb] = __builtin_amdgcn_mfma_f32_16x16x32_bf16(afl[rb], bfh[cb], acc[rb][cb], 0, 0, 0);
                acc[rb][cb] = __builtin_amdgcn_mfma_f32_16x16x32_bf16(afh[rb], bfl[cb], acc[rb][cb], 0, 0, 0);
                acc[rb][cb] = __builtin_amdgcn_mfma_f32_16x16x32_bf16(afh[rb], bfh[cb], acc[rb][cb], 0, 0, 0);
            }
    }

#pragma unroll
    for (int rb = 0; rb < 2; rb++) {
#pragma unroll
        for (int reg = 0; reg < 4; reg++) {
            int r = m0 + wr * 32 + rb * 16 + quad * 4 + reg;
            if (r >= M) continue;
#pragma unroll
            for (int cb = 0; cb < 4; cb++) {
                int c = n0 + wc * 64 + cb * 16 + l16;
                float v = acc[rb][cb][reg] + bias[c];
                if (EPI == 1) {
                    v = 0.5f * v * (1.0f + erff(v * 0.70710678118654752440f));
                    unsigned short h, l;
                    split_bf16(v, h, l);
                    Chi[(size_t)r * N + c] = h;
                    Clo[(size_t)r * N + c] = l;
                } else {
                    if (EPI == 2) v += resid[(size_t)r * N + c];
                    Cf[(size_t)r * N + c] = v;
                }
            }
        }
    }
}

// ---------------- flash attention v3: MFMA (split-bf16) QK^T and PV, fp32 softmax ----------------
// Q fragments in registers; K split [tok][d]; V split transposed [d][tok]; P overwrites K buffer.
__global__ __launch_bounds__(256, 3) void attn_kernel(const float* __restrict__ qkv,
                                                      unsigned short* __restrict__ out_hi,
                                                      unsigned short* __restrict__ out_lo,
                                                      const int* __restrict__ dT)
{
    int T = *dT;
    int q0 = blockIdx.x * 64;
    if (q0 >= T) return;
    int bh = blockIdx.y;
    int b = bh / NHEADS, h = bh % NHEADS;

    __shared__ unsigned short Ks[2][64][72];   // K tile [tok][d]; later P [q][ktok]
    __shared__ unsigned short Vt[2][64][72];   // V^T tile [d][tok]
    __shared__ float Ss[64][66];               // S scores fp32
    __shared__ float m_s[64], l_s[64], al_s[64];

    int t = threadIdx.x;
    int lane = t & 63, w = t >> 6;
    int l16 = lane & 15, quad = lane >> 4;

    // Q fragments (A-operand layout: m=l16 -> q=w*16+l16, k=quad*8+j) in registers
    bf16x8v qf[2][2];   // [kstep][hi/lo]
    {
        int gq = q0 + w * 16 + l16;
        bool valid = gq < T;
        const float* qp = qkv + (size_t)(b * T + (valid ? gq : 0)) * 1152 + h * 64;
#pragma unroll
        for (int ks = 0; ks < 2; ks++) {
            int dbase = ks * 32 + quad * 8;
            float4 f0 = valid ? *(const float4*)(qp + dbase)     : make_float4(0.f,0.f,0.f,0.f);
            float4 f1 = valid ? *(const float4*)(qp + dbase + 4) : make_float4(0.f,0.f,0.f,0.f);
            float f[8] = {f0.x, f0.y, f0.z, f0.w, f1.x, f1.y, f1.z, f1.w};
            bf16x8v hi, lo;
#pragma unroll
            for (int j = 0; j < 8; j++) {
                unsigned short hh, ll;
                split_bf16(f[j], hh, ll);
                hi[j] = (short)hh; lo[j] = (short)ll;
            }
            qf[ks][0] = hi; qf[ks][1] = lo;
        }
    }
    if (t < 64) { m_s[t] = -INFINITY; l_s[t] = 0.f; }

    f32x4v oacc[4];
#pragma unroll
    for (int cb = 0; cb < 4; cb++) oacc[cb] = (f32x4v){0.f, 0.f, 0.f, 0.f};

    int ntiles = (T + 63) >> 6;
    for (int kt = 0; kt < ntiles; kt++) {
        int kbase = kt * 64;
        __syncthreads();   // prior tile's P/V fully consumed (covers init on kt=0)

        // stage K (split, [tok][d]) and V (split, transposed [d][tok])
        {
            int gk = kbase + lane;          // token = lane
            int sd0 = w * 16;               // 16 d-values per thread
            bool valid = gk < T;
            const float* kp = qkv + (size_t)(b * T + (valid ? gk : 0)) * 1152 + 384 + h * 64 + sd0;
            const float* vp = kp + 384;
#pragma unroll
            for (int c = 0; c < 4; c++) {
                float4 kv = valid ? *(const float4*)(kp + c * 4) : make_float4(0.f,0.f,0.f,0.f);
                float4 vv = valid ? *(const float4*)(vp + c * 4) : make_float4(0.f,0.f,0.f,0.f);
                unsigned short hh, ll;
                ushort4 kh, kl;
                split_bf16(kv.x, hh, ll); kh.x = hh; kl.x = ll;
                split_bf16(kv.y, hh, ll); kh.y = hh; kl.y = ll;
                split_bf16(kv.z, hh, ll); kh.z = hh; kl.z = ll;
                split_bf16(kv.w, hh, ll); kh.w = hh; kl.w = ll;
                *(ushort4*)&Ks[0][lane][sd0 + c*4] = kh;
                *(ushort4*)&Ks[1][lane][sd0 + c*4] = kl;
                split_bf16(vv.x, hh, ll); Vt[0][sd0 + c*4 + 0][lane] = hh; Vt[1][sd0 + c*4 + 0][lane] = ll;
                split_bf16(vv.y, hh, ll); Vt[0][sd0 + c*4 + 1][lane] = hh; Vt[1][sd0 + c*4 + 1][lane] = ll;
                split_bf16(vv.z, hh, ll); Vt[0][sd0 + c*4 + 2][lane] = hh; Vt[1][sd0 + c*4 + 2][lane] = ll;
                split_bf16(vv.w, hh, ll); Vt[0][sd0 + c*4 + 3][lane] = hh; Vt[1][sd0 + c*4 + 3][lane] = ll;
            }
        }
        __syncthreads();

        // S = Q K^T (B-operand: n=l16 -> tok col, k=quad*8+j -> d)
#pragma unroll
        for (int cb = 0; cb < 4; cb++) {
            f32x4v sacc = (f32x4v){0.f, 0.f, 0.f, 0.f};
#pragma unroll
            for (int ks = 0; ks < 2; ks++) {
                bf16x8v bhi = *(const bf16x8v*)&Ks[0][cb*16 + l16][ks*32 + quad*8];
                bf16x8v blo = *(const bf16x8v*)&Ks[1][cb*16 + l16][ks*32 + quad*8];
                sacc = __builtin_amdgcn_mfma_f32_16x16x32_bf16(qf[ks][1], bhi, sacc, 0, 0, 0);
                sacc = __builtin_amdgcn_mfma_f32_16x16x32_bf16(qf[ks][0], blo, sacc, 0, 0, 0);
                sacc = __builtin_amdgcn_mfma_f32_16x16x32_bf16(qf[ks][0], bhi, sacc, 0, 0, 0);
            }
            int col = cb*16 + l16;
            int gk = kbase + col;
#pragma unroll
            for (int reg = 0; reg < 4; reg++)
                Ss[w*16 + quad*4 + reg][col] = (gk < T) ? sacc[reg]*0.125f : -INFINITY;
        }
        __syncthreads();

        // online softmax (4 threads/row); P split-bf16 overwrites Ks
        {
            int rr = t >> 2, sub = t & 3;
            float mx = -INFINITY;
#pragma unroll
            for (int kk = 0; kk < 16; kk++) mx = fmaxf(mx, Ss[rr][sub*16 + kk]);
            mx = fmaxf(mx, __shfl_xor(mx, 1, 64));
            mx = fmaxf(mx, __shfl_xor(mx, 2, 64));
            float mold = m_s[rr];
            float newm = fmaxf(mold, mx);
            float ps = 0.f;
#pragma unroll
            for (int kk = 0; kk < 16; kk++) {
                float p = __expf(Ss[rr][sub*16 + kk] - newm);
                unsigned short hh, ll;
                split_bf16(p, hh, ll);
                Ks[0][rr][sub*16 + kk] = hh;
                Ks[1][rr][sub*16 + kk] = ll;
                ps += p;
            }
            ps += __shfl_xor(ps, 1, 64);
            ps += __shfl_xor(ps, 2, 64);
            if (sub == 0) {
                float alpha = __expf(mold - newm);
                l_s[rr] = l_s[rr]*alpha + ps;
                m_s[rr] = newm;
                al_s[rr] = alpha;
            }
        }
        __syncthreads();

        // O = alpha*O + P V (A: m=l16 -> q, k -> ktok; B from Vt: n=l16 -> d, k -> ktok)
#pragma unroll
        for (int reg = 0; reg < 4; reg++) {
            float a = al_s[w*16 + quad*4 + reg];
#pragma unroll
            for (int cb = 0; cb < 4; cb++) oacc[cb][reg] *= a;
        }
#pragma unroll
        for (int ks = 0; ks < 2; ks++) {
            bf16x8v phi = *(const bf16x8v*)&Ks[0][w*16 + l16][ks*32 + quad*8];
            bf16x8v plo = *(const bf16x8v*)&Ks[1][w*16 + l16][ks*32 + quad*8];
#pragma unroll
            for (int cb = 0; cb < 4; cb++) {
                bf16x8v vhi = *(const bf16x8v*)&Vt[0][cb*16 + l16][ks*32 + quad*8];
                bf16x8v vlo = *(const bf16x8v*)&Vt[1][cb*16 + l16][ks*32 + quad*8];
                oacc[cb] = __builtin_amdgcn_mfma_f32_16x16x32_bf16(plo, vhi, oacc[cb], 0, 0, 0);
                oacc[cb] = __builtin_amdgcn_mfma_f32_16x16x32_bf16(phi, vlo, oacc[cb], 0, 0, 0);
                oacc[cb] = __builtin_amdgcn_mfma_f32_16x16x32_bf16(phi, vhi, oacc[cb], 0, 0, 0);
            }
        }
    }

    // epilogue: divide by l, split-bf16 store (C layout: row=quad*4+reg, col=l16)
#pragma unroll
    for (int reg = 0; reg < 4; reg++) {
        int gq = q0 + w*16 + quad*4 + reg;
        if (gq < T) {
            float inv = 1.0f / l_s[w*16 + quad*4 + reg];
#pragma unroll
            for (int cb = 0; cb < 4; cb++) {
                float v = oacc[cb][reg] * inv;
                unsigned short hh, ll;
                split_bf16(v, hh, ll);
                size_t o = (size_t)(b*T + gq)*384 + h*64 + cb*16 + l16;
                out_hi[o] = hh;
                out_lo[o] = ll;
            }
        }
    }
}

// ---------------- cls-row stats: entropy + raw importance per head ----------------
__global__ __launch_bounds__(256) void cls_stats_kernel(const float* __restrict__ qkv,
                                                        float* __restrict__ raw_h,
                                                        float* __restrict__ ent,
                                                        const int* __restrict__ dT)
{
    int T = *dT;
    int bh = blockIdx.x;
    int b = bh / NHEADS, h = bh % NHEADS;
    __shared__ float q0s[64];
    __shared__ float logit[TMAXT];
    __shared__ float red[8];
    int t = threadIdx.x;
    if (t < 64) q0s[t] = qkv[(size_t)(b*T)*1152 + h*64 + t];
    __syncthreads();
    float lmax = -INFINITY;
    for (int j = t; j < T; j += 256) {
        const float* kp = qkv + (size_t)(b*T + j)*1152 + 384 + h*64;
        float dot = 0.f;
#pragma unroll
        for (int d = 0; d < 64; d += 4) {
            float4 kk = *(const float4*)(kp + d);
            dot += q0s[d]*kk.x + q0s[d+1]*kk.y + q0s[d+2]*kk.z + q0s[d+3]*kk.w;
        }
        float lg = dot * 0.125f;
        logit[j] = lg;
        lmax = fmaxf(lmax, lg);
    }
#pragma unroll
    for (int off = 32; off; off >>= 1) lmax = fmaxf(lmax, __shfl_xor(lmax, off, 64));
    if ((t & 63) == 0) red[t >> 6] = lmax;
    __syncthreads();
    float gmax = fmaxf(fmaxf(red[0], red[1]), fmaxf(red[2], red[3]));
    __syncthreads();
    float psum = 0.f;
    for (int j = t; j < T; j += 256) psum += expf(logit[j] - gmax);
#pragma unroll
    for (int off = 32; off; off >>= 1) psum += __shfl_xor(psum, off, 64);
    if ((t & 63) == 0) red[4 + (t >> 6)] = psum;
    __syncthreads();
    float inv = 1.0f / (red[4] + red[5] + red[6] + red[7]);
    float entp = 0.f;
    for (int j = t; j < T; j += 256) {
        float p = expf(logit[j] - gmax) * inv;
        entp += -p * logf(p + 1e-6f);
        if (j >= 1) {
            const float* vp = qkv + (size_t)(b*T + j)*1152 + 768 + h*64;
            float vn = 0.f;
#pragma unroll
            for (int d = 0; d < 64; d += 4) {
                float4 vx = *(const float4*)(vp + d);
                vn += vx.x*vx.x + vx.y*vx.y + vx.z*vx.z + vx.w*vx.w;
            }
            raw_h[(size_t)bh*576 + (j - 1)] = p * sqrtf(vn);
        }
    }
#pragma unroll
    for (int off = 32; off; off >>= 1) entp += __shfl_xor(entp, off, 64);
    __syncthreads();
    if ((t & 63) == 0) red[t >> 6] = entp;
    __syncthreads();
    if (t == 0) ent[bh] = red[0] + red[1] + red[2] + red[3];
}

// ---------------- prune decision (single block) ----------------
__global__ __launch_bounds__(256) void decide_kernel(const float* __restrict__ raw_h,
                                                     const float* __restrict__ ent,
                                                     float* __restrict__ prev_mass,
                                                     int* __restrict__ keep,
                                                     const int* __restrict__ dT,
                                                     int* __restrict__ dTnext,
                                                     int layer)
{
    int t = threadIdx.x;
    int T = *dT, N = T - 1;
    __shared__ float massS[8];
    __shared__ float scores[NMAXT];
    __shared__ int   keptFlag[NMAXT];
    __shared__ int   nnS;
    if (N <= 16) {
        for (int i = t; i < T; i += 256) keep[i] = i;
        if (t == 0) *dTnext = T;
        return;
    }
    {
        int b = t >> 5, lane = t & 31;
        float s = 0.f;
        for (int h = 0; h < 6; h++)
            for (int j = lane; j < N; j += 32)
                s += raw_h[(size_t)(b*6 + h)*576 + j];
#pragma unroll
        for (int off = 16; off; off >>= 1) s += __shfl_xor(s, off, 64);
        if (lane == 0) massS[b] = s;
    }
    __syncthreads();
    for (int j = t; j < N; j += 256) {
        float s = 0.f;
        for (int b = 0; b < 8; b++) {
            float rb = 0.f;
            for (int h = 0; h < 6; h++) rb += raw_h[(size_t)(b*6 + h)*576 + j];
            s += rb / (massS[b] + 1e-6f);
        }
        scores[j] = s * 0.125f;
    }
    __syncthreads();
    if (t == 0) {
        float es = 0.f;
        for (int i = 0; i < 48; i++) es += ent[i];
        float rho_mean = es / 48.0f / logf((float)T);
        int Nn;
        if (layer == 0) {
            Nn = N;
        } else {
            float dm = 0.f;
            for (int b = 0; b < 8; b++)
                dm += fabsf(massS[b] - prev_mass[b]) / (prev_mass[b] + 1e-6f);
            dm *= 0.125f;
            float kr = 1.0f - 0.1f * (rho_mean + dm);
            kr = fminf(fmaxf(kr, 0.0f), 1.0f);
            Nn = (int)((double)N * (double)kr);
            if (Nn < 16) Nn = 16;
        }
        nnS = Nn;
        *dTnext = Nn + 1;
    }
    __syncthreads();
    if (t < 8) prev_mass[t] = massS[t];
    int Nn = nnS;
    if (Nn < N) {
        for (int j = t; j < N; j += 256) {
            float sj = scores[j];
            int cnt = 0;
            for (int j2 = 0; j2 < N; j2++) {
                float s2 = scores[j2];
                cnt += (s2 > sj) || (s2 == sj && j2 < j);
            }
            keptFlag[j] = (cnt < Nn) ? 1 : 0;
        }
        __syncthreads();
        if (t == 0) {
            keep[0] = 0;
            int pos = 1;
            for (int j = 0; j < N; j++)
                if (keptFlag[j]) keep[pos++] = j + 1;
        }
    } else {
        for (int i = t; i < T; i += 256) keep[i] = i;
    }
}

// ---------------- gather pruned tokens (ping-pong) ----------------
__global__ __launch_bounds__(128) void gather_kernel(const float* __restrict__ src,
                                                     float* __restrict__ dst,
                                                     const int* __restrict__ keep,
                                                     const int* __restrict__ dT,
                                                     const int* __restrict__ dTnext)
{
    int Tn = *dTnext;
    int ti = blockIdx.x;
    if (ti >= Tn) return;
    int To = *dT;
    int b = blockIdx.y;
    const float* s = src + (size_t)(b*To + keep[ti]) * 384;
    float* d = dst + (size_t)(b*Tn + ti) * 384;
    int t = threadIdx.x;
    if (t < 96) ((float4*)d)[t] = ((const float4*)s)[t];
}

__global__ void bump_kernel(int* dT, const int* dTnext) { *dT = *dTnext; }

// ---------------- final LN on cls rows (fp32) ----------------
__global__ __launch_bounds__(64) void lnf_kernel(const float* __restrict__ xin,
                                                 const float* __restrict__ sc,
                                                 const float* __restrict__ bi,
                                                 float* __restrict__ xf,
                                                 const int* __restrict__ dT)
{
    int T = *dT;
    int b = blockIdx.x;
    int lane = threadIdx.x;
    const float* xr = xin + (size_t)(b*T) * 384;
    float v[6];
#pragma unroll
    for (int i = 0; i < 6; i++) v[i] = xr[lane + 64*i];
    float s = v[0]+v[1]+v[2]+v[3]+v[4]+v[5];
#pragma unroll
    for (int off = 32; off; off >>= 1) s += __shfl_xor(s, off, 64);
    float mean = s * (1.0f/384.0f);
    float q = 0.f;
#pragma unroll
    for (int i = 0; i < 6; i++) { float d = v[i]-mean; q += d*d; }
#pragma unroll
    for (int off = 32; off; off >>= 1) q += __shfl_xor(q, off, 64);
    float rstd = 1.0f / sqrtf(q * (1.0f/384.0f) + 1e-5f);
#pragma unroll
    for (int i = 0; i < 6; i++) {
        int d = lane + 64*i;
        xf[(size_t)b*384 + d] = (v[i]-mean) * rstd * sc[d] + bi[d];
    }
}

// ---------------- head ----------------
__global__ __launch_bounds__(256) void head_kernel(const float* __restrict__ xf,
                                                   const float* __restrict__ hw,
                                                   const float* __restrict__ hb,
                                                   float* __restrict__ out)
{
    int idx = blockIdx.x * 256 + threadIdx.x;
    if (idx >= 8000) return;
    int b = idx / 1000, n = idx - b*1000;
    const float* xr = xf + (size_t)b*384;
    float s = hb[n];
#pragma unroll 4
    for (int k = 0; k < 384; k++) s += xr[k] * hw[(size_t)k*1000 + n];
    out[idx] = s;
}

// ---------------- launch ----------------
extern "C" void kernel_launch(void* const* d_in, const int* in_sizes, int n_in,
                              void* d_out, int out_size, void* d_ws, size_t ws_size,
                              hipStream_t stream)
{
    (void)in_sizes; (void)n_in; (void)out_size; (void)ws_size;
    const float* x       = (const float*)d_in[0];
    const float* patch_w = (const float*)d_in[1];
    const float* patch_b = (const float*)d_in[2];
    const float* cls_tok = (const float*)d_in[3];
    const float* pos     = (const float*)d_in[4];
    const float* ln1_s   = (const float*)d_in[5];
    const float* ln1_b   = (const float*)d_in[6];
    const float* qkv_w   = (const float*)d_in[7];
    const float* qkv_b   = (const float*)d_in[8];
    const float* proj_w  = (const float*)d_in[9];
    const float* proj_b  = (const float*)d_in[10];
    const float* ln2_s   = (const float*)d_in[11];
    const float* ln2_b   = (const float*)d_in[12];
    const float* fc1_w   = (const float*)d_in[13];
    const float* fc1_b   = (const float*)d_in[14];
    const float* fc2_w   = (const float*)d_in[15];
    const float* fc2_b   = (const float*)d_in[16];
    const float* norm_s  = (const float*)d_in[17];
    const float* norm_b  = (const float*)d_in[18];
    const float* head_w  = (const float*)d_in[19];
    const float* head_b  = (const float*)d_in[20];
    float* out = (float*)d_out;
    float* ws  = (float*)d_ws;

    float* x0   = ws + X0_OFF;
    float* x1   = ws + X1_OFF;
    float* qkvb = ws + QKV_OFF;
    float* rawh = ws + RAWH_OFF;
    float* entb = ws + ENT_OFF;
    float* pm   = ws + PM_OFF;
    float* xf   = ws + XF_OFF;
    int*   keep = (int*)(ws + KEEP_OFF);
    int*   dT   = (int*)(ws + T_OFF);
    int*   dTn  = (int*)(ws + TN_OFF);

    unsigned short* xn_hi = (unsigned short*)(ws + XN_OFF);
    unsigned short* xn_lo = xn_hi + XSZ;
    unsigned short* ao_hi = (unsigned short*)(ws + AO_OFF);
    unsigned short* ao_lo = ao_hi + XSZ;
    unsigned short* hb_hi = (unsigned short*)(ws + QKV_OFF);   // aliases qkvb (dead by fc1)
    unsigned short* hb_lo = hb_hi + HBELEM;
    unsigned short* wspl  = (unsigned short*)(ws + WSPL_OFF);

    prologue_kernel<<<8, 128, 0, stream>>>(cls_tok, pos, x0, dT);
    patch_kernel<<<dim3(6, 72), 256, 0, stream>>>(x, patch_w, patch_b, pos, x0);

    float* bufs[2] = { x0, x1 };
    for (int l = 0; l < LAYERS; l++) {
        float* src = bufs[l & 1];
        float* dst = bufs[(l + 1) & 1];
        wsplit_kernel<<<dim3(576, 4), 256, 0, stream>>>(
            qkv_w + (size_t)l*384*1152, proj_w + (size_t)l*384*384,
            fc1_w + (size_t)l*384*1536, fc2_w + (size_t)l*1536*384, wspl);
        ln_kernel<<<1154, 256, 0, stream>>>(src, ln1_s + l*384, ln1_b + l*384, xn_hi, xn_lo, dT);
        gemm3_kernel<0><<<dim3(9, 73), 256, 0, stream>>>(
            xn_hi, xn_lo, wspl + W_QKV, qkv_b + l*1152, nullptr, qkvb, nullptr, nullptr, 384, 1152, dT);
        attn_kernel<<<dim3(10, 48), 256, 0, stream>>>(qkvb, ao_hi, ao_lo, dT);
        cls_stats_kernel<<<48, 256, 0, stream>>>(qkvb, rawh, entb, dT);
        gemm3_kernel<2><<<dim3(3, 73), 256, 0, stream>>>(
            ao_hi, ao_lo, wspl + W_PROJ, proj_b + l*384, src, src, nullptr, nullptr, 384, 384, dT);
        ln_kernel<<<1154, 256, 0, stream>>>(src, ln2_s + l*384, ln2_b + l*384, xn_hi, xn_lo, dT);
        gemm3_kernel<1><<<dim3(12, 73), 256, 0, stream>>>(
            xn_hi, xn_lo, wspl + W_FC1, fc1_b + l*1536, nullptr, nullptr, hb_hi, hb_lo, 384, 1536, dT);
        gemm3_kernel<2><<<dim3(3, 73), 256, 0, stream>>>(
            hb_hi, hb_lo, wspl + W_FC2, fc2_b + l*384, src, src, nullptr, nullptr, 1536, 384, dT);
        decide_kernel<<<1, 256, 0, stream>>>(rawh, entb, pm, keep, dT, dTn, l);
        gather_kernel<<<dim3(577, 8), 128, 0, stream>>>(src, dst, keep, dT, dTn);
        bump_kernel<<<1, 1, 0, stream>>>(dT, dTn);
    }
    lnf_kernel<<<8, 64, 0, stream>>>(bufs[0], norm_s, norm_b, xf, dT);
    head_kernel<<<32, 256, 0, stream>>>(xf, head_w, head_b, out);
}

// Round 5
// 2627.802 us; speedup vs baseline: 2.2465x; 1.1631x over previous
//
#include <hip/hip_runtime.h>
#include <math.h>

#define NHEADS 6
#define DMODEL 384
#define TMAXT  577
#define NMAXT  576
#define BATCH  8
#define LAYERS 12

typedef __attribute__((ext_vector_type(8))) short bf16x8v;
typedef __attribute__((ext_vector_type(4))) float f32x4v;

// ---------------- workspace layout (float indices) ----------------
#define XSZ      (8ull*577*384)            // 1,772,544
#define X0_OFF   0ull
#define X1_OFF   (X0_OFF + XSZ)
#define XN_OFF   (X1_OFF + XSZ)            // xn split planes: 2 x XSZ ushort = XSZ floats
#define QKV_OFF  (XN_OFF + XSZ)
#define QKV_SZ   (8ull*577*1152)           // 5,317,632 floats
#define AO_OFF   (QKV_OFF + QKV_SZ)        // ao split planes: 2 x XSZ ushort = XSZ floats
#define HBELEM   (8ull*577*1536)           // 7,090,176 elements
#define RAWH_OFF (AO_OFF + XSZ)            // 8*6*576
#define RAWH_SZ  (8ull*6*576)
#define ENT_OFF  (RAWH_OFF + RAWH_SZ)      // 48 (pad 64)
#define PM_OFF   (ENT_OFF + 64)            // 8 (pad 64)
#define XF_OFF   (PM_OFF + 64)             // 8*384
#define KEEP_OFF (XF_OFF + 8*384)          // 577 ints (pad 640)
#define T_OFF    (KEEP_OFF + 640)
#define TN_OFF   (T_OFF + 16)
#define WSPL_OFF (TN_OFF + 16)             // weight splits: 3,538,944 ushort

// weight split sub-offsets (ushort units inside WSPL)
#define W_QKV   0ull
#define W_PROJ  884736ull
#define W_FC1   1179648ull
#define W_FC2   2359296ull

// ---------------- bf16 split helpers ----------------
__device__ inline unsigned short rne_bf16(float f) {
    unsigned int u = __float_as_uint(f);
    u += 0x7FFFu + ((u >> 16) & 1u);
    return (unsigned short)(u >> 16);
}
__device__ inline float bf16_to_f(unsigned short h) {
    return __uint_as_float(((unsigned int)h) << 16);
}
__device__ inline void split_bf16(float x, unsigned short& h, unsigned short& l) {
    h = rne_bf16(x);
    l = rne_bf16(x - bf16_to_f(h));
}

// ---------------- prologue: cls row + pos, init T ----------------
__global__ __launch_bounds__(128) void prologue_kernel(const float* __restrict__ cls_tok,
                                                       const float* __restrict__ pos,
                                                       float* __restrict__ x0,
                                                       int* __restrict__ dT)
{
    int b = blockIdx.x;
    for (int d = threadIdx.x; d < 384; d += 128)
        x0[(size_t)b*577*384 + d] = cls_tok[d] + pos[d];
    if (b == 0 && threadIdx.x == 0) *dT = 577;
}

// ---------------- patch embed GEMM (fp32 vector) ----------------
__global__ __launch_bounds__(256) void patch_kernel(const float* __restrict__ x,
                                                    const float* __restrict__ pw,
                                                    const float* __restrict__ pb,
                                                    const float* __restrict__ pos,
                                                    float* __restrict__ x0)
{
    const int K = 768, Nc = 384;
    int row0 = blockIdx.y * 64, col0 = blockIdx.x * 64;
    __shared__ float As[16][68];
    __shared__ float Bs[16][68];
    int t = threadIdx.x;
    int tx = t & 15, ty = t >> 4;
    int am = t >> 2, ak = (t & 3) * 4;
    int bk = t >> 4, bn = (t & 15) * 4;
    float acc[4][4];
#pragma unroll
    for (int i = 0; i < 4; i++)
#pragma unroll
        for (int j = 0; j < 4; j++) acc[i][j] = 0.f;

    int arow = row0 + am;
    int b  = arow / 576, tt = arow % 576;
    int g1 = tt / 24,    g2 = tt % 24;
    const float* xr = x + ((size_t)(b*3)*384 + g1*16)*384 + g2*16;
    const float* Wp = pw + (size_t)bk*Nc + col0 + bn;

    for (int k0 = 0; k0 < K; k0 += 16) {
        int k = k0 + ak;
        int c = k >> 8, rr = k & 255, p1 = rr >> 4, p2 = rr & 15;
        float4 av = *(const float4*)(xr + ((size_t)c*384 + p1)*384 + p2);
        float4 wv = *(const float4*)(Wp + (size_t)k0*Nc);
        __syncthreads();
        As[ak+0][am] = av.x; As[ak+1][am] = av.y; As[ak+2][am] = av.z; As[ak+3][am] = av.w;
        *(float4*)&Bs[bk][bn] = wv;
        __syncthreads();
#pragma unroll
        for (int kk = 0; kk < 16; kk++) {
            float4 a4 = *(const float4*)&As[kk][ty*4];
            float4 b4 = *(const float4*)&Bs[kk][tx*4];
            acc[0][0] += a4.x*b4.x; acc[0][1] += a4.x*b4.y; acc[0][2] += a4.x*b4.z; acc[0][3] += a4.x*b4.w;
            acc[1][0] += a4.y*b4.x; acc[1][1] += a4.y*b4.y; acc[1][2] += a4.y*b4.z; acc[1][3] += a4.y*b4.w;
            acc[2][0] += a4.z*b4.x; acc[2][1] += a4.z*b4.y; acc[2][2] += a4.z*b4.z; acc[2][3] += a4.z*b4.w;
            acc[3][0] += a4.w*b4.x; acc[3][1] += a4.w*b4.y; acc[3][2] += a4.w*b4.z; acc[3][3] += a4.w*b4.w;
        }
    }
#pragma unroll
    for (int i = 0; i < 4; i++) {
        int r = row0 + ty*4 + i;
        int bb = r / 576, ttt = r % 576;
#pragma unroll
        for (int j = 0; j < 4; j++) {
            int c = col0 + tx*4 + j;
            float v = acc[i][j] + pb[c] + pos[(size_t)(1 + ttt)*384 + c];
            x0[(size_t)(bb*577 + 1 + ttt)*384 + c] = v;
        }
    }
}

// ---------------- weight split+transpose: W[K][N] fp32 -> Wt_hi/lo [N][K] bf16 ----------------
__global__ __launch_bounds__(256) void wsplit_kernel(const float* __restrict__ qkvw,
                                                     const float* __restrict__ projw,
                                                     const float* __restrict__ fc1w,
                                                     const float* __restrict__ fc2w,
                                                     unsigned short* __restrict__ wspl)
{
    int mat = blockIdx.y;
    const float* W; int K, N; size_t off;
    if (mat == 0)      { W = qkvw; K = 384;  N = 1152; off = W_QKV; }
    else if (mat == 1) { W = projw; K = 384; N = 384;  off = W_PROJ; }
    else if (mat == 2) { W = fc1w; K = 384;  N = 1536; off = W_FC1; }
    else               { W = fc2w; K = 1536; N = 384;  off = W_FC2; }
    int ktiles = K >> 5, ntiles = N >> 5;
    int tid = blockIdx.x;
    if (tid >= ktiles * ntiles) return;
    int tk = tid % ktiles, tn = tid / ktiles;
    int k0 = tk << 5, n0 = tn << 5;
    __shared__ unsigned short Th[32][34];
    __shared__ unsigned short Tl[32][34];
    int t = threadIdx.x;
    {
        int row = t >> 3, c4 = (t & 7) << 2;
        float4 wv = *(const float4*)(W + (size_t)(k0 + row) * N + n0 + c4);
        unsigned short h, l;
        split_bf16(wv.x, h, l); Th[c4+0][row] = h; Tl[c4+0][row] = l;
        split_bf16(wv.y, h, l); Th[c4+1][row] = h; Tl[c4+1][row] = l;
        split_bf16(wv.z, h, l); Th[c4+2][row] = h; Tl[c4+2][row] = l;
        split_bf16(wv.w, h, l); Th[c4+3][row] = h; Tl[c4+3][row] = l;
    }
    __syncthreads();
    {
        int n = t >> 3, k4 = (t & 7) << 2;
        unsigned short* dh = wspl + off + (size_t)(n0 + n) * K + k0 + k4;
        unsigned short* dl = dh + (size_t)K * N;
        ushort4 oh = make_ushort4(Th[n][k4], Th[n][k4+1], Th[n][k4+2], Th[n][k4+3]);
        ushort4 ol = make_ushort4(Tl[n][k4], Tl[n][k4+1], Tl[n][k4+2], Tl[n][k4+3]);
        *(ushort4*)dh = oh;
        *(ushort4*)dl = ol;
    }
}

// ---------------- LayerNorm -> split bf16 planes ----------------
__global__ __launch_bounds__(256) void ln_kernel(const float* __restrict__ xin,
                                                 const float* __restrict__ sc,
                                                 const float* __restrict__ bi,
                                                 unsigned short* __restrict__ yhi,
                                                 unsigned short* __restrict__ ylo,
                                                 const int* __restrict__ dT)
{
    int T = *dT;
    int M = 8 * T;
    int r = blockIdx.x * 4 + (threadIdx.x >> 6);
    if (r >= M) return;
    int lane = threadIdx.x & 63;
    const float* xr = xin + (size_t)r * 384;
    float v[6];
#pragma unroll
    for (int i = 0; i < 6; i++) v[i] = xr[lane + 64*i];
    float s = v[0]+v[1]+v[2]+v[3]+v[4]+v[5];
#pragma unroll
    for (int off = 32; off; off >>= 1) s += __shfl_xor(s, off, 64);
    float mean = s * (1.0f/384.0f);
    float q = 0.f;
#pragma unroll
    for (int i = 0; i < 6; i++) { float d = v[i]-mean; q += d*d; }
#pragma unroll
    for (int off = 32; off; off >>= 1) q += __shfl_xor(q, off, 64);
    float rstd = 1.0f / sqrtf(q * (1.0f/384.0f) + 1e-5f);
#pragma unroll
    for (int i = 0; i < 6; i++) {
        int d = lane + 64*i;
        float y = (v[i]-mean) * rstd * sc[d] + bi[d];
        unsigned short h, l;
        split_bf16(y, h, l);
        yhi[(size_t)r*384 + d] = h;
        ylo[(size_t)r*384 + d] = l;
    }
}

// ---------------- bf16x3 MFMA GEMM: C = A*W + bias (+gelu / +resid) ----------------
template<int EPI>
__global__ __launch_bounds__(256, 3) void gemm3_kernel(const unsigned short* __restrict__ Ahi,
                                                       const unsigned short* __restrict__ Alo,
                                                       const unsigned short* __restrict__ Wt,
                                                       const float* __restrict__ bias,
                                                       const float* __restrict__ resid,
                                                       float* __restrict__ Cf,
                                                       unsigned short* __restrict__ Chi,
                                                       unsigned short* __restrict__ Clo,
                                                       int K, int N,
                                                       const int* __restrict__ dT)
{
    int T = *dT; int M = 8 * T;
    int m0 = blockIdx.y * 64;
    if (m0 >= M) return;
    int n0 = blockIdx.x * 128;

    __shared__ unsigned short As[2][64][40];
    __shared__ unsigned short Bs[2][128][40];

    int t = threadIdx.x;
    int lane = t & 63, w = t >> 6;
    int wr = w >> 1, wc = w & 1;
    int quad = lane >> 4, l16 = lane & 15;

    f32x4v acc[2][4];
#pragma unroll
    for (int i = 0; i < 2; i++)
#pragma unroll
        for (int j = 0; j < 4; j++) acc[i][j] = (f32x4v){0.f, 0.f, 0.f, 0.f};

    int arow = t >> 2, ak = (t & 3) * 8;
    int ag = m0 + arow; if (ag > M - 1) ag = M - 1;
    const unsigned short* Ah = Ahi + (size_t)ag * K + ak;
    const unsigned short* Al = Alo + (size_t)ag * K + ak;

    int bn = t >> 1, bk = (t & 1) * 16;
    const unsigned short* Bh = Wt + (size_t)(n0 + bn) * K + bk;
    const unsigned short* Bl = Bh + (size_t)K * N;

    for (int k0 = 0; k0 < K; k0 += 32) {
        uint4 vah  = *(const uint4*)(Ah + k0);
        uint4 val  = *(const uint4*)(Al + k0);
        uint4 vbh0 = *(const uint4*)(Bh + k0);
        uint4 vbh1 = *(const uint4*)(Bh + k0 + 8);
        uint4 vbl0 = *(const uint4*)(Bl + k0);
        uint4 vbl1 = *(const uint4*)(Bl + k0 + 8);
        __syncthreads();
        *(uint4*)&As[0][arow][ak] = vah;
        *(uint4*)&As[1][arow][ak] = val;
        *(uint4*)&Bs[0][bn][bk]     = vbh0;
        *(uint4*)&Bs[0][bn][bk + 8] = vbh1;
        *(uint4*)&Bs[1][bn][bk]     = vbl0;
        *(uint4*)&Bs[1][bn][bk + 8] = vbl1;
        __syncthreads();

        bf16x8v afh[2], afl[2], bfh[4], bfl[4];
#pragma unroll
        for (int rb = 0; rb < 2; rb++) {
            int r = wr * 32 + rb * 16 + l16;
            afh[rb] = *(const bf16x8v*)&As[0][r][quad * 8];
            afl[rb] = *(const bf16x8v*)&As[1][r][quad * 8];
        }
#pragma unroll
        for (int cb = 0; cb < 4; cb++) {
            int c = wc * 64 + cb * 16 + l16;
            bfh[cb] = *(const bf16x8v*)&Bs[0][c][quad * 8];
            bfl[cb] = *(const bf16x8v*)&Bs[1][c][quad * 8];
        }
#pragma unroll
        for (int rb = 0; rb < 2; rb++)
#pragma unroll
            for (int cb = 0; cb < 4; cb++) {
                acc[rb][cb] = __builtin_amdgcn_mfma_f32_16x16x32_bf16(afl[rb], bfh[cb], acc[rb][cb], 0, 0, 0);
                acc[rb][cb] = __builtin_amdgcn_mfma_f32_16x16x32_bf16(afh[rb], bfl[cb], acc[rb][cb], 0, 0, 0);
                acc[rb][cb] = __builtin_amdgcn_mfma_f32_16x16x32_bf16(afh[rb], bfh[cb], acc[rb][cb], 0, 0, 0);
            }
    }

#pragma unroll
    for (int rb = 0; rb < 2; rb++) {
#pragma unroll
        for (int reg = 0; reg < 4; reg++) {
            int r = m0 + wr * 32 + rb * 16 + quad * 4 + reg;
            if (r >= M) continue;
#pragma unroll
            for (int cb = 0; cb < 4; cb++) {
                int c = n0 + wc * 64 + cb * 16 + l16;
                float v = acc[rb][cb][reg] + bias[c];
                if (EPI == 1) {
                    v = 0.5f * v * (1.0f + erff(v * 0.70710678118654752440f));
                    unsigned short h, l;
                    split_bf16(v, h, l);
                    Chi[(size_t)r * N + c] = h;
                    Clo[(size_t)r * N + c] = l;
                } else {
                    if (EPI == 2) v += resid[(size_t)r * N + c];
                    Cf[(size_t)r * N + c] = v;
                }
            }
        }
    }
}

// ---------------- flash attention v3: MFMA (split-bf16) QK^T and PV, fp32 softmax ----------------
__global__ __launch_bounds__(256, 3) void attn_kernel(const float* __restrict__ qkv,
                                                      unsigned short* __restrict__ out_hi,
                                                      unsigned short* __restrict__ out_lo,
                                                      const int* __restrict__ dT)
{
    int T = *dT;
    int q0 = blockIdx.x * 64;
    if (q0 >= T) return;
    int bh = blockIdx.y;
    int b = bh / NHEADS, h = bh % NHEADS;

    __shared__ unsigned short Ks[2][64][72];   // K tile [tok][d]; later P [q][ktok]
    __shared__ unsigned short Vt[2][64][72];   // V^T tile [d][tok]
    __shared__ float Ss[64][66];               // S scores fp32
    __shared__ float m_s[64], l_s[64], al_s[64];

    int t = threadIdx.x;
    int lane = t & 63, w = t >> 6;
    int l16 = lane & 15, quad = lane >> 4;

    bf16x8v qf[2][2];   // [kstep][hi/lo]
    {
        int gq = q0 + w * 16 + l16;
        bool valid = gq < T;
        const float* qp = qkv + (size_t)(b * T + (valid ? gq : 0)) * 1152 + h * 64;
#pragma unroll
        for (int ks = 0; ks < 2; ks++) {
            int dbase = ks * 32 + quad * 8;
            float4 f0 = valid ? *(const float4*)(qp + dbase)     : make_float4(0.f,0.f,0.f,0.f);
            float4 f1 = valid ? *(const float4*)(qp + dbase + 4) : make_float4(0.f,0.f,0.f,0.f);
            float f[8] = {f0.x, f0.y, f0.z, f0.w, f1.x, f1.y, f1.z, f1.w};
            bf16x8v hi, lo;
#pragma unroll
            for (int j = 0; j < 8; j++) {
                unsigned short hh, ll;
                split_bf16(f[j], hh, ll);
                hi[j] = (short)hh; lo[j] = (short)ll;
            }
            qf[ks][0] = hi; qf[ks][1] = lo;
        }
    }
    if (t < 64) { m_s[t] = -INFINITY; l_s[t] = 0.f; }

    f32x4v oacc[4];
#pragma unroll
    for (int cb = 0; cb < 4; cb++) oacc[cb] = (f32x4v){0.f, 0.f, 0.f, 0.f};

    int ntiles = (T + 63) >> 6;
    for (int kt = 0; kt < ntiles; kt++) {
        int kbase = kt * 64;
        __syncthreads();

        {
            int gk = kbase + lane;
            int sd0 = w * 16;
            bool valid = gk < T;
            const float* kp = qkv + (size_t)(b * T + (valid ? gk : 0)) * 1152 + 384 + h * 64 + sd0;
            const float* vp = kp + 384;
#pragma unroll
            for (int c = 0; c < 4; c++) {
                float4 kv = valid ? *(const float4*)(kp + c * 4) : make_float4(0.f,0.f,0.f,0.f);
                float4 vv = valid ? *(const float4*)(vp + c * 4) : make_float4(0.f,0.f,0.f,0.f);
                unsigned short hh, ll;
                ushort4 kh, kl;
                split_bf16(kv.x, hh, ll); kh.x = hh; kl.x = ll;
                split_bf16(kv.y, hh, ll); kh.y = hh; kl.y = ll;
                split_bf16(kv.z, hh, ll); kh.z = hh; kl.z = ll;
                split_bf16(kv.w, hh, ll); kh.w = hh; kl.w = ll;
                *(ushort4*)&Ks[0][lane][sd0 + c*4] = kh;
                *(ushort4*)&Ks[1][lane][sd0 + c*4] = kl;
                split_bf16(vv.x, hh, ll); Vt[0][sd0 + c*4 + 0][lane] = hh; Vt[1][sd0 + c*4 + 0][lane] = ll;
                split_bf16(vv.y, hh, ll); Vt[0][sd0 + c*4 + 1][lane] = hh; Vt[1][sd0 + c*4 + 1][lane] = ll;
                split_bf16(vv.z, hh, ll); Vt[0][sd0 + c*4 + 2][lane] = hh; Vt[1][sd0 + c*4 + 2][lane] = ll;
                split_bf16(vv.w, hh, ll); Vt[0][sd0 + c*4 + 3][lane] = hh; Vt[1][sd0 + c*4 + 3][lane] = ll;
            }
        }
        __syncthreads();

#pragma unroll
        for (int cb = 0; cb < 4; cb++) {
            f32x4v sacc = (f32x4v){0.f, 0.f, 0.f, 0.f};
#pragma unroll
            for (int ks = 0; ks < 2; ks++) {
                bf16x8v bhi = *(const bf16x8v*)&Ks[0][cb*16 + l16][ks*32 + quad*8];
                bf16x8v blo = *(const bf16x8v*)&Ks[1][cb*16 + l16][ks*32 + quad*8];
                sacc = __builtin_amdgcn_mfma_f32_16x16x32_bf16(qf[ks][1], bhi, sacc, 0, 0, 0);
                sacc = __builtin_amdgcn_mfma_f32_16x16x32_bf16(qf[ks][0], blo, sacc, 0, 0, 0);
                sacc = __builtin_amdgcn_mfma_f32_16x16x32_bf16(qf[ks][0], bhi, sacc, 0, 0, 0);
            }
            int col = cb*16 + l16;
            int gk = kbase + col;
#pragma unroll
            for (int reg = 0; reg < 4; reg++)
                Ss[w*16 + quad*4 + reg][col] = (gk < T) ? sacc[reg]*0.125f : -INFINITY;
        }
        __syncthreads();

        {
            int rr = t >> 2, sub = t & 3;
            float mx = -INFINITY;
#pragma unroll
            for (int kk = 0; kk < 16; kk++) mx = fmaxf(mx, Ss[rr][sub*16 + kk]);
            mx = fmaxf(mx, __shfl_xor(mx, 1, 64));
            mx = fmaxf(mx, __shfl_xor(mx, 2, 64));
            float mold = m_s[rr];
            float newm = fmaxf(mold, mx);
            float ps = 0.f;
#pragma unroll
            for (int kk = 0; kk < 16; kk++) {
                float p = __expf(Ss[rr][sub*16 + kk] - newm);
                unsigned short hh, ll;
                split_bf16(p, hh, ll);
                Ks[0][rr][sub*16 + kk] = hh;
                Ks[1][rr][sub*16 + kk] = ll;
                ps += p;
            }
            ps += __shfl_xor(ps, 1, 64);
            ps += __shfl_xor(ps, 2, 64);
            if (sub == 0) {
                float alpha = __expf(mold - newm);
                l_s[rr] = l_s[rr]*alpha + ps;
                m_s[rr] = newm;
                al_s[rr] = alpha;
            }
        }
        __syncthreads();

#pragma unroll
        for (int reg = 0; reg < 4; reg++) {
            float a = al_s[w*16 + quad*4 + reg];
#pragma unroll
            for (int cb = 0; cb < 4; cb++) oacc[cb][reg] *= a;
        }
#pragma unroll
        for (int ks = 0; ks < 2; ks++) {
            bf16x8v phi = *(const bf16x8v*)&Ks[0][w*16 + l16][ks*32 + quad*8];
            bf16x8v plo = *(const bf16x8v*)&Ks[1][w*16 + l16][ks*32 + quad*8];
#pragma unroll
            for (int cb = 0; cb < 4; cb++) {
                bf16x8v vhi = *(const bf16x8v*)&Vt[0][cb*16 + l16][ks*32 + quad*8];
                bf16x8v vlo = *(const bf16x8v*)&Vt[1][cb*16 + l16][ks*32 + quad*8];
                oacc[cb] = __builtin_amdgcn_mfma_f32_16x16x32_bf16(plo, vhi, oacc[cb], 0, 0, 0);
                oacc[cb] = __builtin_amdgcn_mfma_f32_16x16x32_bf16(phi, vlo, oacc[cb], 0, 0, 0);
                oacc[cb] = __builtin_amdgcn_mfma_f32_16x16x32_bf16(phi, vhi, oacc[cb], 0, 0, 0);
            }
        }
    }

#pragma unroll
    for (int reg = 0; reg < 4; reg++) {
        int gq = q0 + w*16 + quad*4 + reg;
        if (gq < T) {
            float inv = 1.0f / l_s[w*16 + quad*4 + reg];
#pragma unroll
            for (int cb = 0; cb < 4; cb++) {
                float v = oacc[cb][reg] * inv;
                unsigned short hh, ll;
                split_bf16(v, hh, ll);
                size_t o = (size_t)(b*T + gq)*384 + h*64 + cb*16 + l16;
                out_hi[o] = hh;
                out_lo[o] = ll;
            }
        }
    }
}

// ---------------- cls-row stats: entropy + raw importance per head ----------------
__global__ __launch_bounds__(256) void cls_stats_kernel(const float* __restrict__ qkv,
                                                        float* __restrict__ raw_h,
                                                        float* __restrict__ ent,
                                                        const int* __restrict__ dT)
{
    int T = *dT;
    int bh = blockIdx.x;
    int b = bh / NHEADS, h = bh % NHEADS;
    __shared__ float q0s[64];
    __shared__ float logit[TMAXT];
    __shared__ float red[8];
    int t = threadIdx.x;
    if (t < 64) q0s[t] = qkv[(size_t)(b*T)*1152 + h*64 + t];
    __syncthreads();
    float lmax = -INFINITY;
    for (int j = t; j < T; j += 256) {
        const float* kp = qkv + (size_t)(b*T + j)*1152 + 384 + h*64;
        float dot = 0.f;
#pragma unroll
        for (int d = 0; d < 64; d += 4) {
            float4 kk = *(const float4*)(kp + d);
            dot += q0s[d]*kk.x + q0s[d+1]*kk.y + q0s[d+2]*kk.z + q0s[d+3]*kk.w;
        }
        float lg = dot * 0.125f;
        logit[j] = lg;
        lmax = fmaxf(lmax, lg);
    }
#pragma unroll
    for (int off = 32; off; off >>= 1) lmax = fmaxf(lmax, __shfl_xor(lmax, off, 64));
    if ((t & 63) == 0) red[t >> 6] = lmax;
    __syncthreads();
    float gmax = fmaxf(fmaxf(red[0], red[1]), fmaxf(red[2], red[3]));
    __syncthreads();
    float psum = 0.f;
    for (int j = t; j < T; j += 256) psum += expf(logit[j] - gmax);
#pragma unroll
    for (int off = 32; off; off >>= 1) psum += __shfl_xor(psum, off, 64);
    if ((t & 63) == 0) red[4 + (t >> 6)] = psum;
    __syncthreads();
    float inv = 1.0f / (red[4] + red[5] + red[6] + red[7]);
    float entp = 0.f;
    for (int j = t; j < T; j += 256) {
        float p = expf(logit[j] - gmax) * inv;
        entp += -p * logf(p + 1e-6f);
        if (j >= 1) {
            const float* vp = qkv + (size_t)(b*T + j)*1152 + 768 + h*64;
            float vn = 0.f;
#pragma unroll
            for (int d = 0; d < 64; d += 4) {
                float4 vx = *(const float4*)(vp + d);
                vn += vx.x*vx.x + vx.y*vx.y + vx.z*vx.z + vx.w*vx.w;
            }
            raw_h[(size_t)bh*576 + (j - 1)] = p * sqrtf(vn);
        }
    }
#pragma unroll
    for (int off = 32; off; off >>= 1) entp += __shfl_xor(entp, off, 64);
    __syncthreads();
    if ((t & 63) == 0) red[t >> 6] = entp;
    __syncthreads();
    if (t == 0) ent[bh] = red[0] + red[1] + red[2] + red[3];
}

// ---------------- prune decision v2: MLP-friendly (latency-parallel) single block ----------------
__global__ __launch_bounds__(256) void decide_kernel(const float* __restrict__ raw_h,
                                                     const float* __restrict__ ent,
                                                     float* __restrict__ prev_mass,
                                                     int* __restrict__ keep,
                                                     const int* __restrict__ dT,
                                                     int* __restrict__ dTnext,
                                                     int layer)
{
    int t = threadIdx.x;
    int T = *dT, N = T - 1;
    __shared__ float rbS[8][580];        // rb[b][j] = sum_h raw
    __shared__ float massS[8];
    __shared__ float pmS[8];
    __shared__ float esumS;
    __shared__ float scores[NMAXT];
    __shared__ int   keptFlag[NMAXT];
    __shared__ int   nnS;
    __shared__ int   wsum[4], wpre[4];

    if (N <= 16) {
        for (int i = t; i < T; i += 256) keep[i] = i;
        if (t == 0) *dTnext = T;
        return;
    }
    if (t < 8) pmS[t] = prev_mass[t];

    // phase A: rb[b][j] (6 independent loads in flight per iter) + mass partial
    {
        int b = t >> 5, lane = t & 31;
        const float* base = raw_h + (size_t)b * 6 * 576;
        float s = 0.f;
        for (int j = lane; j < N; j += 32) {
            float a0 = base[0*576 + j];
            float a1 = base[1*576 + j];
            float a2 = base[2*576 + j];
            float a3 = base[3*576 + j];
            float a4 = base[4*576 + j];
            float a5 = base[5*576 + j];
            float rb = ((a0 + a1) + (a2 + a3)) + (a4 + a5);
            rbS[b][j] = rb;
            s += rb;
        }
#pragma unroll
        for (int off = 16; off; off >>= 1) s += __shfl_xor(s, off, 64);
        if (lane == 0) massS[b] = s;
    }
    // entropy sum in parallel (first wave)
    if (t < 64) {
        float e = (t < 48) ? ent[t] : 0.f;
#pragma unroll
        for (int off = 32; off; off >>= 1) e += __shfl_xor(e, off, 64);
        if (t == 0) esumS = e;
    }
    __syncthreads();

    // phase C: scores[j] (division kept identical to previous-passing version)
    for (int j = t; j < N; j += 256) {
        float s = 0.f;
#pragma unroll
        for (int b = 0; b < 8; b++)
            s += rbS[b][j] / (massS[b] + 1e-6f);
        scores[j] = s * 0.125f;
    }
    __syncthreads();

    if (t == 0) {
        float rho_mean = esumS / 48.0f / logf((float)T);
        int Nn;
        if (layer == 0) {
            Nn = N;
        } else {
            float dm = 0.f;
#pragma unroll
            for (int b = 0; b < 8; b++)
                dm += fabsf(massS[b] - pmS[b]) / (pmS[b] + 1e-6f);
            dm *= 0.125f;
            float kr = 1.0f - 0.1f * (rho_mean + dm);
            kr = fminf(fmaxf(kr, 0.0f), 1.0f);
            Nn = (int)((double)N * (double)kr);   // Python int() truncation
            if (Nn < 16) Nn = 16;
        }
        nnS = Nn;
        *dTnext = Nn + 1;
    }
    __syncthreads();
    if (t < 8) prev_mass[t] = massS[t];          // after delta was read
    int Nn = nnS;

    if (Nn < N) {
        // phase D: rank, inner loop strip-mined x8 (independent LDS reads)
        for (int j = t; j < N; j += 256) {
            float sj = scores[j];
            int cnt = 0;
            int j2 = 0;
            for (; j2 + 8 <= N; j2 += 8) {
                float x0 = scores[j2+0], x1 = scores[j2+1];
                float x2 = scores[j2+2], x3 = scores[j2+3];
                float x4 = scores[j2+4], x5 = scores[j2+5];
                float x6 = scores[j2+6], x7 = scores[j2+7];
                cnt += (x0 > sj) || (x0 == sj && j2+0 < j);
                cnt += (x1 > sj) || (x1 == sj && j2+1 < j);
                cnt += (x2 > sj) || (x2 == sj && j2+2 < j);
                cnt += (x3 > sj) || (x3 == sj && j2+3 < j);
                cnt += (x4 > sj) || (x4 == sj && j2+4 < j);
                cnt += (x5 > sj) || (x5 == sj && j2+5 < j);
                cnt += (x6 > sj) || (x6 == sj && j2+6 < j);
                cnt += (x7 > sj) || (x7 == sj && j2+7 < j);
            }
            for (; j2 < N; j2++) {
                float s2 = scores[j2];
                cnt += (s2 > sj) || (s2 == sj && j2 < j);
            }
            keptFlag[j] = (cnt < Nn) ? 1 : 0;
        }
        __syncthreads();

        // phase E: parallel compaction. thread t owns contiguous j in [3t, 3t+3)
        int local = 0;
        int kf[3];
#pragma unroll
        for (int c = 0; c < 3; c++) {
            int j = 3*t + c;
            kf[c] = (j < N) ? keptFlag[j] : 0;
            local += kf[c];
        }
        int lane64 = t & 63, wv = t >> 6;
        int inc = local;
#pragma unroll
        for (int off = 1; off < 64; off <<= 1) {
            int nb = __shfl_up(inc, off, 64);
            if (lane64 >= off) inc += nb;
        }
        if (lane64 == 63) wsum[wv] = inc;
        __syncthreads();
        if (t == 0) {
            int run = 0;
#pragma unroll
            for (int i = 0; i < 4; i++) { wpre[i] = run; run += wsum[i]; }
            keep[0] = 0;
        }
        __syncthreads();
        int pos = 1 + (inc - local) + wpre[wv];
#pragma unroll
        for (int c = 0; c < 3; c++) {
            int j = 3*t + c;
            if (j < N && kf[c]) keep[pos++] = j + 1;
        }
    } else {
        for (int i = t; i < T; i += 256) keep[i] = i;
    }
}

// ---------------- gather pruned tokens (ping-pong) ----------------
__global__ __launch_bounds__(128) void gather_kernel(const float* __restrict__ src,
                                                     float* __restrict__ dst,
                                                     const int* __restrict__ keep,
                                                     const int* __restrict__ dT,
                                                     const int* __restrict__ dTnext)
{
    int Tn = *dTnext;
    int ti = blockIdx.x;
    if (ti >= Tn) return;
    int To = *dT;
    int b = blockIdx.y;
    const float* s = src + (size_t)(b*To + keep[ti]) * 384;
    float* d = dst + (size_t)(b*Tn + ti) * 384;
    int t = threadIdx.x;
    if (t < 96) ((float4*)d)[t] = ((const float4*)s)[t];
}

__global__ void bump_kernel(int* dT, const int* dTnext) { *dT = *dTnext; }

// ---------------- final LN on cls rows (fp32) ----------------
__global__ __launch_bounds__(64) void lnf_kernel(const float* __restrict__ xin,
                                                 const float* __restrict__ sc,
                                                 const float* __restrict__ bi,
                                                 float* __restrict__ xf,
                                                 const int* __restrict__ dT)
{
    int T = *dT;
    int b = blockIdx.x;
    int lane = threadIdx.x;
    const float* xr = xin + (size_t)(b*T) * 384;
    float v[6];
#pragma unroll
    for (int i = 0; i < 6; i++) v[i] = xr[lane + 64*i];
    float s = v[0]+v[1]+v[2]+v[3]+v[4]+v[5];
#pragma unroll
    for (int off = 32; off; off >>= 1) s += __shfl_xor(s, off, 64);
    float mean = s * (1.0f/384.0f);
    float q = 0.f;
#pragma unroll
    for (int i = 0; i < 6; i++) { float d = v[i]-mean; q += d*d; }
#pragma unroll
    for (int off = 32; off; off >>= 1) q += __shfl_xor(q, off, 64);
    float rstd = 1.0f / sqrtf(q * (1.0f/384.0f) + 1e-5f);
#pragma unroll
    for (int i = 0; i < 6; i++) {
        int d = lane + 64*i;
        xf[(size_t)b*384 + d] = (v[i]-mean) * rstd * sc[d] + bi[d];
    }
}

// ---------------- head ----------------
__global__ __launch_bounds__(256) void head_kernel(const float* __restrict__ xf,
                                                   const float* __restrict__ hw,
                                                   const float* __restrict__ hb,
                                                   float* __restrict__ out)
{
    int idx = blockIdx.x * 256 + threadIdx.x;
    if (idx >= 8000) return;
    int b = idx / 1000, n = idx - b*1000;
    const float* xr = xf + (size_t)b*384;
    float s = hb[n];
#pragma unroll 4
    for (int k = 0; k < 384; k++) s += xr[k] * hw[(size_t)k*1000 + n];
    out[idx] = s;
}

// ---------------- launch ----------------
extern "C" void kernel_launch(void* const* d_in, const int* in_sizes, int n_in,
                              void* d_out, int out_size, void* d_ws, size_t ws_size,
                              hipStream_t stream)
{
    (void)in_sizes; (void)n_in; (void)out_size; (void)ws_size;
    const float* x       = (const float*)d_in[0];
    const float* patch_w = (const float*)d_in[1];
    const float* patch_b = (const float*)d_in[2];
    const float* cls_tok = (const float*)d_in[3];
    const float* pos     = (const float*)d_in[4];
    const float* ln1_s   = (const float*)d_in[5];
    const float* ln1_b   = (const float*)d_in[6];
    const float* qkv_w   = (const float*)d_in[7];
    const float* qkv_b   = (const float*)d_in[8];
    const float* proj_w  = (const float*)d_in[9];
    const float* proj_b  = (const float*)d_in[10];
    const float* ln2_s   = (const float*)d_in[11];
    const float* ln2_b   = (const float*)d_in[12];
    const float* fc1_w   = (const float*)d_in[13];
    const float* fc1_b   = (const float*)d_in[14];
    const float* fc2_w   = (const float*)d_in[15];
    const float* fc2_b   = (const float*)d_in[16];
    const float* norm_s  = (const float*)d_in[17];
    const float* norm_b  = (const float*)d_in[18];
    const float* head_w  = (const float*)d_in[19];
    const float* head_b  = (const float*)d_in[20];
    float* out = (float*)d_out;
    float* ws  = (float*)d_ws;

    float* x0   = ws + X0_OFF;
    float* x1   = ws + X1_OFF;
    float* qkvb = ws + QKV_OFF;
    float* rawh = ws + RAWH_OFF;
    float* entb = ws + ENT_OFF;
    float* pm   = ws + PM_OFF;
    float* xf   = ws + XF_OFF;
    int*   keep = (int*)(ws + KEEP_OFF);
    int*   dT   = (int*)(ws + T_OFF);
    int*   dTn  = (int*)(ws + TN_OFF);

    unsigned short* xn_hi = (unsigned short*)(ws + XN_OFF);
    unsigned short* xn_lo = xn_hi + XSZ;
    unsigned short* ao_hi = (unsigned short*)(ws + AO_OFF);
    unsigned short* ao_lo = ao_hi + XSZ;
    unsigned short* hb_hi = (unsigned short*)(ws + QKV_OFF);   // aliases qkvb (dead by fc1)
    unsigned short* hb_lo = hb_hi + HBELEM;
    unsigned short* wspl  = (unsigned short*)(ws + WSPL_OFF);

    prologue_kernel<<<8, 128, 0, stream>>>(cls_tok, pos, x0, dT);
    patch_kernel<<<dim3(6, 72), 256, 0, stream>>>(x, patch_w, patch_b, pos, x0);

    float* bufs[2] = { x0, x1 };
    for (int l = 0; l < LAYERS; l++) {
        float* src = bufs[l & 1];
        float* dst = bufs[(l + 1) & 1];
        wsplit_kernel<<<dim3(576, 4), 256, 0, stream>>>(
            qkv_w + (size_t)l*384*1152, proj_w + (size_t)l*384*384,
            fc1_w + (size_t)l*384*1536, fc2_w + (size_t)l*1536*384, wspl);
        ln_kernel<<<1154, 256, 0, stream>>>(src, ln1_s + l*384, ln1_b + l*384, xn_hi, xn_lo, dT);
        gemm3_kernel<0><<<dim3(9, 73), 256, 0, stream>>>(
            xn_hi, xn_lo, wspl + W_QKV, qkv_b + l*1152, nullptr, qkvb, nullptr, nullptr, 384, 1152, dT);
        attn_kernel<<<dim3(10, 48), 256, 0, stream>>>(qkvb, ao_hi, ao_lo, dT);
        cls_stats_kernel<<<48, 256, 0, stream>>>(qkvb, rawh, entb, dT);
        gemm3_kernel<2><<<dim3(3, 73), 256, 0, stream>>>(
            ao_hi, ao_lo, wspl + W_PROJ, proj_b + l*384, src, src, nullptr, nullptr, 384, 384, dT);
        ln_kernel<<<1154, 256, 0, stream>>>(src, ln2_s + l*384, ln2_b + l*384, xn_hi, xn_lo, dT);
        gemm3_kernel<1><<<dim3(12, 73), 256, 0, stream>>>(
            xn_hi, xn_lo, wspl + W_FC1, fc1_b + l*1536, nullptr, nullptr, hb_hi, hb_lo, 384, 1536, dT);
        gemm3_kernel<2><<<dim3(3, 73), 256, 0, stream>>>(
            hb_hi, hb_lo, wspl + W_FC2, fc2_b + l*384, src, src, nullptr, nullptr, 1536, 384, dT);
        decide_kernel<<<1, 256, 0, stream>>>(rawh, entb, pm, keep, dT, dTn, l);
        gather_kernel<<<dim3(577, 8), 128, 0, stream>>>(src, dst, keep, dT, dTn);
        bump_kernel<<<1, 1, 0, stream>>>(dT, dTn);
    }
    lnf_kernel<<<8, 64, 0, stream>>>(bufs[0], norm_s, norm_b, xf, dT);
    head_kernel<<<32, 256, 0, stream>>>(xf, head_w, head_b, out);
}

// Round 6
// 2445.700 us; speedup vs baseline: 2.4138x; 1.0745x over previous
//
#include <hip/hip_runtime.h>
#include <math.h>

#define NHEADS 6
#define DMODEL 384
#define TMAXT  577
#define NMAXT  576
#define BATCH  8
#define LAYERS 12

typedef __attribute__((ext_vector_type(8))) short bf16x8v;
typedef __attribute__((ext_vector_type(4))) float f32x4v;

// ---------------- workspace layout (float indices) ----------------
#define XSZ      (8ull*577*384)            // 1,772,544
#define X0_OFF   0ull
#define X1_OFF   (X0_OFF + XSZ)
#define XN_OFF   (X1_OFF + XSZ)            // xn split planes: 2 x XSZ ushort
#define QKV_OFF  (XN_OFF + XSZ)
#define QKV_SZ   (8ull*577*1152)           // elements per plane
#define AO_OFF   (QKV_OFF + QKV_SZ)        // qkv split planes = QKV_SZ floats total
#define HBELEM   (8ull*577*1536)
#define RAWH_OFF (AO_OFF + XSZ)
#define RAWH_SZ  (8ull*6*576)
#define ENT_OFF  (RAWH_OFF + RAWH_SZ)
#define PM_OFF   (ENT_OFF + 64)
#define XF_OFF   (PM_OFF + 64)
#define KEEP_OFF (XF_OFF + 8*384)
#define T_OFF    (KEEP_OFF + 640)          // T slot 0
#define TN_OFF   (T_OFF + 16)              // T slot 1
#define WSPL_OFF (TN_OFF + 16)

// weight split sub-offsets (ushort units inside WSPL)
#define W_QKV   0ull
#define W_PROJ  884736ull
#define W_FC1   1179648ull
#define W_FC2   2359296ull
#define W_PATCH 3538944ull                 // 768*384*2 = 589,824 ushorts

// ---------------- bf16 split helpers ----------------
__device__ inline unsigned short rne_bf16(float f) {
    unsigned int u = __float_as_uint(f);
    u += 0x7FFFu + ((u >> 16) & 1u);
    return (unsigned short)(u >> 16);
}
__device__ inline float bf16_to_f(unsigned short h) {
    return __uint_as_float(((unsigned int)h) << 16);
}
__device__ inline void split_bf16(float x, unsigned short& h, unsigned short& l) {
    h = rne_bf16(x);
    l = rne_bf16(x - bf16_to_f(h));
}

// ---------------- prologue: cls row + pos, init T slot 0 ----------------
__global__ __launch_bounds__(128) void prologue_kernel(const float* __restrict__ cls_tok,
                                                       const float* __restrict__ pos,
                                                       float* __restrict__ x0,
                                                       int* __restrict__ dT0)
{
    int b = blockIdx.x;
    for (int d = threadIdx.x; d < 384; d += 128)
        x0[(size_t)b*577*384 + d] = cls_tok[d] + pos[d];
    if (b == 0 && threadIdx.x == 0) *dT0 = 577;
}

// ---------------- generic split+transpose: W[K][N] fp32 -> [N][K] hi/lo bf16 ----------------
__global__ __launch_bounds__(256) void psplit_kernel(const float* __restrict__ W,
                                                     unsigned short* __restrict__ dst,
                                                     int K, int N)
{
    int ktiles = K >> 5, ntiles = N >> 5;
    int tid = blockIdx.x;
    if (tid >= ktiles * ntiles) return;
    int tk = tid % ktiles, tn = tid / ktiles;
    int k0 = tk << 5, n0 = tn << 5;
    __shared__ unsigned short Th[32][34];
    __shared__ unsigned short Tl[32][34];
    int t = threadIdx.x;
    {
        int row = t >> 3, c4 = (t & 7) << 2;
        float4 wv = *(const float4*)(W + (size_t)(k0 + row) * N + n0 + c4);
        unsigned short h, l;
        split_bf16(wv.x, h, l); Th[c4+0][row] = h; Tl[c4+0][row] = l;
        split_bf16(wv.y, h, l); Th[c4+1][row] = h; Tl[c4+1][row] = l;
        split_bf16(wv.z, h, l); Th[c4+2][row] = h; Tl[c4+2][row] = l;
        split_bf16(wv.w, h, l); Th[c4+3][row] = h; Tl[c4+3][row] = l;
    }
    __syncthreads();
    {
        int n = t >> 3, k4 = (t & 7) << 2;
        unsigned short* dh = dst + (size_t)(n0 + n) * K + k0 + k4;
        unsigned short* dl = dh + (size_t)K * N;
        *(ushort4*)dh = make_ushort4(Th[n][k4], Th[n][k4+1], Th[n][k4+2], Th[n][k4+3]);
        *(ushort4*)dl = make_ushort4(Tl[n][k4], Tl[n][k4+1], Tl[n][k4+2], Tl[n][k4+3]);
    }
}

// ---------------- per-layer weight split (4 matrices) ----------------
__global__ __launch_bounds__(256) void wsplit_kernel(const float* __restrict__ qkvw,
                                                     const float* __restrict__ projw,
                                                     const float* __restrict__ fc1w,
                                                     const float* __restrict__ fc2w,
                                                     unsigned short* __restrict__ wspl)
{
    int mat = blockIdx.y;
    const float* W; int K, N; size_t off;
    if (mat == 0)      { W = qkvw; K = 384;  N = 1152; off = W_QKV; }
    else if (mat == 1) { W = projw; K = 384; N = 384;  off = W_PROJ; }
    else if (mat == 2) { W = fc1w; K = 384;  N = 1536; off = W_FC1; }
    else               { W = fc2w; K = 1536; N = 384;  off = W_FC2; }
    int ktiles = K >> 5, ntiles = N >> 5;
    int tid = blockIdx.x;
    if (tid >= ktiles * ntiles) return;
    int tk = tid % ktiles, tn = tid / ktiles;
    int k0 = tk << 5, n0 = tn << 5;
    __shared__ unsigned short Th[32][34];
    __shared__ unsigned short Tl[32][34];
    int t = threadIdx.x;
    {
        int row = t >> 3, c4 = (t & 7) << 2;
        float4 wv = *(const float4*)(W + (size_t)(k0 + row) * N + n0 + c4);
        unsigned short h, l;
        split_bf16(wv.x, h, l); Th[c4+0][row] = h; Tl[c4+0][row] = l;
        split_bf16(wv.y, h, l); Th[c4+1][row] = h; Tl[c4+1][row] = l;
        split_bf16(wv.z, h, l); Th[c4+2][row] = h; Tl[c4+2][row] = l;
        split_bf16(wv.w, h, l); Th[c4+3][row] = h; Tl[c4+3][row] = l;
    }
    __syncthreads();
    {
        int n = t >> 3, k4 = (t & 7) << 2;
        unsigned short* dh = wspl + off + (size_t)(n0 + n) * K + k0 + k4;
        unsigned short* dl = dh + (size_t)K * N;
        *(ushort4*)dh = make_ushort4(Th[n][k4], Th[n][k4+1], Th[n][k4+2], Th[n][k4+3]);
        *(ushort4*)dl = make_ushort4(Tl[n][k4], Tl[n][k4+1], Tl[n][k4+2], Tl[n][k4+3]);
    }
}

// ---------------- patch embed: bf16x3 MFMA, 64x64 tile ----------------
// A = gathered image patches (split in-kernel), B = pre-split patch_w^T, out fp32 + pb + pos
__global__ __launch_bounds__(256, 4) void patch_mfma_kernel(const float* __restrict__ x,
                                                            const unsigned short* __restrict__ Wt,
                                                            const float* __restrict__ pb,
                                                            const float* __restrict__ pos,
                                                            float* __restrict__ x0)
{
    const int K = 768, N = 384, M = 4608;
    int m0 = blockIdx.y * 64;
    int n0 = blockIdx.x * 64;

    __shared__ unsigned short As[2][64][40];
    __shared__ unsigned short Bs[2][64][40];

    int t = threadIdx.x;
    int lane = t & 63, w = t >> 6;
    int wr = w >> 1, wc = w & 1;
    int quad = lane >> 4, l16 = lane & 15;

    f32x4v acc[2][2];
#pragma unroll
    for (int i = 0; i < 2; i++)
#pragma unroll
        for (int j = 0; j < 2; j++) acc[i][j] = (f32x4v){0.f, 0.f, 0.f, 0.f};

    int arow = t >> 2, ak8 = (t & 3) * 8;
    int garow = m0 + arow;
    int ab = garow / 576, att = garow % 576;
    int g1 = att / 24, g2 = att % 24;
    const float* xr = x + ((size_t)(ab*3)*384 + g1*16)*384 + g2*16;

    int bn = t >> 2, bk8 = (t & 3) * 8;
    const unsigned short* Bh = Wt + (size_t)(n0 + bn) * K + bk8;
    const unsigned short* Bl = Bh + (size_t)K * N;

    for (int k0 = 0; k0 < K; k0 += 32) {
        int k = k0 + ak8;
        int c = k >> 8, rr = k & 255, p1 = rr >> 4, p2 = rr & 15;
        const float* src = xr + ((size_t)c*384 + p1)*384 + p2;
        float4 f0 = *(const float4*)(src);
        float4 f1 = *(const float4*)(src + 4);
        float f[8] = {f0.x, f0.y, f0.z, f0.w, f1.x, f1.y, f1.z, f1.w};
        unsigned short ah[8], al[8];
#pragma unroll
        for (int j = 0; j < 8; j++) split_bf16(f[j], ah[j], al[j]);
        uint4 vbh = *(const uint4*)(Bh + k0);
        uint4 vbl = *(const uint4*)(Bl + k0);
        __syncthreads();
        *(uint4*)&As[0][arow][ak8] = *(uint4*)ah;
        *(uint4*)&As[1][arow][ak8] = *(uint4*)al;
        *(uint4*)&Bs[0][bn][bk8] = vbh;
        *(uint4*)&Bs[1][bn][bk8] = vbl;
        __syncthreads();

        bf16x8v afh[2], afl[2], bfh[2], bfl[2];
#pragma unroll
        for (int rb = 0; rb < 2; rb++) {
            int r = wr * 32 + rb * 16 + l16;
            afh[rb] = *(const bf16x8v*)&As[0][r][quad * 8];
            afl[rb] = *(const bf16x8v*)&As[1][r][quad * 8];
        }
#pragma unroll
        for (int cb = 0; cb < 2; cb++) {
            int cc = wc * 32 + cb * 16 + l16;
            bfh[cb] = *(const bf16x8v*)&Bs[0][cc][quad * 8];
            bfl[cb] = *(const bf16x8v*)&Bs[1][cc][quad * 8];
        }
#pragma unroll
        for (int rb = 0; rb < 2; rb++)
#pragma unroll
            for (int cb = 0; cb < 2; cb++) {
                acc[rb][cb] = __builtin_amdgcn_mfma_f32_16x16x32_bf16(afl[rb], bfh[cb], acc[rb][cb], 0, 0, 0);
                acc[rb][cb] = __builtin_amdgcn_mfma_f32_16x16x32_bf16(afh[rb], bfl[cb], acc[rb][cb], 0, 0, 0);
                acc[rb][cb] = __builtin_amdgcn_mfma_f32_16x16x32_bf16(afh[rb], bfh[cb], acc[rb][cb], 0, 0, 0);
            }
    }

#pragma unroll
    for (int rb = 0; rb < 2; rb++) {
#pragma unroll
        for (int reg = 0; reg < 4; reg++) {
            int r = m0 + wr * 32 + rb * 16 + quad * 4 + reg;
            if (r >= M) continue;
            int bb = r / 576, ttt = r % 576;
#pragma unroll
            for (int cb = 0; cb < 2; cb++) {
                int cc = n0 + wc * 32 + cb * 16 + l16;
                float v = acc[rb][cb][reg] + pb[cc] + pos[(size_t)(1 + ttt)*384 + cc];
                x0[(size_t)(bb*577 + 1 + ttt)*384 + cc] = v;
            }
        }
    }
}

// ---------------- LayerNorm -> split bf16 planes ----------------
__global__ __launch_bounds__(256) void ln_kernel(const float* __restrict__ xin,
                                                 const float* __restrict__ sc,
                                                 const float* __restrict__ bi,
                                                 unsigned short* __restrict__ yhi,
                                                 unsigned short* __restrict__ ylo,
                                                 const int* __restrict__ dT)
{
    int T = *dT;
    int M = 8 * T;
    int r = blockIdx.x * 4 + (threadIdx.x >> 6);
    if (r >= M) return;
    int lane = threadIdx.x & 63;
    const float* xr = xin + (size_t)r * 384;
    float v[6];
#pragma unroll
    for (int i = 0; i < 6; i++) v[i] = xr[lane + 64*i];
    float s = v[0]+v[1]+v[2]+v[3]+v[4]+v[5];
#pragma unroll
    for (int off = 32; off; off >>= 1) s += __shfl_xor(s, off, 64);
    float mean = s * (1.0f/384.0f);
    float q = 0.f;
#pragma unroll
    for (int i = 0; i < 6; i++) { float d = v[i]-mean; q += d*d; }
#pragma unroll
    for (int off = 32; off; off >>= 1) q += __shfl_xor(q, off, 64);
    float rstd = 1.0f / sqrtf(q * (1.0f/384.0f) + 1e-5f);
#pragma unroll
    for (int i = 0; i < 6; i++) {
        int d = lane + 64*i;
        float y = (v[i]-mean) * rstd * sc[d] + bi[d];
        unsigned short h, l;
        split_bf16(y, h, l);
        yhi[(size_t)r*384 + d] = h;
        ylo[(size_t)r*384 + d] = l;
    }
}

// ---------------- bf16x3 MFMA GEMM, 64x128 tile, split-bf16 out (+optional gelu) ----------------
template<bool GELU>
__global__ __launch_bounds__(256, 3) void gemm3_kernel(const unsigned short* __restrict__ Ahi,
                                                       const unsigned short* __restrict__ Alo,
                                                       const unsigned short* __restrict__ Wt,
                                                       const float* __restrict__ bias,
                                                       unsigned short* __restrict__ Chi,
                                                       unsigned short* __restrict__ Clo,
                                                       int K, int N,
                                                       const int* __restrict__ dT)
{
    int T = *dT; int M = 8 * T;
    int m0 = blockIdx.y * 64;
    if (m0 >= M) return;
    int n0 = blockIdx.x * 128;

    __shared__ unsigned short As[2][64][40];
    __shared__ unsigned short Bs[2][128][40];

    int t = threadIdx.x;
    int lane = t & 63, w = t >> 6;
    int wr = w >> 1, wc = w & 1;
    int quad = lane >> 4, l16 = lane & 15;

    f32x4v acc[2][4];
#pragma unroll
    for (int i = 0; i < 2; i++)
#pragma unroll
        for (int j = 0; j < 4; j++) acc[i][j] = (f32x4v){0.f, 0.f, 0.f, 0.f};

    int arow = t >> 2, ak = (t & 3) * 8;
    int ag = m0 + arow; if (ag > M - 1) ag = M - 1;
    const unsigned short* Ah = Ahi + (size_t)ag * K + ak;
    const unsigned short* Al = Alo + (size_t)ag * K + ak;

    int bn = t >> 1, bk = (t & 1) * 16;
    const unsigned short* Bh = Wt + (size_t)(n0 + bn) * K + bk;
    const unsigned short* Bl = Bh + (size_t)K * N;

    for (int k0 = 0; k0 < K; k0 += 32) {
        uint4 vah  = *(const uint4*)(Ah + k0);
        uint4 val  = *(const uint4*)(Al + k0);
        uint4 vbh0 = *(const uint4*)(Bh + k0);
        uint4 vbh1 = *(const uint4*)(Bh + k0 + 8);
        uint4 vbl0 = *(const uint4*)(Bl + k0);
        uint4 vbl1 = *(const uint4*)(Bl + k0 + 8);
        __syncthreads();
        *(uint4*)&As[0][arow][ak] = vah;
        *(uint4*)&As[1][arow][ak] = val;
        *(uint4*)&Bs[0][bn][bk]     = vbh0;
        *(uint4*)&Bs[0][bn][bk + 8] = vbh1;
        *(uint4*)&Bs[1][bn][bk]     = vbl0;
        *(uint4*)&Bs[1][bn][bk + 8] = vbl1;
        __syncthreads();

        bf16x8v afh[2], afl[2], bfh[4], bfl[4];
#pragma unroll
        for (int rb = 0; rb < 2; rb++) {
            int r = wr * 32 + rb * 16 + l16;
            afh[rb] = *(const bf16x8v*)&As[0][r][quad * 8];
            afl[rb] = *(const bf16x8v*)&As[1][r][quad * 8];
        }
#pragma unroll
        for (int cb = 0; cb < 4; cb++) {
            int c = wc * 64 + cb * 16 + l16;
            bfh[cb] = *(const bf16x8v*)&Bs[0][c][quad * 8];
            bfl[cb] = *(const bf16x8v*)&Bs[1][c][quad * 8];
        }
#pragma unroll
        for (int rb = 0; rb < 2; rb++)
#pragma unroll
            for (int cb = 0; cb < 4; cb++) {
                acc[rb][cb] = __builtin_amdgcn_mfma_f32_16x16x32_bf16(afl[rb], bfh[cb], acc[rb][cb], 0, 0, 0);
                acc[rb][cb] = __builtin_amdgcn_mfma_f32_16x16x32_bf16(afh[rb], bfl[cb], acc[rb][cb], 0, 0, 0);
                acc[rb][cb] = __builtin_amdgcn_mfma_f32_16x16x32_bf16(afh[rb], bfh[cb], acc[rb][cb], 0, 0, 0);
            }
    }

#pragma unroll
    for (int rb = 0; rb < 2; rb++) {
#pragma unroll
        for (int reg = 0; reg < 4; reg++) {
            int r = m0 + wr * 32 + rb * 16 + quad * 4 + reg;
            if (r >= M) continue;
#pragma unroll
            for (int cb = 0; cb < 4; cb++) {
                int c = n0 + wc * 64 + cb * 16 + l16;
                float v = acc[rb][cb][reg] + bias[c];
                if (GELU) v = 0.5f * v * (1.0f + erff(v * 0.70710678118654752440f));
                unsigned short h, l;
                split_bf16(v, h, l);
                Chi[(size_t)r * N + c] = h;
                Clo[(size_t)r * N + c] = l;
            }
        }
    }
}

// ---------------- bf16x3 MFMA GEMM, 64x64 tile, +resid, fp32 out (N=384 GEMMs) ----------------
__global__ __launch_bounds__(256, 4) void gemm64_kernel(const unsigned short* __restrict__ Ahi,
                                                        const unsigned short* __restrict__ Alo,
                                                        const unsigned short* __restrict__ Wt,
                                                        const float* __restrict__ bias,
                                                        const float* __restrict__ resid,
                                                        float* __restrict__ Cf,
                                                        int K, int N,
                                                        const int* __restrict__ dT)
{
    int T = *dT; int M = 8 * T;
    int m0 = blockIdx.y * 64;
    if (m0 >= M) return;
    int n0 = blockIdx.x * 64;

    __shared__ unsigned short As[2][64][40];
    __shared__ unsigned short Bs[2][64][40];

    int t = threadIdx.x;
    int lane = t & 63, w = t >> 6;
    int wr = w >> 1, wc = w & 1;
    int quad = lane >> 4, l16 = lane & 15;

    f32x4v acc[2][2];
#pragma unroll
    for (int i = 0; i < 2; i++)
#pragma unroll
        for (int j = 0; j < 2; j++) acc[i][j] = (f32x4v){0.f, 0.f, 0.f, 0.f};

    int arow = t >> 2, ak = (t & 3) * 8;
    int ag = m0 + arow; if (ag > M - 1) ag = M - 1;
    const unsigned short* Ah = Ahi + (size_t)ag * K + ak;
    const unsigned short* Al = Alo + (size_t)ag * K + ak;

    int bn = t >> 2, bk = (t & 3) * 8;
    const unsigned short* Bh = Wt + (size_t)(n0 + bn) * K + bk;
    const unsigned short* Bl = Bh + (size_t)K * N;

    for (int k0 = 0; k0 < K; k0 += 32) {
        uint4 vah = *(const uint4*)(Ah + k0);
        uint4 val = *(const uint4*)(Al + k0);
        uint4 vbh = *(const uint4*)(Bh + k0);
        uint4 vbl = *(const uint4*)(Bl + k0);
        __syncthreads();
        *(uint4*)&As[0][arow][ak] = vah;
        *(uint4*)&As[1][arow][ak] = val;
        *(uint4*)&Bs[0][bn][bk] = vbh;
        *(uint4*)&Bs[1][bn][bk] = vbl;
        __syncthreads();

        bf16x8v afh[2], afl[2], bfh[2], bfl[2];
#pragma unroll
        for (int rb = 0; rb < 2; rb++) {
            int r = wr * 32 + rb * 16 + l16;
            afh[rb] = *(const bf16x8v*)&As[0][r][quad * 8];
            afl[rb] = *(const bf16x8v*)&As[1][r][quad * 8];
        }
#pragma unroll
        for (int cb = 0; cb < 2; cb++) {
            int c = wc * 32 + cb * 16 + l16;
            bfh[cb] = *(const bf16x8v*)&Bs[0][c][quad * 8];
            bfl[cb] = *(const bf16x8v*)&Bs[1][c][quad * 8];
        }
#pragma unroll
        for (int rb = 0; rb < 2; rb++)
#pragma unroll
            for (int cb = 0; cb < 2; cb++) {
                acc[rb][cb] = __builtin_amdgcn_mfma_f32_16x16x32_bf16(afl[rb], bfh[cb], acc[rb][cb], 0, 0, 0);
                acc[rb][cb] = __builtin_amdgcn_mfma_f32_16x16x32_bf16(afh[rb], bfl[cb], acc[rb][cb], 0, 0, 0);
                acc[rb][cb] = __builtin_amdgcn_mfma_f32_16x16x32_bf16(afh[rb], bfh[cb], acc[rb][cb], 0, 0, 0);
            }
    }

#pragma unroll
    for (int rb = 0; rb < 2; rb++) {
#pragma unroll
        for (int reg = 0; reg < 4; reg++) {
            int r = m0 + wr * 32 + rb * 16 + quad * 4 + reg;
            if (r >= M) continue;
#pragma unroll
            for (int cb = 0; cb < 2; cb++) {
                int c = n0 + wc * 32 + cb * 16 + l16;
                float v = acc[rb][cb][reg] + bias[c] + resid[(size_t)r * N + c];
                Cf[(size_t)r * N + c] = v;
            }
        }
    }
}

// ---------------- flash attention v4: pre-split qkv planes, MFMA QK^T/PV ----------------
__global__ __launch_bounds__(256, 3) void attn_kernel(const unsigned short* __restrict__ qh,
                                                      const unsigned short* __restrict__ ql,
                                                      unsigned short* __restrict__ out_hi,
                                                      unsigned short* __restrict__ out_lo,
                                                      const int* __restrict__ dT)
{
    int T = *dT;
    int q0 = blockIdx.x * 64;
    if (q0 >= T) return;
    int bh = blockIdx.y;
    int b = bh / NHEADS, h = bh % NHEADS;

    __shared__ unsigned short Ks[2][64][72];   // K tile [tok][d]; later P [q][ktok]
    __shared__ unsigned short Vt[2][64][72];   // V^T tile [d][tok]
    __shared__ float Ss[64][66];
    __shared__ float m_s[64], l_s[64], al_s[64];

    int t = threadIdx.x;
    int lane = t & 63, w = t >> 6;
    int l16 = lane & 15, quad = lane >> 4;

    const bf16x8v zf = (bf16x8v){0,0,0,0,0,0,0,0};
    bf16x8v qf[2][2];   // [kstep][hi/lo]
    {
        int gq = q0 + w * 16 + l16;
        bool valid = gq < T;
        size_t base = (size_t)(b * T + (valid ? gq : 0)) * 1152 + h * 64;
#pragma unroll
        for (int ks = 0; ks < 2; ks++) {
            int off = ks * 32 + quad * 8;
            qf[ks][0] = valid ? *(const bf16x8v*)(qh + base + off) : zf;
            qf[ks][1] = valid ? *(const bf16x8v*)(ql + base + off) : zf;
        }
    }
    if (t < 64) { m_s[t] = -INFINITY; l_s[t] = 0.f; }

    f32x4v oacc[4];
#pragma unroll
    for (int cb = 0; cb < 4; cb++) oacc[cb] = (f32x4v){0.f, 0.f, 0.f, 0.f};

    int ntiles = (T + 63) >> 6;
    for (int kt = 0; kt < ntiles; kt++) {
        int kbase = kt * 64;
        __syncthreads();

        // stage K direct (pre-split), V transposed
        {
            int gk = kbase + lane;
            int sd0 = w * 16;
            bool valid = gk < T;
            size_t base = (size_t)(b * T + (valid ? gk : 0)) * 1152 + 384 + h * 64 + sd0;
            const uint4 z4 = make_uint4(0,0,0,0);
            uint4 kh0 = valid ? *(const uint4*)(qh + base)     : z4;
            uint4 kh1 = valid ? *(const uint4*)(qh + base + 8) : z4;
            uint4 kl0 = valid ? *(const uint4*)(ql + base)     : z4;
            uint4 kl1 = valid ? *(const uint4*)(ql + base + 8) : z4;
            *(uint4*)&Ks[0][lane][sd0]     = kh0;
            *(uint4*)&Ks[0][lane][sd0 + 8] = kh1;
            *(uint4*)&Ks[1][lane][sd0]     = kl0;
            *(uint4*)&Ks[1][lane][sd0 + 8] = kl1;
            uint4 vh0 = valid ? *(const uint4*)(qh + base + 384)     : z4;
            uint4 vh1 = valid ? *(const uint4*)(qh + base + 384 + 8) : z4;
            uint4 vl0 = valid ? *(const uint4*)(ql + base + 384)     : z4;
            uint4 vl1 = valid ? *(const uint4*)(ql + base + 384 + 8) : z4;
            unsigned short th[16], tl[16];
            *(uint4*)&th[0] = vh0; *(uint4*)&th[8] = vh1;
            *(uint4*)&tl[0] = vl0; *(uint4*)&tl[8] = vl1;
#pragma unroll
            for (int i = 0; i < 16; i++) {
                Vt[0][sd0 + i][lane] = th[i];
                Vt[1][sd0 + i][lane] = tl[i];
            }
        }
        __syncthreads();

        // S = Q K^T
#pragma unroll
        for (int cb = 0; cb < 4; cb++) {
            f32x4v sacc = (f32x4v){0.f, 0.f, 0.f, 0.f};
#pragma unroll
            for (int ks = 0; ks < 2; ks++) {
                bf16x8v bhi = *(const bf16x8v*)&Ks[0][cb*16 + l16][ks*32 + quad*8];
                bf16x8v blo = *(const bf16x8v*)&Ks[1][cb*16 + l16][ks*32 + quad*8];
                sacc = __builtin_amdgcn_mfma_f32_16x16x32_bf16(qf[ks][1], bhi, sacc, 0, 0, 0);
                sacc = __builtin_amdgcn_mfma_f32_16x16x32_bf16(qf[ks][0], blo, sacc, 0, 0, 0);
                sacc = __builtin_amdgcn_mfma_f32_16x16x32_bf16(qf[ks][0], bhi, sacc, 0, 0, 0);
            }
            int col = cb*16 + l16;
            int gk = kbase + col;
#pragma unroll
            for (int reg = 0; reg < 4; reg++)
                Ss[w*16 + quad*4 + reg][col] = (gk < T) ? sacc[reg]*0.125f : -INFINITY;
        }
        __syncthreads();

        // online softmax; P split overwrites Ks
        {
            int rr = t >> 2, sub = t & 3;
            float mx = -INFINITY;
#pragma unroll
            for (int kk = 0; kk < 16; kk++) mx = fmaxf(mx, Ss[rr][sub*16 + kk]);
            mx = fmaxf(mx, __shfl_xor(mx, 1, 64));
            mx = fmaxf(mx, __shfl_xor(mx, 2, 64));
            float mold = m_s[rr];
            float newm = fmaxf(mold, mx);
            float ps = 0.f;
#pragma unroll
            for (int kk = 0; kk < 16; kk++) {
                float p = __expf(Ss[rr][sub*16 + kk] - newm);
                unsigned short hh, ll;
                split_bf16(p, hh, ll);
                Ks[0][rr][sub*16 + kk] = hh;
                Ks[1][rr][sub*16 + kk] = ll;
                ps += p;
            }
            ps += __shfl_xor(ps, 1, 64);
            ps += __shfl_xor(ps, 2, 64);
            if (sub == 0) {
                float alpha = __expf(mold - newm);
                l_s[rr] = l_s[rr]*alpha + ps;
                m_s[rr] = newm;
                al_s[rr] = alpha;
            }
        }
        __syncthreads();

        // O = alpha*O + P V
#pragma unroll
        for (int reg = 0; reg < 4; reg++) {
            float a = al_s[w*16 + quad*4 + reg];
#pragma unroll
            for (int cb = 0; cb < 4; cb++) oacc[cb][reg] *= a;
        }
#pragma unroll
        for (int ks = 0; ks < 2; ks++) {
            bf16x8v phi = *(const bf16x8v*)&Ks[0][w*16 + l16][ks*32 + quad*8];
            bf16x8v plo = *(const bf16x8v*)&Ks[1][w*16 + l16][ks*32 + quad*8];
#pragma unroll
            for (int cb = 0; cb < 4; cb++) {
                bf16x8v vhi = *(const bf16x8v*)&Vt[0][cb*16 + l16][ks*32 + quad*8];
                bf16x8v vlo = *(const bf16x8v*)&Vt[1][cb*16 + l16][ks*32 + quad*8];
                oacc[cb] = __builtin_amdgcn_mfma_f32_16x16x32_bf16(plo, vhi, oacc[cb], 0, 0, 0);
                oacc[cb] = __builtin_amdgcn_mfma_f32_16x16x32_bf16(phi, vlo, oacc[cb], 0, 0, 0);
                oacc[cb] = __builtin_amdgcn_mfma_f32_16x16x32_bf16(phi, vhi, oacc[cb], 0, 0, 0);
            }
        }
    }

#pragma unroll
    for (int reg = 0; reg < 4; reg++) {
        int gq = q0 + w*16 + quad*4 + reg;
        if (gq < T) {
            float inv = 1.0f / l_s[w*16 + quad*4 + reg];
#pragma unroll
            for (int cb = 0; cb < 4; cb++) {
                float v = oacc[cb][reg] * inv;
                unsigned short hh, ll;
                split_bf16(v, hh, ll);
                size_t o = (size_t)(b*T + gq)*384 + h*64 + cb*16 + l16;
                out_hi[o] = hh;
                out_lo[o] = ll;
            }
        }
    }
}

// ---------------- cls-row stats (reads split qkv planes) ----------------
__global__ __launch_bounds__(256) void cls_stats_kernel(const unsigned short* __restrict__ qh,
                                                        const unsigned short* __restrict__ ql,
                                                        float* __restrict__ raw_h,
                                                        float* __restrict__ ent,
                                                        const int* __restrict__ dT)
{
    int T = *dT;
    int bh = blockIdx.x;
    int b = bh / NHEADS, h = bh % NHEADS;
    __shared__ float q0s[64];
    __shared__ float logit[TMAXT];
    __shared__ float red[8];
    int t = threadIdx.x;
    if (t < 64) {
        size_t o = (size_t)(b*T)*1152 + h*64 + t;
        q0s[t] = bf16_to_f(qh[o]) + bf16_to_f(ql[o]);
    }
    __syncthreads();
    float lmax = -INFINITY;
    for (int j = t; j < T; j += 256) {
        size_t o = (size_t)(b*T + j)*1152 + 384 + h*64;
        float dot = 0.f;
#pragma unroll
        for (int d = 0; d < 64; d += 4) {
            ushort4 a = *(const ushort4*)(qh + o + d);
            ushort4 c = *(const ushort4*)(ql + o + d);
            dot += q0s[d+0]*(bf16_to_f(a.x)+bf16_to_f(c.x));
            dot += q0s[d+1]*(bf16_to_f(a.y)+bf16_to_f(c.y));
            dot += q0s[d+2]*(bf16_to_f(a.z)+bf16_to_f(c.z));
            dot += q0s[d+3]*(bf16_to_f(a.w)+bf16_to_f(c.w));
        }
        float lg = dot * 0.125f;
        logit[j] = lg;
        lmax = fmaxf(lmax, lg);
    }
#pragma unroll
    for (int off = 32; off; off >>= 1) lmax = fmaxf(lmax, __shfl_xor(lmax, off, 64));
    if ((t & 63) == 0) red[t >> 6] = lmax;
    __syncthreads();
    float gmax = fmaxf(fmaxf(red[0], red[1]), fmaxf(red[2], red[3]));
    __syncthreads();
    float psum = 0.f;
    for (int j = t; j < T; j += 256) psum += expf(logit[j] - gmax);
#pragma unroll
    for (int off = 32; off; off >>= 1) psum += __shfl_xor(psum, off, 64);
    if ((t & 63) == 0) red[4 + (t >> 6)] = psum;
    __syncthreads();
    float inv = 1.0f / (red[4] + red[5] + red[6] + red[7]);
    float entp = 0.f;
    for (int j = t; j < T; j += 256) {
        float p = expf(logit[j] - gmax) * inv;
        entp += -p * logf(p + 1e-6f);
        if (j >= 1) {
            size_t o = (size_t)(b*T + j)*1152 + 768 + h*64;
            float vn = 0.f;
#pragma unroll
            for (int d = 0; d < 64; d += 4) {
                ushort4 a = *(const ushort4*)(qh + o + d);
                ushort4 c = *(const ushort4*)(ql + o + d);
                float v0 = bf16_to_f(a.x)+bf16_to_f(c.x);
                float v1 = bf16_to_f(a.y)+bf16_to_f(c.y);
                float v2 = bf16_to_f(a.z)+bf16_to_f(c.z);
                float v3 = bf16_to_f(a.w)+bf16_to_f(c.w);
                vn += v0*v0 + v1*v1 + v2*v2 + v3*v3;
            }
            raw_h[(size_t)bh*576 + (j - 1)] = p * sqrtf(vn);
        }
    }
#pragma unroll
    for (int off = 32; off; off >>= 1) entp += __shfl_xor(entp, off, 64);
    __syncthreads();
    if ((t & 63) == 0) red[t >> 6] = entp;
    __syncthreads();
    if (t == 0) ent[bh] = red[0] + red[1] + red[2] + red[3];
}

// ---------------- prune decision (latency-parallel single block) ----------------
__global__ __launch_bounds__(256) void decide_kernel(const float* __restrict__ raw_h,
                                                     const float* __restrict__ ent,
                                                     float* __restrict__ prev_mass,
                                                     int* __restrict__ keep,
                                                     const int* __restrict__ dT,
                                                     int* __restrict__ dTnext,
                                                     int layer)
{
    int t = threadIdx.x;
    int T = *dT, N = T - 1;
    __shared__ float rbS[8][580];
    __shared__ float massS[8];
    __shared__ float pmS[8];
    __shared__ float esumS;
    __shared__ float scores[NMAXT];
    __shared__ int   keptFlag[NMAXT];
    __shared__ int   nnS;
    __shared__ int   wsum[4], wpre[4];

    if (N <= 16) {
        for (int i = t; i < T; i += 256) keep[i] = i;
        if (t == 0) *dTnext = T;
        return;
    }
    if (t < 8) pmS[t] = prev_mass[t];

    {
        int b = t >> 5, lane = t & 31;
        const float* base = raw_h + (size_t)b * 6 * 576;
        float s = 0.f;
        for (int j = lane; j < N; j += 32) {
            float a0 = base[0*576 + j];
            float a1 = base[1*576 + j];
            float a2 = base[2*576 + j];
            float a3 = base[3*576 + j];
            float a4 = base[4*576 + j];
            float a5 = base[5*576 + j];
            float rb = ((a0 + a1) + (a2 + a3)) + (a4 + a5);
            rbS[b][j] = rb;
            s += rb;
        }
#pragma unroll
        for (int off = 16; off; off >>= 1) s += __shfl_xor(s, off, 64);
        if (lane == 0) massS[b] = s;
    }
    if (t < 64) {
        float e = (t < 48) ? ent[t] : 0.f;
#pragma unroll
        for (int off = 32; off; off >>= 1) e += __shfl_xor(e, off, 64);
        if (t == 0) esumS = e;
    }
    __syncthreads();

    for (int j = t; j < N; j += 256) {
        float s = 0.f;
#pragma unroll
        for (int b = 0; b < 8; b++)
            s += rbS[b][j] / (massS[b] + 1e-6f);
        scores[j] = s * 0.125f;
    }
    __syncthreads();

    if (t == 0) {
        float rho_mean = esumS / 48.0f / logf((float)T);
        int Nn;
        if (layer == 0) {
            Nn = N;
        } else {
            float dm = 0.f;
#pragma unroll
            for (int b = 0; b < 8; b++)
                dm += fabsf(massS[b] - pmS[b]) / (pmS[b] + 1e-6f);
            dm *= 0.125f;
            float kr = 1.0f - 0.1f * (rho_mean + dm);
            kr = fminf(fmaxf(kr, 0.0f), 1.0f);
            Nn = (int)((double)N * (double)kr);
            if (Nn < 16) Nn = 16;
        }
        nnS = Nn;
        *dTnext = Nn + 1;
    }
    __syncthreads();
    if (t < 8) prev_mass[t] = massS[t];
    int Nn = nnS;

    if (Nn < N) {
        for (int j = t; j < N; j += 256) {
            float sj = scores[j];
            int cnt = 0;
            int j2 = 0;
            for (; j2 + 8 <= N; j2 += 8) {
                float x0 = scores[j2+0], x1 = scores[j2+1];
                float x2 = scores[j2+2], x3 = scores[j2+3];
                float x4 = scores[j2+4], x5 = scores[j2+5];
                float x6 = scores[j2+6], x7 = scores[j2+7];
                cnt += (x0 > sj) || (x0 == sj && j2+0 < j);
                cnt += (x1 > sj) || (x1 == sj && j2+1 < j);
                cnt += (x2 > sj) || (x2 == sj && j2+2 < j);
                cnt += (x3 > sj) || (x3 == sj && j2+3 < j);
                cnt += (x4 > sj) || (x4 == sj && j2+4 < j);
                cnt += (x5 > sj) || (x5 == sj && j2+5 < j);
                cnt += (x6 > sj) || (x6 == sj && j2+6 < j);
                cnt += (x7 > sj) || (x7 == sj && j2+7 < j);
            }
            for (; j2 < N; j2++) {
                float s2 = scores[j2];
                cnt += (s2 > sj) || (s2 == sj && j2 < j);
            }
            keptFlag[j] = (cnt < Nn) ? 1 : 0;
        }
        __syncthreads();

        int local = 0;
        int kf[3];
#pragma unroll
        for (int c = 0; c < 3; c++) {
            int j = 3*t + c;
            kf[c] = (j < N) ? keptFlag[j] : 0;
            local += kf[c];
        }
        int lane64 = t & 63, wv = t >> 6;
        int inc = local;
#pragma unroll
        for (int off = 1; off < 64; off <<= 1) {
            int nb = __shfl_up(inc, off, 64);
            if (lane64 >= off) inc += nb;
        }
        if (lane64 == 63) wsum[wv] = inc;
        __syncthreads();
        if (t == 0) {
            int run = 0;
#pragma unroll
            for (int i = 0; i < 4; i++) { wpre[i] = run; run += wsum[i]; }
            keep[0] = 0;
        }
        __syncthreads();
        int pos = 1 + (inc - local) + wpre[wv];
#pragma unroll
        for (int c = 0; c < 3; c++) {
            int j = 3*t + c;
            if (j < N && kf[c]) keep[pos++] = j + 1;
        }
    } else {
        for (int i = t; i < T; i += 256) keep[i] = i;
    }
}

// ---------------- gather pruned tokens (ping-pong) ----------------
__global__ __launch_bounds__(128) void gather_kernel(const float* __restrict__ src,
                                                     float* __restrict__ dst,
                                                     const int* __restrict__ keep,
                                                     const int* __restrict__ dT,
                                                     const int* __restrict__ dTnext)
{
    int Tn = *dTnext;
    int ti = blockIdx.x;
    if (ti >= Tn) return;
    int To = *dT;
    int b = blockIdx.y;
    const float* s = src + (size_t)(b*To + keep[ti]) * 384;
    float* d = dst + (size_t)(b*Tn + ti) * 384;
    int t = threadIdx.x;
    if (t < 96) ((float4*)d)[t] = ((const float4*)s)[t];
}

// ---------------- final LN on cls rows ----------------
__global__ __launch_bounds__(64) void lnf_kernel(const float* __restrict__ xin,
                                                 const float* __restrict__ sc,
                                                 const float* __restrict__ bi,
                                                 float* __restrict__ xf,
                                                 const int* __restrict__ dT)
{
    int T = *dT;
    int b = blockIdx.x;
    int lane = threadIdx.x;
    const float* xr = xin + (size_t)(b*T) * 384;
    float v[6];
#pragma unroll
    for (int i = 0; i < 6; i++) v[i] = xr[lane + 64*i];
    float s = v[0]+v[1]+v[2]+v[3]+v[4]+v[5];
#pragma unroll
    for (int off = 32; off; off >>= 1) s += __shfl_xor(s, off, 64);
    float mean = s * (1.0f/384.0f);
    float q = 0.f;
#pragma unroll
    for (int i = 0; i < 6; i++) { float d = v[i]-mean; q += d*d; }
#pragma unroll
    for (int off = 32; off; off >>= 1) q += __shfl_xor(q, off, 64);
    float rstd = 1.0f / sqrtf(q * (1.0f/384.0f) + 1e-5f);
#pragma unroll
    for (int i = 0; i < 6; i++) {
        int d = lane + 64*i;
        xf[(size_t)b*384 + d] = (v[i]-mean) * rstd * sc[d] + bi[d];
    }
}

// ---------------- head ----------------
__global__ __launch_bounds__(256) void head_kernel(const float* __restrict__ xf,
                                                   const float* __restrict__ hw,
                                                   const float* __restrict__ hb,
                                                   float* __restrict__ out)
{
    int idx = blockIdx.x * 256 + threadIdx.x;
    if (idx >= 8000) return;
    int b = idx / 1000, n = idx - b*1000;
    const float* xr = xf + (size_t)b*384;
    float s = hb[n];
#pragma unroll 4
    for (int k = 0; k < 384; k++) s += xr[k] * hw[(size_t)k*1000 + n];
    out[idx] = s;
}

// ---------------- launch ----------------
extern "C" void kernel_launch(void* const* d_in, const int* in_sizes, int n_in,
                              void* d_out, int out_size, void* d_ws, size_t ws_size,
                              hipStream_t stream)
{
    (void)in_sizes; (void)n_in; (void)out_size; (void)ws_size;
    const float* x       = (const float*)d_in[0];
    const float* patch_w = (const float*)d_in[1];
    const float* patch_b = (const float*)d_in[2];
    const float* cls_tok = (const float*)d_in[3];
    const float* pos     = (const float*)d_in[4];
    const float* ln1_s   = (const float*)d_in[5];
    const float* ln1_b   = (const float*)d_in[6];
    const float* qkv_w   = (const float*)d_in[7];
    const float* qkv_b   = (const float*)d_in[8];
    const float* proj_w  = (const float*)d_in[9];
    const float* proj_b  = (const float*)d_in[10];
    const float* ln2_s   = (const float*)d_in[11];
    const float* ln2_b   = (const float*)d_in[12];
    const float* fc1_w   = (const float*)d_in[13];
    const float* fc1_b   = (const float*)d_in[14];
    const float* fc2_w   = (const float*)d_in[15];
    const float* fc2_b   = (const float*)d_in[16];
    const float* norm_s  = (const float*)d_in[17];
    const float* norm_b  = (const float*)d_in[18];
    const float* head_w  = (const float*)d_in[19];
    const float* head_b  = (const float*)d_in[20];
    float* out = (float*)d_out;
    float* ws  = (float*)d_ws;

    float* x0   = ws + X0_OFF;
    float* x1   = ws + X1_OFF;
    float* rawh = ws + RAWH_OFF;
    float* entb = ws + ENT_OFF;
    float* pm   = ws + PM_OFF;
    float* xf   = ws + XF_OFF;
    int*   keep = (int*)(ws + KEEP_OFF);
    int*   dT0  = (int*)(ws + T_OFF);
    int*   dT1  = (int*)(ws + TN_OFF);

    unsigned short* xn_hi  = (unsigned short*)(ws + XN_OFF);
    unsigned short* xn_lo  = xn_hi + XSZ;
    unsigned short* qkv_hi = (unsigned short*)(ws + QKV_OFF);
    unsigned short* qkv_lo = qkv_hi + QKV_SZ;
    unsigned short* ao_hi  = (unsigned short*)(ws + AO_OFF);
    unsigned short* ao_lo  = ao_hi + XSZ;
    unsigned short* hb_hi  = (unsigned short*)(ws + QKV_OFF);   // aliases qkv (dead by fc1)
    unsigned short* hb_lo  = hb_hi + HBELEM;
    unsigned short* wspl   = (unsigned short*)(ws + WSPL_OFF);

    prologue_kernel<<<8, 128, 0, stream>>>(cls_tok, pos, x0, dT0);
    psplit_kernel<<<288, 256, 0, stream>>>(patch_w, wspl + W_PATCH, 768, 384);
    patch_mfma_kernel<<<dim3(6, 72), 256, 0, stream>>>(x, wspl + W_PATCH, patch_b, pos, x0);

    float* bufs[2] = { x0, x1 };
    for (int l = 0; l < LAYERS; l++) {
        float* src = bufs[l & 1];
        float* dst = bufs[(l + 1) & 1];
        int* cur = (l & 1) ? dT1 : dT0;
        int* nxt = (l & 1) ? dT0 : dT1;
        wsplit_kernel<<<dim3(576, 4), 256, 0, stream>>>(
            qkv_w + (size_t)l*384*1152, proj_w + (size_t)l*384*384,
            fc1_w + (size_t)l*384*1536, fc2_w + (size_t)l*1536*384, wspl);
        ln_kernel<<<1154, 256, 0, stream>>>(src, ln1_s + l*384, ln1_b + l*384, xn_hi, xn_lo, cur);
        gemm3_kernel<false><<<dim3(9, 73), 256, 0, stream>>>(
            xn_hi, xn_lo, wspl + W_QKV, qkv_b + l*1152, qkv_hi, qkv_lo, 384, 1152, cur);
        attn_kernel<<<dim3(10, 48), 256, 0, stream>>>(qkv_hi, qkv_lo, ao_hi, ao_lo, cur);
        cls_stats_kernel<<<48, 256, 0, stream>>>(qkv_hi, qkv_lo, rawh, entb, cur);
        gemm64_kernel<<<dim3(6, 73), 256, 0, stream>>>(
            ao_hi, ao_lo, wspl + W_PROJ, proj_b + l*384, src, src, 384, 384, cur);
        ln_kernel<<<1154, 256, 0, stream>>>(src, ln2_s + l*384, ln2_b + l*384, xn_hi, xn_lo, cur);
        gemm3_kernel<true><<<dim3(12, 73), 256, 0, stream>>>(
            xn_hi, xn_lo, wspl + W_FC1, fc1_b + l*1536, hb_hi, hb_lo, 384, 1536, cur);
        gemm64_kernel<<<dim3(6, 73), 256, 0, stream>>>(
            hb_hi, hb_lo, wspl + W_FC2, fc2_b + l*384, src, src, 1536, 384, cur);
        decide_kernel<<<1, 256, 0, stream>>>(rawh, entb, pm, keep, cur, nxt, l);
        gather_kernel<<<dim3(577, 8), 128, 0, stream>>>(src, dst, keep, cur, nxt);
    }
    lnf_kernel<<<8, 64, 0, stream>>>(bufs[0], norm_s, norm_b, xf, dT0);
    head_kernel<<<32, 256, 0, stream>>>(xf, head_w, head_b, out);
}